// Round 1
// baseline (17341.508 us; speedup 1.0000x reference)
//
#include <hip/hip_runtime.h>
#include <math.h>

// ---------------- constants ----------------
#define NRAYS 200
#define NUNI  32
#define NFINE 64

__device__ __forceinline__ float sigmoidf_(float x){ return 1.0f/(1.0f+expf(-x)); }
__device__ __forceinline__ float softplusf_(float x){ return x>20.0f ? x : log1pf(expf(x)); }
__device__ __forceinline__ int iclampi(int v,int lo,int hi){ return v<lo?lo:(v>hi?hi:v); }

__device__ __forceinline__ float pe_elem(int s, float vx, float vy, float vz){
  // layout: [x,y,z, sin(pi*2^f * comp) f-major f=0..5 comp=0..2, cos(...)]
  const float F0 = 3.14159265358979f;
  if (s < 3) return s==0?vx:(s==1?vy:vz);
  s -= 3;
  bool isCos = false;
  if (s >= 18){ s -= 18; isCos = true; }
  int fi = s/3, ci = s%3;
  float v = ci==0?vx:(ci==1?vy:vz);
  float f = F0 * (float)(1<<fi);
  return isCos ? cosf(f*v) : sinf(f*v);
}

// ---------------- per-ray setup ----------------
__global__ void setup_rays_k(const int* __restrict__ pix, const float* __restrict__ sK,
                             const float* __restrict__ s2in,
                             float* __restrict__ dirs, float* __restrict__ vd,
                             float* __restrict__ vdl)
{
  int r = blockIdx.x*blockDim.x + threadIdx.x;
  if (r >= NRAYS) return;
  // 3x3 inverse of sK (rows of the 4x4, stride 4)
  float a=sK[0],b=sK[1],c=sK[2],d=sK[4],e=sK[5],f=sK[6],g=sK[8],h=sK[9],i=sK[10];
  float det = a*(e*i-f*h) - b*(d*i-f*g) + c*(d*h-e*g);
  float inv00=(e*i-f*h)/det, inv01=(c*h-b*i)/det, inv02=(b*f-c*e)/det;
  float inv10=(f*g-d*i)/det, inv11=(a*i-c*g)/det, inv12=(c*d-a*f)/det;
  float inv20=(d*h-e*g)/det, inv21=(b*g-a*h)/det, inv22=(a*e-b*d)/det;
  int idx = pix[r];
  float x = (float)(idx % 400) * 2.0f;
  float y = (float)(idx / 400) * 2.0f;
  float dx = inv00*x + inv01*y + inv02;
  float dy = inv10*x + inv11*y + inv12;
  float dz = inv20*x + inv21*y + inv22;
  dirs[r*3+0]=dx; dirs[r*3+1]=dy; dirs[r*3+2]=dz;
  float n = sqrtf(dx*dx+dy*dy+dz*dz);
  float vx=dx/n, vy=dy/n, vz=dz/n;
  vd[r*3+0]=vx; vd[r*3+1]=vy; vd[r*3+2]=vz;
  vdl[r*3+0]=s2in[0]*vx + s2in[1]*vy + s2in[2]*vz;
  vdl[r*3+1]=s2in[4]*vx + s2in[5]*vy + s2in[6]*vz;
  vdl[r*3+2]=s2in[8]*vx + s2in[9]*vy + s2in[10]*vz;
}

// ---------------- point eval: feat(84) + latent(768) ----------------
__global__ __launch_bounds__(256) void eval_pts_k(
    const float* __restrict__ cf, const float* __restrict__ bf,
    const float* __restrict__ dirs, const float* __restrict__ vd, const float* __restrict__ vdl,
    const float* __restrict__ dall, int ndepth, int r0,
    const float* __restrict__ s2in, const float* __restrict__ l2c, const float* __restrict__ rK,
    float* __restrict__ feat, float* __restrict__ lat, float* __restrict__ vf)
{
  int p  = blockIdx.x;
  int rl = p / ndepth;
  int j  = p - rl*ndepth;
  int r  = r0 + rl;
  float dx = dirs[r*3+0], dy = dirs[r*3+1], dz = dirs[r*3+2];
  float d = dall ? dall[(size_t)rl*ndepth + j] : (((float)j + 0.5f)/32.0f)*100.0f;
  float px = dx*d, py = dy*d, pz = dz*d;                      // pts_cam
  float lx = s2in[0]*px + s2in[1]*py + s2in[2]*pz + s2in[3];  // pts_lid
  float ly = s2in[4]*px + s2in[5]*py + s2in[6]*pz + s2in[7];
  float lz = s2in[8]*px + s2in[9]*py + s2in[10]*pz + s2in[11];
  float ccx = l2c[0]*lx + l2c[1]*ly + l2c[2]*lz + l2c[3];     // pc
  float ccy = l2c[4]*lx + l2c[5]*ly + l2c[6]*lz + l2c[7];
  float ccz = l2c[8]*lx + l2c[9]*ly + l2c[10]*lz + l2c[11];
  float zs = fmaxf(ccz, 0.001f);
  float uu = rK[0]*ccx + rK[1]*ccy + rK[2]*ccz;
  float vv = rK[4]*ccx + rK[5]*ccy + rK[6]*ccz;
  float fu = uu/zs*(100.0f/1600.0f);
  float fv = vv/zs*(56.0f/900.0f);
  bool cvalid = (fu>=0.0f)&&(fu<=99.0f)&&(fv>=0.0f)&&(fv<=55.0f)&&(ccz>0.1f);
  float cfx0 = floorf(fu), cfy0 = floorf(fv);
  int cx0=iclampi((int)cfx0,0,99), cx1=iclampi(cx0+1,0,99);
  int cy0=iclampi((int)cfy0,0,55), cy1=iclampi(cy0+1,0,55);
  float cwx=fu-cfx0, cwy=fv-cfy0;
  float cw00=(1-cwx)*(1-cwy), cw01=cwx*(1-cwy), cw10=(1-cwx)*cwy, cw11=cwx*cwy;
  float bx = (lx+51.2f)/102.4f*199.0f;
  float by = (ly+51.2f)/102.4f*199.0f;
  bool bvalid = (bx>=0.0f)&&(bx<=199.0f)&&(by>=0.0f)&&(by<=199.0f);
  float bfx0=floorf(bx), bfy0=floorf(by);
  int bx0=iclampi((int)bfx0,0,199), bx1=iclampi(bx0+1,0,199);
  int by0=iclampi((int)bfy0,0,199), by1=iclampi(by0+1,0,199);
  float bwx=bx-bfx0, bwy=by-bfy0;
  float bw00=(1-bwx)*(1-bwy), bw01=bwx*(1-bwy), bw10=(1-bwx)*bwy, bw11=bwx*bwy;
  float vflag = (cvalid && bvalid) ? 1.0f : 0.0f;
  int t = threadIdx.x;
  { // cam channel t (256 total) -> latent[512..767]
    const float* cp = cf + (size_t)t*5600;
    float v = cw00*cp[cy0*100+cx0] + cw01*cp[cy0*100+cx1]
            + cw10*cp[cy1*100+cx0] + cw11*cp[cy1*100+cx1];
    lat[(size_t)p*768 + 512 + t] = v*vflag;
  }
  for (int ch = t; ch < 512; ch += 256){ // bev channels -> latent[0..511]
    const float* bp = bf + (size_t)ch*40000;
    float v = bw00*bp[by0*200+bx0] + bw01*bp[by0*200+bx1]
            + bw10*bp[by1*200+bx0] + bw11*bp[by1*200+bx1];
    lat[(size_t)p*768 + ch] = v*vflag;
  }
  if (t < 84){
    float plx = lx/51.2f, ply = ly/51.2f, plz = (lz+1.0f)/4.0f;
    float pcx = px/100.0f, pcy = py/100.0f, pcz = pz/100.0f;
    float vx=vd[r*3], vy=vd[r*3+1], vz=vd[r*3+2];
    float wx=vdl[r*3], wy=vdl[r*3+1], wz=vdl[r*3+2];
    float val;
    if (t < 39)      val = pe_elem(t, plx, ply, plz);
    else if (t < 42) val = (t==39)?wx:((t==40)?wy:wz);
    else if (t < 81) val = pe_elem(t-42, pcx, pcy, pcz);
    else             val = (t==81)?vx:((t==82)?vy:vz);
    feat[(size_t)p*84 + t] = val;
  }
  if (vf && t==0) vf[p] = vflag;
}

// ---------------- generic f32 tiled GEMM: C = [C +] (reluA?relu(A):A) @ B + bias [, reluOut] ----------------
#define BM 64
#define BN 64
#define BKT 16
template<int RELU_A, int ACC, int RELU_OUT>
__global__ __launch_bounds__(256) void gemm_k(const float* __restrict__ A, const float* __restrict__ B,
                                              const float* __restrict__ bias, float* __restrict__ C,
                                              int M, int N, int K)
{
  __shared__ float As[BKT][BM+1];
  __shared__ float Bs[BKT][BN];
  int tid = threadIdx.x;
  int tx = tid & 15, ty = tid >> 4;
  int row0 = blockIdx.y*BM, col0 = blockIdx.x*BN;
  float acc[4][4] = {};
  for (int kt = 0; kt < K; kt += BKT){
    { // A tile 64x16
      int c = tid & 15, rbase = tid >> 4;
      #pragma unroll
      for (int l=0;l<4;++l){
        int rr = rbase + 16*l;
        int gr = row0 + rr, gc = kt + c;
        float v = 0.0f;
        if (gr < M && gc < K) v = A[(size_t)gr*K + gc];
        if (RELU_A) v = fmaxf(v, 0.0f);
        As[c][rr] = v;
      }
    }
    { // B tile 16x64
      int c = tid & 63, rbase = tid >> 6;
      #pragma unroll
      for (int l=0;l<4;++l){
        int rr = rbase + 4*l;
        int gr = kt + rr, gc = col0 + c;
        float v = 0.0f;
        if (gr < K && gc < N) v = B[(size_t)gr*N + gc];
        Bs[rr][c] = v;
      }
    }
    __syncthreads();
    #pragma unroll
    for (int k=0;k<BKT;++k){
      float a[4], b[4];
      #pragma unroll
      for (int i=0;i<4;++i) a[i] = As[k][ty*4+i];
      #pragma unroll
      for (int jj=0;jj<4;++jj) b[jj] = Bs[k][tx*4+jj];
      #pragma unroll
      for (int i=0;i<4;++i)
        #pragma unroll
        for (int jj=0;jj<4;++jj)
          acc[i][jj] += a[i]*b[jj];
    }
    __syncthreads();
  }
  #pragma unroll
  for (int i=0;i<4;++i){
    int gr = row0 + ty*4 + i;
    if (gr >= M) continue;
    #pragma unroll
    for (int jj=0;jj<4;++jj){
      int gc = col0 + tx*4 + jj;
      if (gc >= N) continue;
      float v = acc[i][jj] + bias[gc];
      if (ACC) v += C[(size_t)gr*N + gc];
      if (RELU_OUT) v = fmaxf(v, 0.0f);
      C[(size_t)gr*N + gc] = v;
    }
  }
}

// ---------------- out layer: O = relu(X) @ W(512,dout) + b ----------------
__global__ void outlayer_k(const float* __restrict__ X, const float* __restrict__ W,
                           const float* __restrict__ b, float* __restrict__ O,
                           int M, int dout)
{
  int idx = blockIdx.x*blockDim.x + threadIdx.x;
  if (idx >= M*dout) return;
  int row = idx / dout, col = idx - row*dout;
  const float* xr = X + (size_t)row*512;
  float s = b[col];
  for (int k=0;k<512;++k) s += fmaxf(xr[k],0.0f) * W[k*dout + col];
  O[idx] = s;
}

// ---------------- coarse post: mu/std + sorted d_all ----------------
__global__ void coarse_post_k(const float* __restrict__ OUTB, float* __restrict__ MU,
                              float* __restrict__ STD, float* __restrict__ DALL,
                              int r0, int rn)
{
  int rl = blockIdx.x*blockDim.x + threadIdx.x;
  if (rl >= rn) return;
  int r = r0 + rl;
  float mu[4], sd[4];
  for (int g=0; g<4; ++g){
    float lg[8], sv[8], mx = -1e30f;
    for (int pp=0; pp<8; ++pp){
      int j = g*8+pp;
      lg[pp] = OUTB[((size_t)rl*32 + j)*2 + 0];
      sv[pp] = OUTB[((size_t)rl*32 + j)*2 + 1];
      mx = fmaxf(mx, lg[pp]);
    }
    float se = 0.0f;
    for (int pp=0; pp<8; ++pp){ lg[pp] = expf(lg[pp]-mx); se += lg[pp]; }
    float m=0.0f, s=0.0f;
    for (int pp=0; pp<8; ++pp){
      float wgt = lg[pp]/se;
      float du = (((float)(g*8+pp)+0.5f)/32.0f)*100.0f;
      m += wgt*du; s += wgt*sv[pp];
    }
    mu[g]=m; sd[g]=softplusf_(s)+0.1f;
    MU[r*4+g]=mu[g]; STD[r*4+g]=sd[g];
  }
  float da[64];
  for (int j=0;j<32;++j) da[j] = (((float)j+0.5f)/32.0f)*100.0f;
  for (int g=0; g<4; ++g)
    for (int pp=0; pp<8; ++pp){
      float off = -2.0f + (4.0f/7.0f)*(float)pp;
      float v = mu[g] + sd[g]*off;
      v = fminf(fmaxf(v, 0.5f), 100.0f);
      da[32 + g*8+pp] = v;
    }
  for (int i=1;i<64;++i){ float key=da[i]; int k=i-1;
    while (k>=0 && da[k]>key){ da[k+1]=da[k]; --k; } da[k+1]=key; }
  for (int j=0;j<64;++j) DALL[(size_t)rl*64+j] = da[j];
}

// ---------------- 3-channel image bilinear ----------------
__device__ __forceinline__ void bilin_img(const float* __restrict__ img, int H, int W,
                                          float u, float v, float* out3, bool* valid)
{
  *valid = (u>=0.0f)&&(u<=(float)(W-1))&&(v>=0.0f)&&(v<=(float)(H-1));
  float fx0=floorf(u), fy0=floorf(v);
  int x0=iclampi((int)fx0,0,W-1), x1=iclampi(x0+1,0,W-1);
  int y0=iclampi((int)fy0,0,H-1), y1=iclampi(y0+1,0,H-1);
  float wx=u-fx0, wy=v-fy0;
  float w00=(1-wx)*(1-wy), w01=wx*(1-wy), w10=(1-wx)*wy, w11=wx*wy;
  for (int ch=0; ch<3; ++ch){
    const float* p = img + (size_t)ch*H*W;
    out3[ch] = w00*p[y0*W+x0] + w01*p[y0*W+x1] + w10*p[y1*W+x0] + w11*p[y1*W+x1];
  }
}

// ---------------- render + losses per ray ----------------
__global__ void render_loss_k(const float* __restrict__ OUTB, const float* __restrict__ VF,
  const float* __restrict__ DALL, const float* __restrict__ MU, const float* __restrict__ STD,
  const float* __restrict__ dirs, const int* __restrict__ pix,
  const float* __restrict__ si, const float* __restrict__ ti,
  const float* __restrict__ s2tg, const float* __restrict__ sK,
  float* __restrict__ acc, int r0, int rn)
{
  int rl = blockIdx.x*blockDim.x + threadIdx.x;
  if (rl >= rn) return;
  int r = r0 + rl;
  float d[64], w[64];
  float T=1.0f, col0=0, col1=0, col2=0, depth=0, vsum=0;
  for (int j=0;j<64;++j){
    float dj = DALL[(size_t)rl*64+j];
    d[j]=dj;
    const float* o = OUTB + ((size_t)rl*64+j)*4;
    float vfp = VF[(size_t)rl*64+j];
    vsum += vfp;
    float sg = softplusf_(o[3])*vfp;
    float delta = (j<63)? (DALL[(size_t)rl*64+j+1]-dj) : 1000.0f;
    float alpha = 1.0f - expf(-sg*delta);
    float wj = alpha*T;
    w[j]=wj;
    col0 += wj*sigmoidf_(o[0]);
    col1 += wj*sigmoidf_(o[1]);
    col2 += wj*sigmoidf_(o[2]);
    depth += wj*dj;
    T *= (1.0f - alpha + 1e-10f);
  }
  float rvr = vsum/64.0f;
  float mu[4], sd[4];
  for (int g=0;g<4;++g){ mu[g]=MU[r*4+g]; sd[g]=STD[r*4+g]; }
  float srw[4]={0,0,0,0}, srwd[4]={0,0,0,0};
  for (int j=0;j<64;++j){
    float e[4], mx=-1e30f;
    for (int g=0;g<4;++g){ float dd=d[j]-mu[g]; e[g]=-dd*dd*0.125f; mx=fmaxf(mx,e[g]); }
    float se=0; for (int g=0;g<4;++g){ e[g]=expf(e[g]-mx); se+=e[g]; }
    for (int g=0;g<4;++g){ float rw=e[g]/se*w[j]+1e-8f; srw[g]+=rw; srwd[g]+=rw*d[j]; }
  }
  float smean[4]; for (int g=0;g<4;++g) smean[g]=srwd[g]/srw[g];
  float svar[4]={0,0,0,0};
  for (int j=0;j<64;++j){
    float e[4], mx=-1e30f;
    for (int g=0;g<4;++g){ float dd=d[j]-mu[g]; e[g]=-dd*dd*0.125f; mx=fmaxf(mx,e[g]); }
    float se=0; for (int g=0;g<4;++g){ e[g]=expf(e[g]-mx); se+=e[g]; }
    for (int g=0;g<4;++g){ float rw=e[g]/se*w[j]+1e-8f; float dd=d[j]-smean[g]; svar[g]+=rw*dd*dd; }
  }
  float klsum=0;
  for (int g=0;g<4;++g){
    float var = svar[g]/srw[g];
    float sstd = sqrtf(var + 1e-6f);
    float dm = mu[g]-smean[g];
    klsum += logf(sstd/sd[g]) + (sd[g]*sd[g] + dm*dm)/(2.0f*(var+1e-6f)) - 0.5f;
  }
  float mind=1e30f;
  for (int g=0;g<4;++g) mind = fminf(mind, fabsf(mu[g]-depth));
  int idx = pix[r];
  float x = (float)(idx % 400) * 2.0f;
  float y = (float)(idx / 400) * 2.0f;
  float csrc[3]; bool sval;
  bilin_img(si, 300, 800, x, y, csrc, &sval);
  if (!sval){ csrc[0]=0; csrc[1]=0; csrc[2]=0; }
  float csum = fabsf(csrc[0]-col0)+fabsf(csrc[1]-col1)+fabsf(csrc[2]-col2);
  // reprojection
  float dx=dirs[r*3], dy=dirs[r*3+1], dz=dirs[r*3+2];
  float px=dx*depth, py=dy*depth, pz=dz*depth;
  float tx=s2tg[0]*px+s2tg[1]*py+s2tg[2]*pz+s2tg[3];
  float ty=s2tg[4]*px+s2tg[5]*py+s2tg[6]*pz+s2tg[7];
  float tz=s2tg[8]*px+s2tg[9]*py+s2tg[10]*pz+s2tg[11];
  float zt=fmaxf(tz,0.001f);
  float uu=(sK[0]*tx+sK[1]*ty+sK[2]*tz)/zt;
  float vv=(sK[4]*tx+sK[5]*ty+sK[6]*tz)/zt;
  float pred[3]; bool tval;
  bilin_img(ti, 300, 800, uu, vv, pred, &tval);
  float tvf = tval?1.0f:0.0f;
  pred[0]*=tvf; pred[1]*=tvf; pred[2]*=tvf;
  float mask = (tval && (tz>0.1f) && (depth<30.0f)) ? 1.0f : 0.0f;
  float l1 = (fabsf(pred[0]-csrc[0])+fabsf(pred[1]-csrc[1])+fabsf(pred[2]-csrc[2]))*(1.0f/3.0f);
  atomicAdd(&acc[0], csum*rvr);
  atomicAdd(&acc[1], klsum);
  atomicAdd(&acc[2], mind);
  atomicAdd(&acc[3], l1*mask);
  atomicAdd(&acc[4], mask);
}

__global__ void zero_acc_k(float* a){ a[threadIdx.x] = 0.0f; }

__global__ void finalize_k(const float* __restrict__ acc, float* __restrict__ out){
  if (threadIdx.x==0 && blockIdx.x==0){
    float tot = 0.0f;
    for (int c=0;c<6;++c){
      const float* a = acc + c*8;
      float lc  = a[0] / 600.0f;   // mean over 200 rays x 3 ch
      float lkl = a[1] / 800.0f;   // mean over 200 x 4
      float ld  = a[2] / 200.0f;   // mean over 200
      float lr  = a[3] / (a[4] + 1e-6f);
      if (lr != lr) lr = 0.0f;
      tot += lc + lkl + 0.01f*ld + lr;
    }
    out[0] = tot / 6.0f;
  }
}

// ---------------- host-side MLP driver ----------------
static void run_mlp(hipStream_t stream, int M,
   const float* win, const float* bin, const float* wz, const float* bz,
   const float* w0, const float* b0, const float* w1, const float* b1,
   const float* wout, const float* bout, int dout,
   const float* FEAT, const float* LAT, float* X, float* H, float* OUTB)
{
  dim3 grid(512/BN, (M+BM-1)/BM);
  gemm_k<0,0,0><<<grid,256,0,stream>>>(FEAT, win, bin, X, M, 512, 84);
  for (int i=0;i<3;++i){
    gemm_k<0,1,0><<<grid,256,0,stream>>>(LAT, wz + (size_t)i*768*512, bz + i*512, X, M, 512, 768);
    gemm_k<1,0,1><<<grid,256,0,stream>>>(X,   w0 + (size_t)i*512*512, b0 + i*512, H, M, 512, 512);
    gemm_k<0,1,0><<<grid,256,0,stream>>>(H,   w1 + (size_t)i*512*512, b1 + i*512, X, M, 512, 512);
  }
  int tot = M*dout;
  outlayer_k<<<(tot+255)/256, 256, 0, stream>>>(X, wout, bout, OUTB, M, dout);
}

extern "C" void kernel_launch(void* const* d_in, const int* in_sizes, int n_in,
                              void* d_out, int out_size, void* d_ws, size_t ws_size,
                              hipStream_t stream) {
  (void)in_sizes; (void)n_in; (void)out_size;
  const float* cam_feat = (const float*)d_in[0];
  const float* bev_feat = (const float*)d_in[1];
  const float* src_imgs = (const float*)d_in[2];
  const float* tgt_imgs = (const float*)d_in[3];
  const float* rK   = (const float*)d_in[4];
  const float* sK   = (const float*)d_in[5];
  const float* l2c  = (const float*)d_in[6];
  const float* s2in = (const float*)d_in[7];
  const float* s2tg = (const float*)d_in[8];
  const int*   pix  = (const int*)d_in[9];
  const float* mlp_win = (const float*)d_in[10];
  const float* mlp_bin = (const float*)d_in[11];
  const float* mlp_wz  = (const float*)d_in[12];
  const float* mlp_bz  = (const float*)d_in[13];
  const float* mlp_w0  = (const float*)d_in[14];
  const float* mlp_b0  = (const float*)d_in[15];
  const float* mlp_w1  = (const float*)d_in[16];
  const float* mlp_b1  = (const float*)d_in[17];
  const float* mlp_wout= (const float*)d_in[18];
  const float* mlp_bout= (const float*)d_in[19];
  const float* g_win = (const float*)d_in[20];
  const float* g_bin = (const float*)d_in[21];
  const float* g_wz  = (const float*)d_in[22];
  const float* g_bz  = (const float*)d_in[23];
  const float* g_w0  = (const float*)d_in[24];
  const float* g_b0  = (const float*)d_in[25];
  const float* g_w1  = (const float*)d_in[26];
  const float* g_b1  = (const float*)d_in[27];
  const float* g_wout= (const float*)d_in[28];
  const float* g_bout= (const float*)d_in[29];

  float* ws = (float*)d_ws;
  size_t wsf = ws_size / 4;
  size_t off = 0;
  auto alloc = [&](size_t n){ size_t o = off; off += (n + 255) & ~(size_t)255; return o; };
  size_t oACC  = alloc(64);
  size_t oDIR  = alloc(600);
  size_t oVD   = alloc(600);
  size_t oVDL  = alloc(600);
  size_t oMU   = alloc(800);
  size_t oSTD  = alloc(800);
  size_t fixed = off;
  const size_t perray = (size_t)64*(84 + 768 + 512 + 512 + 4 + 1 + 1); // feat,lat,x,h,out,vf,dall
  int Rc = 200;
  if (fixed + (size_t)200*perray + 4096 > wsf){
    size_t avail = (wsf > fixed + 4096) ? (wsf - fixed - 4096) : perray;
    Rc = (int)(avail / perray);
    if (Rc < 1) Rc = 1;
    if (Rc > 200) Rc = 200;
  }
  size_t oDALL = alloc((size_t)Rc*64);
  size_t oFEAT = alloc((size_t)Rc*64*84);
  size_t oLAT  = alloc((size_t)Rc*64*768);
  size_t oX    = alloc((size_t)Rc*64*512);
  size_t oH    = alloc((size_t)Rc*64*512);
  size_t oOUT  = alloc((size_t)Rc*64*4);
  size_t oVF   = alloc((size_t)Rc*64);

  zero_acc_k<<<1,64,0,stream>>>(ws + oACC);

  for (int c=0; c<6; ++c){
    const float* cf   = cam_feat + (size_t)c*256*56*100;
    const float* si   = src_imgs + (size_t)c*3*300*800;
    const float* ti   = tgt_imgs + (size_t)c*3*300*800;
    const float* rKc  = rK  + c*16;
    const float* sKc  = sK  + c*16;
    const float* l2cc = l2c + c*16;
    const float* s2ic = s2in + c*16;
    const float* s2tc = s2tg + c*16;
    const int*   pxc  = pix + c*200;

    setup_rays_k<<<1,256,0,stream>>>(pxc, sKc, s2ic, ws+oDIR, ws+oVD, ws+oVDL);

    for (int r0=0; r0<200; r0+=Rc){
      int rn = (200 - r0 < Rc) ? (200 - r0) : Rc;
      int Pc = rn*32;
      // coarse eval + MLP (g)
      eval_pts_k<<<Pc,256,0,stream>>>(cf, bev_feat, ws+oDIR, ws+oVD, ws+oVDL,
          nullptr, 32, r0, s2ic, l2cc, rKc, ws+oFEAT, ws+oLAT, nullptr);
      run_mlp(stream, Pc, g_win,g_bin,g_wz,g_bz,g_w0,g_b0,g_w1,g_b1,g_wout,g_bout, 2,
              ws+oFEAT, ws+oLAT, ws+oX, ws+oH, ws+oOUT);
      int pb = (rn + 255)/256;
      coarse_post_k<<<pb,256,0,stream>>>(ws+oOUT, ws+oMU, ws+oSTD, ws+oDALL, r0, rn);
      // fine eval + MLP
      int Pf = rn*64;
      eval_pts_k<<<Pf,256,0,stream>>>(cf, bev_feat, ws+oDIR, ws+oVD, ws+oVDL,
          ws+oDALL, 64, r0, s2ic, l2cc, rKc, ws+oFEAT, ws+oLAT, ws+oVF);
      run_mlp(stream, Pf, mlp_win,mlp_bin,mlp_wz,mlp_bz,mlp_w0,mlp_b0,mlp_w1,mlp_b1,mlp_wout,mlp_bout, 4,
              ws+oFEAT, ws+oLAT, ws+oX, ws+oH, ws+oOUT);
      render_loss_k<<<pb,256,0,stream>>>(ws+oOUT, ws+oVF, ws+oDALL, ws+oMU, ws+oSTD,
          ws+oDIR, pxc, si, ti, s2tc, sKc, ws+oACC + (size_t)c*8, r0, rn);
    }
  }
  finalize_k<<<1,1,0,stream>>>(ws+oACC, (float*)d_out);
}

// Round 2
// 7068.115 us; speedup vs baseline: 2.4535x; 2.4535x over previous
//
#include <hip/hip_runtime.h>
#include <math.h>

typedef unsigned int uint32;
typedef short bf16x8 __attribute__((ext_vector_type(8)));
typedef float f32x4 __attribute__((ext_vector_type(4)));

__device__ __forceinline__ float sigmoidf_(float x){ return 1.0f/(1.0f+expf(-x)); }
__device__ __forceinline__ float softplusf_(float x){ return x>20.0f ? x : log1pf(expf(x)); }
__device__ __forceinline__ int iclampi(int v,int lo,int hi){ return v<lo?lo:(v>hi?hi:v); }

__device__ __forceinline__ float bf2f(uint32 u){ return __uint_as_float(u<<16); }
__device__ __forceinline__ unsigned short f2bf(float f){
  uint32 x = __float_as_uint(f);
  uint32 r = (x + 0x7fffu + ((x>>16)&1u)) >> 16;
  return (unsigned short)r;
}

__device__ __forceinline__ float pe_elem(int s, float vx, float vy, float vz){
  const float F0 = 3.14159265358979f;
  if (s < 3) return s==0?vx:(s==1?vy:vz);
  s -= 3;
  bool isCos = false;
  if (s >= 18){ s -= 18; isCos = true; }
  int fi = s/3, ci = s%3;
  float v = ci==0?vx:(ci==1?vy:vz);
  float f = F0 * (float)(1<<fi);
  return isCos ? cosf(f*v) : sinf(f*v);
}

// ---------------- transpose+convert: in f32 [C][S] -> out bf16 [S][Cout] (zero-pad c>=C) ----------------
__global__ __launch_bounds__(256) void transpose_cb_k(const float* __restrict__ in,
    unsigned short* __restrict__ out, int C, int S, int Cout,
    size_t inStride, size_t outStride)
{
  __shared__ float tile[32][33];
  int b = blockIdx.z;
  int s0 = blockIdx.x*32, c0 = blockIdx.y*32;
  int tx = threadIdx.x & 31, ty = threadIdx.x >> 5; // 32 x 8
  #pragma unroll
  for (int i=0;i<32;i+=8){
    int c = c0+ty+i, s = s0+tx;
    tile[ty+i][tx] = (c<C && s<S) ? in[(size_t)b*inStride + (size_t)c*S + s] : 0.0f;
  }
  __syncthreads();
  #pragma unroll
  for (int i=0;i<32;i+=8){
    int s = s0+ty+i, c = c0+tx;
    if (s<S && c<Cout) out[(size_t)b*outStride + (size_t)s*Cout + c] = f2bf(tile[tx][ty+i]);
  }
}

// ---------------- per-ray setup ----------------
__global__ void setup_rays_k(const int* __restrict__ pix, const float* __restrict__ sK,
                             const float* __restrict__ s2in,
                             float* __restrict__ dirs, float* __restrict__ vd,
                             float* __restrict__ vdl)
{
  int r = blockIdx.x*blockDim.x + threadIdx.x;
  if (r >= 200) return;
  float a=sK[0],b=sK[1],c=sK[2],d=sK[4],e=sK[5],f=sK[6],g=sK[8],h=sK[9],i=sK[10];
  float det = a*(e*i-f*h) - b*(d*i-f*g) + c*(d*h-e*g);
  float inv00=(e*i-f*h)/det, inv01=(c*h-b*i)/det, inv02=(b*f-c*e)/det;
  float inv10=(f*g-d*i)/det, inv11=(a*i-c*g)/det, inv12=(c*d-a*f)/det;
  float inv20=(d*h-e*g)/det, inv21=(b*g-a*h)/det, inv22=(a*e-b*d)/det;
  int idx = pix[r];
  float x = (float)(idx % 400) * 2.0f;
  float y = (float)(idx / 400) * 2.0f;
  float dx = inv00*x + inv01*y + inv02;
  float dy = inv10*x + inv11*y + inv12;
  float dz = inv20*x + inv21*y + inv22;
  dirs[r*3+0]=dx; dirs[r*3+1]=dy; dirs[r*3+2]=dz;
  float n = sqrtf(dx*dx+dy*dy+dz*dz);
  float vx=dx/n, vy=dy/n, vz=dz/n;
  vd[r*3+0]=vx; vd[r*3+1]=vy; vd[r*3+2]=vz;
  vdl[r*3+0]=s2in[0]*vx + s2in[1]*vy + s2in[2]*vz;
  vdl[r*3+1]=s2in[4]*vx + s2in[5]*vy + s2in[6]*vz;
  vdl[r*3+2]=s2in[8]*vx + s2in[9]*vy + s2in[10]*vz;
}

// ---------------- point eval: feat(bf16 [P][128]) + latent(bf16 [P][768]) ----------------
__global__ __launch_bounds__(256) void eval2_k(
    const unsigned short* __restrict__ camT,  // [5600][256] bf16
    const unsigned short* __restrict__ bevT,  // [40000][512] bf16
    const float* __restrict__ dirs, const float* __restrict__ vd, const float* __restrict__ vdl,
    const float* __restrict__ dall, int ndepth, int r0,
    const float* __restrict__ s2in, const float* __restrict__ l2c, const float* __restrict__ rK,
    unsigned short* __restrict__ feat, unsigned short* __restrict__ lat, float* __restrict__ vf)
{
  int p  = blockIdx.x;
  int rl = p / ndepth;
  int j  = p - rl*ndepth;
  int r  = r0 + rl;
  float dx = dirs[r*3+0], dy = dirs[r*3+1], dz = dirs[r*3+2];
  float d = dall ? dall[(size_t)rl*ndepth + j] : (((float)j + 0.5f)/32.0f)*100.0f;
  float px = dx*d, py = dy*d, pz = dz*d;
  float lx = s2in[0]*px + s2in[1]*py + s2in[2]*pz + s2in[3];
  float ly = s2in[4]*px + s2in[5]*py + s2in[6]*pz + s2in[7];
  float lz = s2in[8]*px + s2in[9]*py + s2in[10]*pz + s2in[11];
  float ccx = l2c[0]*lx + l2c[1]*ly + l2c[2]*lz + l2c[3];
  float ccy = l2c[4]*lx + l2c[5]*ly + l2c[6]*lz + l2c[7];
  float ccz = l2c[8]*lx + l2c[9]*ly + l2c[10]*lz + l2c[11];
  float zs = fmaxf(ccz, 0.001f);
  float uu = rK[0]*ccx + rK[1]*ccy + rK[2]*ccz;
  float vv = rK[4]*ccx + rK[5]*ccy + rK[6]*ccz;
  float fu = uu/zs*(100.0f/1600.0f);
  float fv = vv/zs*(56.0f/900.0f);
  bool cvalid = (fu>=0.0f)&&(fu<=99.0f)&&(fv>=0.0f)&&(fv<=55.0f)&&(ccz>0.1f);
  float cfx0 = floorf(fu), cfy0 = floorf(fv);
  int cx0=iclampi((int)cfx0,0,99), cx1=iclampi(cx0+1,0,99);
  int cy0=iclampi((int)cfy0,0,55), cy1=iclampi(cy0+1,0,55);
  float cwx=fu-cfx0, cwy=fv-cfy0;
  float cw00=(1-cwx)*(1-cwy), cw01=cwx*(1-cwy), cw10=(1-cwx)*cwy, cw11=cwx*cwy;
  float bx = (lx+51.2f)/102.4f*199.0f;
  float by = (ly+51.2f)/102.4f*199.0f;
  bool bvalid = (bx>=0.0f)&&(bx<=199.0f)&&(by>=0.0f)&&(by<=199.0f);
  float bfx0=floorf(bx), bfy0=floorf(by);
  int bx0=iclampi((int)bfx0,0,199), bx1=iclampi(bx0+1,0,199);
  int by0=iclampi((int)bfy0,0,199), by1=iclampi(by0+1,0,199);
  float bwx=bx-bfx0, bwy=by-bfy0;
  float bw00=(1-bwx)*(1-bwy), bw01=bwx*(1-bwy), bw10=(1-bwx)*bwy, bw11=bwx*bwy;
  float vflag = (cvalid && bvalid) ? 1.0f : 0.0f;
  int t = threadIdx.x;
  // bev gather: thread t -> channels 2t, 2t+1 (coalesced along channel)
  {
    size_t sb00 = (size_t)(by0*200+bx0)*512, sb01 = (size_t)(by0*200+bx1)*512;
    size_t sb10 = (size_t)(by1*200+bx0)*512, sb11 = (size_t)(by1*200+bx1)*512;
    uint32 u00 = ((const uint32*)(bevT + sb00))[t];
    uint32 u01 = ((const uint32*)(bevT + sb01))[t];
    uint32 u10 = ((const uint32*)(bevT + sb10))[t];
    uint32 u11 = ((const uint32*)(bevT + sb11))[t];
    float lo = bw00*bf2f(u00&0xffffu) + bw01*bf2f(u01&0xffffu) + bw10*bf2f(u10&0xffffu) + bw11*bf2f(u11&0xffffu);
    float hi = bw00*bf2f(u00>>16) + bw01*bf2f(u01>>16) + bw10*bf2f(u10>>16) + bw11*bf2f(u11>>16);
    lo *= vflag; hi *= vflag;
    ((uint32*)(lat + (size_t)p*768))[t] = (uint32)f2bf(lo) | ((uint32)f2bf(hi)<<16);
  }
  if (t < 128){ // cam gather: channels 2t,2t+1 -> latent[512..767]
    size_t sc00 = (size_t)(cy0*100+cx0)*256, sc01 = (size_t)(cy0*100+cx1)*256;
    size_t sc10 = (size_t)(cy1*100+cx0)*256, sc11 = (size_t)(cy1*100+cx1)*256;
    uint32 u00 = ((const uint32*)(camT + sc00))[t];
    uint32 u01 = ((const uint32*)(camT + sc01))[t];
    uint32 u10 = ((const uint32*)(camT + sc10))[t];
    uint32 u11 = ((const uint32*)(camT + sc11))[t];
    float lo = cw00*bf2f(u00&0xffffu) + cw01*bf2f(u01&0xffffu) + cw10*bf2f(u10&0xffffu) + cw11*bf2f(u11&0xffffu);
    float hi = cw00*bf2f(u00>>16) + cw01*bf2f(u01>>16) + cw10*bf2f(u10>>16) + cw11*bf2f(u11>>16);
    lo *= vflag; hi *= vflag;
    ((uint32*)(lat + (size_t)p*768))[256 + t] = (uint32)f2bf(lo) | ((uint32)f2bf(hi)<<16);
  }
  if (t < 128){ // feature vector, padded to 128 with zeros
    float val = 0.0f;
    if (t < 84){
      float plx = lx/51.2f, ply = ly/51.2f, plz = (lz+1.0f)/4.0f;
      float pcx = px/100.0f, pcy = py/100.0f, pcz = pz/100.0f;
      float vx=vd[r*3], vy=vd[r*3+1], vz=vd[r*3+2];
      float wx=vdl[r*3], wy=vdl[r*3+1], wz=vdl[r*3+2];
      if (t < 39)      val = pe_elem(t, plx, ply, plz);
      else if (t < 42) val = (t==39)?wx:((t==40)?wy:wz);
      else if (t < 81) val = pe_elem(t-42, pcx, pcy, pcz);
      else             val = (t==81)?vx:((t==82)?vy:vz);
    }
    feat[(size_t)p*128 + t] = f2bf(val);
  }
  if (vf && t==0) vf[p] = vflag;
}

// ---------------- MFMA bf16 GEMM: C[M][N] = [C +] act(A)[M][K] @ BT[N][K]^T + bias ----------------
// A_MODE: 0 = A bf16, 1 = A f32 with relu applied. ACC: C += . RELU_OUT / OUT_BF16 epilogue.
#define GBM 128
#define GBN 128
#define GBK 64
template<int A_MODE, int ACC, int RELU_OUT, int OUT_BF16>
__global__ __launch_bounds__(256) void mgemm_k(
    const void* __restrict__ Aptr, const unsigned short* __restrict__ BT,
    const float* __restrict__ bias, void* __restrict__ Cptr,
    int M, int N, int K)
{
  __shared__ unsigned short As[GBM*GBK];
  __shared__ unsigned short Bs[GBN*GBK];
  int tid = threadIdx.x;
  int row0 = blockIdx.y*GBM, col0 = blockIdx.x*GBN;
  int lane = tid & 63, wave = tid >> 6;
  int wm = wave >> 1, wn = wave & 1;   // 2x2 waves, each 64x64
  int l15 = lane & 15, l4 = lane >> 4;
  f32x4 acc[4][4];
  #pragma unroll
  for (int mi=0;mi<4;++mi)
    #pragma unroll
    for (int nj=0;nj<4;++nj){ f32x4 z = {0.f,0.f,0.f,0.f}; acc[mi][nj] = z; }

  for (int k0 = 0; k0 < K; k0 += GBK){
    // ---- stage A tile: 128 rows x 64 k (bf16), 16B chunks, XOR-swizzled ----
    if (A_MODE == 0){
      const unsigned short* Ab = (const unsigned short*)Aptr;
      #pragma unroll
      for (int it=0; it<4; ++it){
        int id = it*256 + tid;
        int rr = id >> 3, ch = id & 7;
        int gr = row0 + rr;
        bf16x8 val = {0,0,0,0,0,0,0,0};
        if (gr < M) val = *(const bf16x8*)(Ab + (size_t)gr*K + k0 + ch*8);
        *(bf16x8*)&As[rr*64 + ((ch ^ (rr&7))<<3)] = val;
      }
    } else {
      const float* Af = (const float*)Aptr;
      #pragma unroll
      for (int it=0; it<4; ++it){
        int id = it*256 + tid;
        int rr = id >> 3, ch = id & 7;
        int gr = row0 + rr;
        bf16x8 val = {0,0,0,0,0,0,0,0};
        if (gr < M){
          const f32x4* src = (const f32x4*)(Af + (size_t)gr*K + k0 + ch*8);
          f32x4 x0 = src[0], x1 = src[1];
          #pragma unroll
          for (int q=0;q<4;++q) val[q]   = (short)f2bf(fmaxf(x0[q],0.f));
          #pragma unroll
          for (int q=0;q<4;++q) val[4+q] = (short)f2bf(fmaxf(x1[q],0.f));
        }
        *(bf16x8*)&As[rr*64 + ((ch ^ (rr&7))<<3)] = val;
      }
    }
    // ---- stage B tile (BT rows are output-cols) ----
    #pragma unroll
    for (int it=0; it<4; ++it){
      int id = it*256 + tid;
      int rr = id >> 3, ch = id & 7;
      int gc = col0 + rr;
      bf16x8 val = {0,0,0,0,0,0,0,0};
      if (gc < N) val = *(const bf16x8*)(BT + (size_t)gc*K + k0 + ch*8);
      *(bf16x8*)&Bs[rr*64 + ((ch ^ (rr&7))<<3)] = val;
    }
    __syncthreads();
    #pragma unroll
    for (int ks=0; ks<2; ++ks){
      bf16x8 a[4], b[4];
      #pragma unroll
      for (int mi=0;mi<4;++mi){
        int row = wm*64 + mi*16 + l15;
        int sc = (ks*4 + l4) ^ (row&7);
        a[mi] = *(const bf16x8*)&As[row*64 + sc*8];
      }
      #pragma unroll
      for (int nj=0;nj<4;++nj){
        int colr = wn*64 + nj*16 + l15;
        int sc = (ks*4 + l4) ^ (colr&7);
        b[nj] = *(const bf16x8*)&Bs[colr*64 + sc*8];
      }
      #pragma unroll
      for (int mi=0;mi<4;++mi)
        #pragma unroll
        for (int nj=0;nj<4;++nj)
          acc[mi][nj] = __builtin_amdgcn_mfma_f32_16x16x32_bf16(a[mi], b[nj], acc[mi][nj], 0,0,0);
    }
    __syncthreads();
  }
  // ---- epilogue ----
  #pragma unroll
  for (int mi=0;mi<4;++mi){
    int gr0 = row0 + wm*64 + mi*16 + l4*4;
    #pragma unroll
    for (int nj=0;nj<4;++nj){
      int gc = col0 + wn*64 + nj*16 + l15;
      if (gc >= N) continue;
      float bv = bias[gc];
      #pragma unroll
      for (int i=0;i<4;++i){
        int gr = gr0 + i;
        if (gr >= M) continue;
        float v = acc[mi][nj][i] + bv;
        if (ACC) v += ((const float*)Cptr)[(size_t)gr*N + gc];
        if (RELU_OUT) v = fmaxf(v, 0.0f);
        if (OUT_BF16) ((unsigned short*)Cptr)[(size_t)gr*N + gc] = f2bf(v);
        else          ((float*)Cptr)[(size_t)gr*N + gc] = v;
      }
    }
  }
}

// ---------------- out layer: O = relu(X) @ W(512,dout) + b ----------------
__global__ void outlayer_k(const float* __restrict__ X, const float* __restrict__ W,
                           const float* __restrict__ b, float* __restrict__ O,
                           int M, int dout)
{
  int idx = blockIdx.x*blockDim.x + threadIdx.x;
  if (idx >= M*dout) return;
  int row = idx / dout, col = idx - row*dout;
  const float* xr = X + (size_t)row*512;
  float s = b[col];
  for (int k=0;k<512;++k) s += fmaxf(xr[k],0.0f) * W[k*dout + col];
  O[idx] = s;
}

// ---------------- coarse post: mu/std + sorted d_all ----------------
__global__ void coarse_post_k(const float* __restrict__ OUTB, float* __restrict__ MU,
                              float* __restrict__ STD, float* __restrict__ DALL,
                              int r0, int rn)
{
  int rl = blockIdx.x*blockDim.x + threadIdx.x;
  if (rl >= rn) return;
  int r = r0 + rl;
  float mu[4], sd[4];
  for (int g=0; g<4; ++g){
    float lg[8], sv[8], mx = -1e30f;
    for (int pp=0; pp<8; ++pp){
      int j = g*8+pp;
      lg[pp] = OUTB[((size_t)rl*32 + j)*2 + 0];
      sv[pp] = OUTB[((size_t)rl*32 + j)*2 + 1];
      mx = fmaxf(mx, lg[pp]);
    }
    float se = 0.0f;
    for (int pp=0; pp<8; ++pp){ lg[pp] = expf(lg[pp]-mx); se += lg[pp]; }
    float m=0.0f, s=0.0f;
    for (int pp=0; pp<8; ++pp){
      float wgt = lg[pp]/se;
      float du = (((float)(g*8+pp)+0.5f)/32.0f)*100.0f;
      m += wgt*du; s += wgt*sv[pp];
    }
    mu[g]=m; sd[g]=softplusf_(s)+0.1f;
    MU[r*4+g]=mu[g]; STD[r*4+g]=sd[g];
  }
  float da[64];
  for (int j=0;j<32;++j) da[j] = (((float)j+0.5f)/32.0f)*100.0f;
  for (int g=0; g<4; ++g)
    for (int pp=0; pp<8; ++pp){
      float off = -2.0f + (4.0f/7.0f)*(float)pp;
      float v = mu[g] + sd[g]*off;
      v = fminf(fmaxf(v, 0.5f), 100.0f);
      da[32 + g*8+pp] = v;
    }
  for (int i=1;i<64;++i){ float key=da[i]; int k=i-1;
    while (k>=0 && da[k]>key){ da[k+1]=da[k]; --k; } da[k+1]=key; }
  for (int j=0;j<64;++j) DALL[(size_t)rl*64+j] = da[j];
}

// ---------------- 3-channel image bilinear ----------------
__device__ __forceinline__ void bilin_img(const float* __restrict__ img, int H, int W,
                                          float u, float v, float* out3, bool* valid)
{
  *valid = (u>=0.0f)&&(u<=(float)(W-1))&&(v>=0.0f)&&(v<=(float)(H-1));
  float fx0=floorf(u), fy0=floorf(v);
  int x0=iclampi((int)fx0,0,W-1), x1=iclampi(x0+1,0,W-1);
  int y0=iclampi((int)fy0,0,H-1), y1=iclampi(y0+1,0,H-1);
  float wx=u-fx0, wy=v-fy0;
  float w00=(1-wx)*(1-wy), w01=wx*(1-wy), w10=(1-wx)*wy, w11=wx*wy;
  for (int ch=0; ch<3; ++ch){
    const float* p = img + (size_t)ch*H*W;
    out3[ch] = w00*p[y0*W+x0] + w01*p[y0*W+x1] + w10*p[y1*W+x0] + w11*p[y1*W+x1];
  }
}

// ---------------- render + losses per ray ----------------
__global__ void render_loss_k(const float* __restrict__ OUTB, const float* __restrict__ VF,
  const float* __restrict__ DALL, const float* __restrict__ MU, const float* __restrict__ STD,
  const float* __restrict__ dirs, const int* __restrict__ pix,
  const float* __restrict__ si, const float* __restrict__ ti,
  const float* __restrict__ s2tg, const float* __restrict__ sK,
  float* __restrict__ acc, int r0, int rn)
{
  int rl = blockIdx.x*blockDim.x + threadIdx.x;
  if (rl >= rn) return;
  int r = r0 + rl;
  float d[64], w[64];
  float T=1.0f, col0=0, col1=0, col2=0, depth=0, vsum=0;
  for (int j=0;j<64;++j){
    float dj = DALL[(size_t)rl*64+j];
    d[j]=dj;
    const float* o = OUTB + ((size_t)rl*64+j)*4;
    float vfp = VF[(size_t)rl*64+j];
    vsum += vfp;
    float sg = softplusf_(o[3])*vfp;
    float delta = (j<63)? (DALL[(size_t)rl*64+j+1]-dj) : 1000.0f;
    float alpha = 1.0f - expf(-sg*delta);
    float wj = alpha*T;
    w[j]=wj;
    col0 += wj*sigmoidf_(o[0]);
    col1 += wj*sigmoidf_(o[1]);
    col2 += wj*sigmoidf_(o[2]);
    depth += wj*dj;
    T *= (1.0f - alpha + 1e-10f);
  }
  float rvr = vsum/64.0f;
  float mu[4], sd[4];
  for (int g=0;g<4;++g){ mu[g]=MU[r*4+g]; sd[g]=STD[r*4+g]; }
  float srw[4]={0,0,0,0}, srwd[4]={0,0,0,0};
  for (int j=0;j<64;++j){
    float e[4], mx=-1e30f;
    for (int g=0;g<4;++g){ float dd=d[j]-mu[g]; e[g]=-dd*dd*0.125f; mx=fmaxf(mx,e[g]); }
    float se=0; for (int g=0;g<4;++g){ e[g]=expf(e[g]-mx); se+=e[g]; }
    for (int g=0;g<4;++g){ float rw=e[g]/se*w[j]+1e-8f; srw[g]+=rw; srwd[g]+=rw*d[j]; }
  }
  float smean[4]; for (int g=0;g<4;++g) smean[g]=srwd[g]/srw[g];
  float svar[4]={0,0,0,0};
  for (int j=0;j<64;++j){
    float e[4], mx=-1e30f;
    for (int g=0;g<4;++g){ float dd=d[j]-mu[g]; e[g]=-dd*dd*0.125f; mx=fmaxf(mx,e[g]); }
    float se=0; for (int g=0;g<4;++g){ e[g]=expf(e[g]-mx); se+=e[g]; }
    for (int g=0;g<4;++g){ float rw=e[g]/se*w[j]+1e-8f; float dd=d[j]-smean[g]; svar[g]+=rw*dd*dd; }
  }
  float klsum=0;
  for (int g=0;g<4;++g){
    float var = svar[g]/srw[g];
    float sstd = sqrtf(var + 1e-6f);
    float dm = mu[g]-smean[g];
    klsum += logf(sstd/sd[g]) + (sd[g]*sd[g] + dm*dm)/(2.0f*(var+1e-6f)) - 0.5f;
  }
  float mind=1e30f;
  for (int g=0;g<4;++g) mind = fminf(mind, fabsf(mu[g]-depth));
  int idx = pix[r];
  float x = (float)(idx % 400) * 2.0f;
  float y = (float)(idx / 400) * 2.0f;
  float csrc[3]; bool sval;
  bilin_img(si, 300, 800, x, y, csrc, &sval);
  if (!sval){ csrc[0]=0; csrc[1]=0; csrc[2]=0; }
  float csum = fabsf(csrc[0]-col0)+fabsf(csrc[1]-col1)+fabsf(csrc[2]-col2);
  float dx=dirs[r*3], dy=dirs[r*3+1], dz=dirs[r*3+2];
  float px=dx*depth, py=dy*depth, pz=dz*depth;
  float tx=s2tg[0]*px+s2tg[1]*py+s2tg[2]*pz+s2tg[3];
  float ty=s2tg[4]*px+s2tg[5]*py+s2tg[6]*pz+s2tg[7];
  float tz=s2tg[8]*px+s2tg[9]*py+s2tg[10]*pz+s2tg[11];
  float zt=fmaxf(tz,0.001f);
  float uu=(sK[0]*tx+sK[1]*ty+sK[2]*tz)/zt;
  float vv=(sK[4]*tx+sK[5]*ty+sK[6]*tz)/zt;
  float pred[3]; bool tval;
  bilin_img(ti, 300, 800, uu, vv, pred, &tval);
  float tvf = tval?1.0f:0.0f;
  pred[0]*=tvf; pred[1]*=tvf; pred[2]*=tvf;
  float mask = (tval && (tz>0.1f) && (depth<30.0f)) ? 1.0f : 0.0f;
  float l1 = (fabsf(pred[0]-csrc[0])+fabsf(pred[1]-csrc[1])+fabsf(pred[2]-csrc[2]))*(1.0f/3.0f);
  atomicAdd(&acc[0], csum*rvr);
  atomicAdd(&acc[1], klsum);
  atomicAdd(&acc[2], mind);
  atomicAdd(&acc[3], l1*mask);
  atomicAdd(&acc[4], mask);
}

__global__ void zero_acc_k(float* a){ a[threadIdx.x] = 0.0f; }

__global__ void finalize_k(const float* __restrict__ acc, float* __restrict__ out){
  if (threadIdx.x==0 && blockIdx.x==0){
    float tot = 0.0f;
    for (int c=0;c<6;++c){
      const float* a = acc + c*8;
      float lc  = a[0] / 600.0f;
      float lkl = a[1] / 800.0f;
      float ld  = a[2] / 200.0f;
      float lr  = a[3] / (a[4] + 1e-6f);
      if (lr != lr) lr = 0.0f;
      tot += lc + lkl + 0.01f*ld + lr;
    }
    out[0] = tot / 6.0f;
  }
}

// ---------------- host-side MLP driver (bf16 MFMA) ----------------
static void run_mlp2(hipStream_t stream, int M,
   const unsigned short* WinT, const float* bin,
   const unsigned short* WzT,  const float* bz,
   const unsigned short* W0T,  const float* b0,
   const unsigned short* W1T,  const float* b1,
   const float* wout, const float* bout, int dout,
   const unsigned short* FEAT, const unsigned short* LAT,
   float* X, unsigned short* H, float* OUTB)
{
  dim3 grid(512/GBN, (M+GBM-1)/GBM);
  mgemm_k<0,0,0,0><<<grid,256,0,stream>>>(FEAT, WinT, bin, X, M, 512, 128);
  for (int i=0;i<3;++i){
    mgemm_k<0,1,0,0><<<grid,256,0,stream>>>(LAT, WzT + (size_t)i*512*768, bz + i*512, X, M, 512, 768);
    mgemm_k<1,0,1,1><<<grid,256,0,stream>>>(X,   W0T + (size_t)i*512*512, b0 + i*512, H, M, 512, 512);
    mgemm_k<0,1,0,0><<<grid,256,0,stream>>>(H,   W1T + (size_t)i*512*512, b1 + i*512, X, M, 512, 512);
  }
  int tot = M*dout;
  outlayer_k<<<(tot+255)/256, 256, 0, stream>>>(X, wout, bout, OUTB, M, dout);
}

extern "C" void kernel_launch(void* const* d_in, const int* in_sizes, int n_in,
                              void* d_out, int out_size, void* d_ws, size_t ws_size,
                              hipStream_t stream) {
  (void)in_sizes; (void)n_in; (void)out_size;
  const float* cam_feat = (const float*)d_in[0];
  const float* bev_feat = (const float*)d_in[1];
  const float* src_imgs = (const float*)d_in[2];
  const float* tgt_imgs = (const float*)d_in[3];
  const float* rK   = (const float*)d_in[4];
  const float* sK   = (const float*)d_in[5];
  const float* l2c  = (const float*)d_in[6];
  const float* s2in = (const float*)d_in[7];
  const float* s2tg = (const float*)d_in[8];
  const int*   pix  = (const int*)d_in[9];
  const float* mlp_win = (const float*)d_in[10];
  const float* mlp_bin = (const float*)d_in[11];
  const float* mlp_wz  = (const float*)d_in[12];
  const float* mlp_bz  = (const float*)d_in[13];
  const float* mlp_w0  = (const float*)d_in[14];
  const float* mlp_b0  = (const float*)d_in[15];
  const float* mlp_w1  = (const float*)d_in[16];
  const float* mlp_b1  = (const float*)d_in[17];
  const float* mlp_wout= (const float*)d_in[18];
  const float* mlp_bout= (const float*)d_in[19];
  const float* g_win = (const float*)d_in[20];
  const float* g_bin = (const float*)d_in[21];
  const float* g_wz  = (const float*)d_in[22];
  const float* g_bz  = (const float*)d_in[23];
  const float* g_w0  = (const float*)d_in[24];
  const float* g_b0  = (const float*)d_in[25];
  const float* g_w1  = (const float*)d_in[26];
  const float* g_b1  = (const float*)d_in[27];
  const float* g_wout= (const float*)d_in[28];
  const float* g_bout= (const float*)d_in[29];

  char* base = (char*)d_ws;
  size_t off = 0;
  auto alloc = [&](size_t bytes)->char*{
    char* p = base + off;
    off = (off + bytes + 255) & ~(size_t)255;
    return p;
  };
  float* ACC  = (float*)alloc(64*4);
  float* DIR  = (float*)alloc(600*4);
  float* VD   = (float*)alloc(600*4);
  float* VDL  = (float*)alloc(600*4);
  float* MU   = (float*)alloc(800*4);
  float* STD  = (float*)alloc(800*4);
  unsigned short* bevT = (unsigned short*)alloc((size_t)40000*512*2);
  unsigned short* camT = (unsigned short*)alloc((size_t)6*5600*256*2);
  unsigned short* gWinT = (unsigned short*)alloc((size_t)512*128*2);
  unsigned short* mWinT = (unsigned short*)alloc((size_t)512*128*2);
  unsigned short* gWzT  = (unsigned short*)alloc((size_t)3*512*768*2);
  unsigned short* mWzT  = (unsigned short*)alloc((size_t)3*512*768*2);
  unsigned short* gW0T  = (unsigned short*)alloc((size_t)3*512*512*2);
  unsigned short* mW0T  = (unsigned short*)alloc((size_t)3*512*512*2);
  unsigned short* gW1T  = (unsigned short*)alloc((size_t)3*512*512*2);
  unsigned short* mW1T  = (unsigned short*)alloc((size_t)3*512*512*2);
  size_t fixed = off;
  const size_t perray = 256 + 16384 + 98304 + 131072 + 65536 + 1024 + 256; // bytes
  int Rc = 200;
  if (fixed + (size_t)200*perray + 8192 > ws_size){
    size_t avail = (ws_size > fixed + 8192) ? (ws_size - fixed - 8192) : perray;
    Rc = (int)(avail / perray);
    if (Rc < 1) Rc = 1;
    if (Rc > 200) Rc = 200;
  }
  float*          DALL = (float*)alloc((size_t)Rc*64*4);
  unsigned short* FEAT = (unsigned short*)alloc((size_t)Rc*64*128*2);
  unsigned short* LAT  = (unsigned short*)alloc((size_t)Rc*64*768*2);
  float*          X    = (float*)alloc((size_t)Rc*64*512*4);
  unsigned short* H    = (unsigned short*)alloc((size_t)Rc*64*512*2);
  float*          OUTB = (float*)alloc((size_t)Rc*64*4*4);
  float*          VF   = (float*)alloc((size_t)Rc*64*4);

  // ---- one-time transposes (re-run every call; deterministic) ----
  { dim3 g((40000+31)/32, (512+31)/32, 1);
    transpose_cb_k<<<g,256,0,stream>>>(bev_feat, bevT, 512, 40000, 512, 0, 0); }
  { dim3 g((5600+31)/32, (256+31)/32, 6);
    transpose_cb_k<<<g,256,0,stream>>>(cam_feat, camT, 256, 5600, 256, (size_t)256*5600, (size_t)5600*256); }
  { dim3 g((512+31)/32, (128+31)/32, 1);
    transpose_cb_k<<<g,256,0,stream>>>(g_win,  gWinT, 84, 512, 128, 0, 0);
    transpose_cb_k<<<g,256,0,stream>>>(mlp_win, mWinT, 84, 512, 128, 0, 0); }
  { dim3 g((512+31)/32, (768+31)/32, 3);
    transpose_cb_k<<<g,256,0,stream>>>(g_wz,  gWzT, 768, 512, 768, (size_t)768*512, (size_t)512*768);
    transpose_cb_k<<<g,256,0,stream>>>(mlp_wz, mWzT, 768, 512, 768, (size_t)768*512, (size_t)512*768); }
  { dim3 g((512+31)/32, (512+31)/32, 3);
    transpose_cb_k<<<g,256,0,stream>>>(g_w0,  gW0T, 512, 512, 512, (size_t)512*512, (size_t)512*512);
    transpose_cb_k<<<g,256,0,stream>>>(mlp_w0, mW0T, 512, 512, 512, (size_t)512*512, (size_t)512*512);
    transpose_cb_k<<<g,256,0,stream>>>(g_w1,  gW1T, 512, 512, 512, (size_t)512*512, (size_t)512*512);
    transpose_cb_k<<<g,256,0,stream>>>(mlp_w1, mW1T, 512, 512, 512, (size_t)512*512, (size_t)512*512); }

  zero_acc_k<<<1,64,0,stream>>>(ACC);

  for (int c=0; c<6; ++c){
    const unsigned short* cfT = camT + (size_t)c*5600*256;
    const float* si   = src_imgs + (size_t)c*3*300*800;
    const float* ti   = tgt_imgs + (size_t)c*3*300*800;
    const float* rKc  = rK  + c*16;
    const float* sKc  = sK  + c*16;
    const float* l2cc = l2c + c*16;
    const float* s2ic = s2in + c*16;
    const float* s2tc = s2tg + c*16;
    const int*   pxc  = pix + c*200;

    setup_rays_k<<<1,256,0,stream>>>(pxc, sKc, s2ic, DIR, VD, VDL);

    for (int r0=0; r0<200; r0+=Rc){
      int rn = (200 - r0 < Rc) ? (200 - r0) : Rc;
      int Pc = rn*32;
      eval2_k<<<Pc,256,0,stream>>>(cfT, bevT, DIR, VD, VDL,
          nullptr, 32, r0, s2ic, l2cc, rKc, FEAT, LAT, nullptr);
      run_mlp2(stream, Pc, gWinT,g_bin,gWzT,g_bz,gW0T,g_b0,gW1T,g_b1,g_wout,g_bout, 2,
               FEAT, LAT, X, H, OUTB);
      int pb = (rn + 255)/256;
      coarse_post_k<<<pb,256,0,stream>>>(OUTB, MU, STD, DALL, r0, rn);
      int Pf = rn*64;
      eval2_k<<<Pf,256,0,stream>>>(cfT, bevT, DIR, VD, VDL,
          DALL, 64, r0, s2ic, l2cc, rKc, FEAT, LAT, VF);
      run_mlp2(stream, Pf, mWinT,mlp_bin,mWzT,mlp_bz,mW0T,mlp_b0,mW1T,mlp_b1,mlp_wout,mlp_bout, 4,
               FEAT, LAT, X, H, OUTB);
      render_loss_k<<<pb,256,0,stream>>>(OUTB, VF, DALL, MU, STD,
          DIR, pxc, si, ti, s2tc, sKc, ACC + (size_t)c*8, r0, rn);
    }
  }
  finalize_k<<<1,1,0,stream>>>(ACC, (float*)d_out);
}

// Round 3
// 4061.436 us; speedup vs baseline: 4.2698x; 1.7403x over previous
//
#include <hip/hip_runtime.h>
#include <math.h>

typedef unsigned int uint32;
typedef short bf16x8 __attribute__((ext_vector_type(8)));
typedef float f32x4 __attribute__((ext_vector_type(4)));

__device__ __forceinline__ float sigmoidf_(float x){ return 1.0f/(1.0f+expf(-x)); }
__device__ __forceinline__ float softplusf_(float x){ return x>20.0f ? x : log1pf(expf(x)); }
__device__ __forceinline__ int iclampi(int v,int lo,int hi){ return v<lo?lo:(v>hi?hi:v); }

__device__ __forceinline__ float bf2f(uint32 u){ return __uint_as_float(u<<16); }
__device__ __forceinline__ unsigned short f2bf(float f){
  uint32 x = __float_as_uint(f);
  uint32 r = (x + 0x7fffu + ((x>>16)&1u)) >> 16;
  return (unsigned short)r;
}

__device__ __forceinline__ float pe_elem(int s, float vx, float vy, float vz){
  const float F0 = 3.14159265358979f;
  if (s < 3) return s==0?vx:(s==1?vy:vz);
  s -= 3;
  bool isCos = false;
  if (s >= 18){ s -= 18; isCos = true; }
  int fi = s/3, ci = s%3;
  float v = ci==0?vx:(ci==1?vy:vz);
  float f = F0 * (float)(1<<fi);
  return isCos ? cosf(f*v) : sinf(f*v);
}

// ---------------- transpose+convert: in f32 [C][S] -> out bf16 [S][Cout] (zero-pad c>=C) ----------------
__global__ __launch_bounds__(256) void transpose_cb_k(const float* __restrict__ in,
    unsigned short* __restrict__ out, int C, int S, int Cout,
    size_t inStride, size_t outStride)
{
  __shared__ float tile[32][33];
  int b = blockIdx.z;
  int s0 = blockIdx.x*32, c0 = blockIdx.y*32;
  int tx = threadIdx.x & 31, ty = threadIdx.x >> 5;
  #pragma unroll
  for (int i=0;i<32;i+=8){
    int c = c0+ty+i, s = s0+tx;
    tile[ty+i][tx] = (c<C && s<S) ? in[(size_t)b*inStride + (size_t)c*S + s] : 0.0f;
  }
  __syncthreads();
  #pragma unroll
  for (int i=0;i<32;i+=8){
    int s = s0+ty+i, c = c0+tx;
    if (s<S && c<Cout) out[(size_t)b*outStride + (size_t)s*Cout + c] = f2bf(tile[tx][ty+i]);
  }
}

// ---------------- per-ray setup: all 1200 rays ----------------
__global__ void setup_rays_k(const int* __restrict__ pix, const float* __restrict__ sK_all,
                             const float* __restrict__ s2in_all,
                             float* __restrict__ dirs, float* __restrict__ vd,
                             float* __restrict__ vdl)
{
  int r = blockIdx.x*blockDim.x + threadIdx.x;
  if (r >= 1200) return;
  int cam = r / 200;
  const float* sK = sK_all + cam*16;
  const float* s2in = s2in_all + cam*16;
  float a=sK[0],b=sK[1],c=sK[2],d=sK[4],e=sK[5],f=sK[6],g=sK[8],h=sK[9],i=sK[10];
  float det = a*(e*i-f*h) - b*(d*i-f*g) + c*(d*h-e*g);
  float inv00=(e*i-f*h)/det, inv01=(c*h-b*i)/det, inv02=(b*f-c*e)/det;
  float inv10=(f*g-d*i)/det, inv11=(a*i-c*g)/det, inv12=(c*d-a*f)/det;
  float inv20=(d*h-e*g)/det, inv21=(b*g-a*h)/det, inv22=(a*e-b*d)/det;
  int idx = pix[r];
  float x = (float)(idx % 400) * 2.0f;
  float y = (float)(idx / 400) * 2.0f;
  float dx = inv00*x + inv01*y + inv02;
  float dy = inv10*x + inv11*y + inv12;
  float dz = inv20*x + inv21*y + inv22;
  dirs[r*3+0]=dx; dirs[r*3+1]=dy; dirs[r*3+2]=dz;
  float n = sqrtf(dx*dx+dy*dy+dz*dz);
  float vx=dx/n, vy=dy/n, vz=dz/n;
  vd[r*3+0]=vx; vd[r*3+1]=vy; vd[r*3+2]=vz;
  vdl[r*3+0]=s2in[0]*vx + s2in[1]*vy + s2in[2]*vz;
  vdl[r*3+1]=s2in[4]*vx + s2in[5]*vy + s2in[6]*vz;
  vdl[r*3+2]=s2in[8]*vx + s2in[9]*vy + s2in[10]*vz;
}

// ---------------- point eval (cam-indexed): feat(bf16 [P][128]) + latent(bf16 [P][768]) ----------------
__global__ __launch_bounds__(256) void eval2_k(
    const unsigned short* __restrict__ camT,  // [6][5600][256] bf16
    const unsigned short* __restrict__ bevT,  // [40000][512] bf16
    const float* __restrict__ dirs, const float* __restrict__ vd, const float* __restrict__ vdl,
    const float* __restrict__ dall, int ndepth, int R0,
    const float* __restrict__ s2in_all, const float* __restrict__ l2c_all, const float* __restrict__ rK_all,
    unsigned short* __restrict__ feat, unsigned short* __restrict__ lat, float* __restrict__ vf)
{
  int p  = blockIdx.x;
  int rl = p / ndepth;
  int j  = p - rl*ndepth;
  int R  = R0 + rl;
  int cam = R / 200;
  const float* s2in = s2in_all + cam*16;
  const float* l2c  = l2c_all + cam*16;
  const float* rK   = rK_all + cam*16;
  float dx = dirs[R*3+0], dy = dirs[R*3+1], dz = dirs[R*3+2];
  float d = dall ? dall[(size_t)rl*ndepth + j] : (((float)j + 0.5f)/32.0f)*100.0f;
  float px = dx*d, py = dy*d, pz = dz*d;
  float lx = s2in[0]*px + s2in[1]*py + s2in[2]*pz + s2in[3];
  float ly = s2in[4]*px + s2in[5]*py + s2in[6]*pz + s2in[7];
  float lz = s2in[8]*px + s2in[9]*py + s2in[10]*pz + s2in[11];
  float ccx = l2c[0]*lx + l2c[1]*ly + l2c[2]*lz + l2c[3];
  float ccy = l2c[4]*lx + l2c[5]*ly + l2c[6]*lz + l2c[7];
  float ccz = l2c[8]*lx + l2c[9]*ly + l2c[10]*lz + l2c[11];
  float zs = fmaxf(ccz, 0.001f);
  float uu = rK[0]*ccx + rK[1]*ccy + rK[2]*ccz;
  float vv = rK[4]*ccx + rK[5]*ccy + rK[6]*ccz;
  float fu = uu/zs*(100.0f/1600.0f);
  float fv = vv/zs*(56.0f/900.0f);
  bool cvalid = (fu>=0.0f)&&(fu<=99.0f)&&(fv>=0.0f)&&(fv<=55.0f)&&(ccz>0.1f);
  float cfx0 = floorf(fu), cfy0 = floorf(fv);
  int cx0=iclampi((int)cfx0,0,99), cx1=iclampi(cx0+1,0,99);
  int cy0=iclampi((int)cfy0,0,55), cy1=iclampi(cy0+1,0,55);
  float cwx=fu-cfx0, cwy=fv-cfy0;
  float cw00=(1-cwx)*(1-cwy), cw01=cwx*(1-cwy), cw10=(1-cwx)*cwy, cw11=cwx*cwy;
  float bx = (lx+51.2f)/102.4f*199.0f;
  float by = (ly+51.2f)/102.4f*199.0f;
  bool bvalid = (bx>=0.0f)&&(bx<=199.0f)&&(by>=0.0f)&&(by<=199.0f);
  float bfx0=floorf(bx), bfy0=floorf(by);
  int bx0=iclampi((int)bfx0,0,199), bx1=iclampi(bx0+1,0,199);
  int by0=iclampi((int)bfy0,0,199), by1=iclampi(by0+1,0,199);
  float bwx=bx-bfx0, bwy=by-bfy0;
  float bw00=(1-bwx)*(1-bwy), bw01=bwx*(1-bwy), bw10=(1-bwx)*bwy, bw11=bwx*bwy;
  float vflag = (cvalid && bvalid) ? 1.0f : 0.0f;
  int t = threadIdx.x;
  {
    size_t sb00 = (size_t)(by0*200+bx0)*512, sb01 = (size_t)(by0*200+bx1)*512;
    size_t sb10 = (size_t)(by1*200+bx0)*512, sb11 = (size_t)(by1*200+bx1)*512;
    uint32 u00 = ((const uint32*)(bevT + sb00))[t];
    uint32 u01 = ((const uint32*)(bevT + sb01))[t];
    uint32 u10 = ((const uint32*)(bevT + sb10))[t];
    uint32 u11 = ((const uint32*)(bevT + sb11))[t];
    float lo = bw00*bf2f(u00&0xffffu) + bw01*bf2f(u01&0xffffu) + bw10*bf2f(u10&0xffffu) + bw11*bf2f(u11&0xffffu);
    float hi = bw00*bf2f(u00>>16) + bw01*bf2f(u01>>16) + bw10*bf2f(u10>>16) + bw11*bf2f(u11>>16);
    lo *= vflag; hi *= vflag;
    ((uint32*)(lat + (size_t)p*768))[t] = (uint32)f2bf(lo) | ((uint32)f2bf(hi)<<16);
  }
  if (t < 128){
    const unsigned short* cfT = camT + (size_t)cam*5600*256;
    size_t sc00 = (size_t)(cy0*100+cx0)*256, sc01 = (size_t)(cy0*100+cx1)*256;
    size_t sc10 = (size_t)(cy1*100+cx0)*256, sc11 = (size_t)(cy1*100+cx1)*256;
    uint32 u00 = ((const uint32*)(cfT + sc00))[t];
    uint32 u01 = ((const uint32*)(cfT + sc01))[t];
    uint32 u10 = ((const uint32*)(cfT + sc10))[t];
    uint32 u11 = ((const uint32*)(cfT + sc11))[t];
    float lo = cw00*bf2f(u00&0xffffu) + cw01*bf2f(u01&0xffffu) + cw10*bf2f(u10&0xffffu) + cw11*bf2f(u11&0xffffu);
    float hi = cw00*bf2f(u00>>16) + cw01*bf2f(u01>>16) + cw10*bf2f(u10>>16) + cw11*bf2f(u11>>16);
    lo *= vflag; hi *= vflag;
    ((uint32*)(lat + (size_t)p*768))[256 + t] = (uint32)f2bf(lo) | ((uint32)f2bf(hi)<<16);
  }
  if (t < 128){
    float val = 0.0f;
    if (t < 84){
      float plx = lx/51.2f, ply = ly/51.2f, plz = (lz+1.0f)/4.0f;
      float pcx = px/100.0f, pcy = py/100.0f, pcz = pz/100.0f;
      float vx=vd[R*3], vy=vd[R*3+1], vz=vd[R*3+2];
      float wx=vdl[R*3], wy=vdl[R*3+1], wz=vdl[R*3+2];
      if (t < 39)      val = pe_elem(t, plx, ply, plz);
      else if (t < 42) val = (t==39)?wx:((t==40)?wy:wz);
      else if (t < 81) val = pe_elem(t-42, pcx, pcy, pcz);
      else             val = (t==81)?vx:((t==82)?vy:vz);
    }
    feat[(size_t)p*128 + t] = f2bf(val);
  }
  if (vf && t==0) vf[p] = vflag;
}

// ---------------- MFMA bf16 GEMM ----------------
#define GBM 128
#define GBN 128
#define GBK 64
template<int A_MODE, int ACC, int RELU_OUT, int OUT_BF16>
__global__ __launch_bounds__(256) void mgemm_k(
    const void* __restrict__ Aptr, const unsigned short* __restrict__ BT,
    const float* __restrict__ bias, void* __restrict__ Cptr,
    int M, int N, int K)
{
  __shared__ unsigned short As[GBM*GBK];
  __shared__ unsigned short Bs[GBN*GBK];
  int tid = threadIdx.x;
  int row0 = blockIdx.y*GBM, col0 = blockIdx.x*GBN;
  int lane = tid & 63, wave = tid >> 6;
  int wm = wave >> 1, wn = wave & 1;
  int l15 = lane & 15, l4 = lane >> 4;
  f32x4 acc[4][4];
  #pragma unroll
  for (int mi=0;mi<4;++mi)
    #pragma unroll
    for (int nj=0;nj<4;++nj){ f32x4 z = {0.f,0.f,0.f,0.f}; acc[mi][nj] = z; }

  for (int k0 = 0; k0 < K; k0 += GBK){
    if (A_MODE == 0){
      const unsigned short* Ab = (const unsigned short*)Aptr;
      #pragma unroll
      for (int it=0; it<4; ++it){
        int id = it*256 + tid;
        int rr = id >> 3, ch = id & 7;
        int gr = row0 + rr;
        bf16x8 val = {0,0,0,0,0,0,0,0};
        if (gr < M) val = *(const bf16x8*)(Ab + (size_t)gr*K + k0 + ch*8);
        *(bf16x8*)&As[rr*64 + ((ch ^ (rr&7))<<3)] = val;
      }
    } else {
      const float* Af = (const float*)Aptr;
      #pragma unroll
      for (int it=0; it<4; ++it){
        int id = it*256 + tid;
        int rr = id >> 3, ch = id & 7;
        int gr = row0 + rr;
        bf16x8 val = {0,0,0,0,0,0,0,0};
        if (gr < M){
          const f32x4* src = (const f32x4*)(Af + (size_t)gr*K + k0 + ch*8);
          f32x4 x0 = src[0], x1 = src[1];
          #pragma unroll
          for (int q=0;q<4;++q) val[q]   = (short)f2bf(fmaxf(x0[q],0.f));
          #pragma unroll
          for (int q=0;q<4;++q) val[4+q] = (short)f2bf(fmaxf(x1[q],0.f));
        }
        *(bf16x8*)&As[rr*64 + ((ch ^ (rr&7))<<3)] = val;
      }
    }
    #pragma unroll
    for (int it=0; it<4; ++it){
      int id = it*256 + tid;
      int rr = id >> 3, ch = id & 7;
      int gc = col0 + rr;
      bf16x8 val = {0,0,0,0,0,0,0,0};
      if (gc < N) val = *(const bf16x8*)(BT + (size_t)gc*K + k0 + ch*8);
      *(bf16x8*)&Bs[rr*64 + ((ch ^ (rr&7))<<3)] = val;
    }
    __syncthreads();
    #pragma unroll
    for (int ks=0; ks<2; ++ks){
      bf16x8 a[4], b[4];
      #pragma unroll
      for (int mi=0;mi<4;++mi){
        int row = wm*64 + mi*16 + l15;
        int sc = (ks*4 + l4) ^ (row&7);
        a[mi] = *(const bf16x8*)&As[row*64 + sc*8];
      }
      #pragma unroll
      for (int nj=0;nj<4;++nj){
        int colr = wn*64 + nj*16 + l15;
        int sc = (ks*4 + l4) ^ (colr&7);
        b[nj] = *(const bf16x8*)&Bs[colr*64 + sc*8];
      }
      #pragma unroll
      for (int mi=0;mi<4;++mi)
        #pragma unroll
        for (int nj=0;nj<4;++nj)
          acc[mi][nj] = __builtin_amdgcn_mfma_f32_16x16x32_bf16(a[mi], b[nj], acc[mi][nj], 0,0,0);
    }
    __syncthreads();
  }
  #pragma unroll
  for (int mi=0;mi<4;++mi){
    int gr0 = row0 + wm*64 + mi*16 + l4*4;
    #pragma unroll
    for (int nj=0;nj<4;++nj){
      int gc = col0 + wn*64 + nj*16 + l15;
      if (gc >= N) continue;
      float bv = bias[gc];
      #pragma unroll
      for (int i=0;i<4;++i){
        int gr = gr0 + i;
        if (gr >= M) continue;
        float v = acc[mi][nj][i] + bv;
        if (ACC) v += ((const float*)Cptr)[(size_t)gr*N + gc];
        if (RELU_OUT) v = fmaxf(v, 0.0f);
        if (OUT_BF16) ((unsigned short*)Cptr)[(size_t)gr*N + gc] = f2bf(v);
        else          ((float*)Cptr)[(size_t)gr*N + gc] = v;
      }
    }
  }
}

// ---------------- out layer, wave per row: O[row][c] = relu(X[row]) . W[:,c] + b[c] ----------------
__global__ __launch_bounds__(256) void outlayer_w_k(const float* __restrict__ X,
    const float* __restrict__ W, const float* __restrict__ b, float* __restrict__ O,
    int M, int dout)
{
  int wid = threadIdx.x >> 6, lane = threadIdx.x & 63;
  int row = blockIdx.x*4 + wid;
  if (row >= M) return;
  const float* xr = X + (size_t)row*512;
  float s[4] = {0,0,0,0};
  for (int k=lane; k<512; k+=64){
    float xv = fmaxf(xr[k], 0.0f);
    #pragma unroll
    for (int c=0;c<4;++c)
      if (c < dout) s[c] += xv * W[(size_t)k*dout + c];
  }
  #pragma unroll
  for (int c=0;c<4;++c)
    #pragma unroll
    for (int m=32;m;m>>=1) s[c] += __shfl_xor(s[c], m, 64);
  if (lane == 0)
    for (int c=0;c<dout;++c) O[(size_t)row*dout + c] = s[c] + b[c];
}

// ---------------- coarse post ----------------
__global__ void coarse_post_k(const float* __restrict__ OUTB, float* __restrict__ MU,
                              float* __restrict__ STD, float* __restrict__ DALL,
                              int R0, int rn)
{
  int rl = blockIdx.x*blockDim.x + threadIdx.x;
  if (rl >= rn) return;
  int R = R0 + rl;
  float mu[4], sd[4];
  for (int g=0; g<4; ++g){
    float lg[8], sv[8], mx = -1e30f;
    for (int pp=0; pp<8; ++pp){
      int j = g*8+pp;
      lg[pp] = OUTB[((size_t)rl*32 + j)*2 + 0];
      sv[pp] = OUTB[((size_t)rl*32 + j)*2 + 1];
      mx = fmaxf(mx, lg[pp]);
    }
    float se = 0.0f;
    for (int pp=0; pp<8; ++pp){ lg[pp] = expf(lg[pp]-mx); se += lg[pp]; }
    float m=0.0f, s=0.0f;
    for (int pp=0; pp<8; ++pp){
      float wgt = lg[pp]/se;
      float du = (((float)(g*8+pp)+0.5f)/32.0f)*100.0f;
      m += wgt*du; s += wgt*sv[pp];
    }
    mu[g]=m; sd[g]=softplusf_(s)+0.1f;
    MU[R*4+g]=mu[g]; STD[R*4+g]=sd[g];
  }
  float da[64];
  for (int j=0;j<32;++j) da[j] = (((float)j+0.5f)/32.0f)*100.0f;
  for (int g=0; g<4; ++g)
    for (int pp=0; pp<8; ++pp){
      float off = -2.0f + (4.0f/7.0f)*(float)pp;
      float v = mu[g] + sd[g]*off;
      v = fminf(fmaxf(v, 0.5f), 100.0f);
      da[32 + g*8+pp] = v;
    }
  for (int i=1;i<64;++i){ float key=da[i]; int k=i-1;
    while (k>=0 && da[k]>key){ da[k+1]=da[k]; --k; } da[k+1]=key; }
  for (int j=0;j<64;++j) DALL[(size_t)rl*64+j] = da[j];
}

__device__ __forceinline__ void bilin_img(const float* __restrict__ img, int H, int W,
                                          float u, float v, float* out3, bool* valid)
{
  *valid = (u>=0.0f)&&(u<=(float)(W-1))&&(v>=0.0f)&&(v<=(float)(H-1));
  float fx0=floorf(u), fy0=floorf(v);
  int x0=iclampi((int)fx0,0,W-1), x1=iclampi(x0+1,0,W-1);
  int y0=iclampi((int)fy0,0,H-1), y1=iclampi(y0+1,0,H-1);
  float wx=u-fx0, wy=v-fy0;
  float w00=(1-wx)*(1-wy), w01=wx*(1-wy), w10=(1-wx)*wy, w11=wx*wy;
  for (int ch=0; ch<3; ++ch){
    const float* p = img + (size_t)ch*H*W;
    out3[ch] = w00*p[y0*W+x0] + w01*p[y0*W+x1] + w10*p[y1*W+x0] + w11*p[y1*W+x1];
  }
}

// ---------------- render + losses, one wave per ray ----------------
__global__ __launch_bounds__(256) void render_loss_w_k(
  const float* __restrict__ OUTB, const float* __restrict__ VF,
  const float* __restrict__ DALL, const float* __restrict__ MU, const float* __restrict__ STD,
  const float* __restrict__ dirs, const int* __restrict__ pix,
  const float* __restrict__ src_imgs, const float* __restrict__ tgt_imgs,
  const float* __restrict__ s2tg_all, const float* __restrict__ sK_all,
  float* __restrict__ acc, int R0, int rn)
{
  int wid = threadIdx.x >> 6, lane = threadIdx.x & 63;
  int rl = blockIdx.x*4 + wid;
  if (rl >= rn) return;
  int R = R0 + rl;
  int cam = R / 200;
  int j = lane;
  float dj = DALL[(size_t)rl*64 + j];
  float delta = (j<63) ? (DALL[(size_t)rl*64 + j + 1] - dj) : 1000.0f;
  f32x4 o = *(const f32x4*)(OUTB + ((size_t)rl*64 + j)*4);
  float vfp = VF[(size_t)rl*64 + j];
  float sg = softplusf_(o[3])*vfp;
  float alpha = 1.0f - expf(-sg*delta);
  // exclusive prefix product of (1-alpha+1e-10)
  float prod = 1.0f - alpha + 1e-10f;
  #pragma unroll
  for (int dstep=1; dstep<64; dstep<<=1){
    float v = __shfl_up(prod, dstep, 64);
    if (lane >= dstep) prod *= v;
  }
  float T = __shfl_up(prod, 1, 64);
  if (lane == 0) T = 1.0f;
  float w = alpha*T;
  // reductions: color(3), depth, vsum
  float c0 = w*sigmoidf_(o[0]), c1 = w*sigmoidf_(o[1]), c2 = w*sigmoidf_(o[2]);
  float dsum = w*dj, vs = vfp;
  #pragma unroll
  for (int m=32;m;m>>=1){
    c0 += __shfl_xor(c0,m,64); c1 += __shfl_xor(c1,m,64); c2 += __shfl_xor(c2,m,64);
    dsum += __shfl_xor(dsum,m,64); vs += __shfl_xor(vs,m,64);
  }
  float depth = dsum, rvr = vs/64.0f;
  // SOM responsibilities (per-lane softmax over 4 groups)
  float mu[4], sd[4];
  #pragma unroll
  for (int g=0;g<4;++g){ mu[g]=MU[R*4+g]; sd[g]=STD[R*4+g]; }
  float e[4], mx=-1e30f;
  #pragma unroll
  for (int g=0;g<4;++g){ float dd=dj-mu[g]; e[g]=-dd*dd*0.125f; mx=fmaxf(mx,e[g]); }
  float se=0;
  #pragma unroll
  for (int g=0;g<4;++g){ e[g]=expf(e[g]-mx); se+=e[g]; }
  float rw[4];
  #pragma unroll
  for (int g=0;g<4;++g) rw[g] = e[g]/se*w + 1e-8f;
  float srw[4], srwd[4];
  #pragma unroll
  for (int g=0;g<4;++g){ srw[g]=rw[g]; srwd[g]=rw[g]*dj; }
  #pragma unroll
  for (int m=32;m;m>>=1){
    #pragma unroll
    for (int g=0;g<4;++g){ srw[g]+=__shfl_xor(srw[g],m,64); srwd[g]+=__shfl_xor(srwd[g],m,64); }
  }
  float smean[4];
  #pragma unroll
  for (int g=0;g<4;++g) smean[g]=srwd[g]/srw[g];
  float sv[4];
  #pragma unroll
  for (int g=0;g<4;++g){ float dd=dj-smean[g]; sv[g]=rw[g]*dd*dd; }
  #pragma unroll
  for (int m=32;m;m>>=1){
    #pragma unroll
    for (int g=0;g<4;++g) sv[g]+=__shfl_xor(sv[g],m,64);
  }
  if (lane != 0) return;
  float klsum=0;
  #pragma unroll
  for (int g=0;g<4;++g){
    float var = sv[g]/srw[g];
    float sstd = sqrtf(var + 1e-6f);
    float dm = mu[g]-smean[g];
    klsum += logf(sstd/sd[g]) + (sd[g]*sd[g] + dm*dm)/(2.0f*(var+1e-6f)) - 0.5f;
  }
  float mind=1e30f;
  #pragma unroll
  for (int g=0;g<4;++g) mind = fminf(mind, fabsf(mu[g]-depth));
  const float* si = src_imgs + (size_t)cam*3*300*800;
  const float* ti = tgt_imgs + (size_t)cam*3*300*800;
  const float* s2tg = s2tg_all + cam*16;
  const float* sK = sK_all + cam*16;
  int idx = pix[R];
  float x = (float)(idx % 400) * 2.0f;
  float y = (float)(idx / 400) * 2.0f;
  float csrc[3]; bool sval;
  bilin_img(si, 300, 800, x, y, csrc, &sval);
  if (!sval){ csrc[0]=0; csrc[1]=0; csrc[2]=0; }
  float csum = fabsf(csrc[0]-c0)+fabsf(csrc[1]-c1)+fabsf(csrc[2]-c2);
  float dx=dirs[R*3], dy=dirs[R*3+1], dz=dirs[R*3+2];
  float px=dx*depth, py=dy*depth, pz=dz*depth;
  float tx=s2tg[0]*px+s2tg[1]*py+s2tg[2]*pz+s2tg[3];
  float ty=s2tg[4]*px+s2tg[5]*py+s2tg[6]*pz+s2tg[7];
  float tz=s2tg[8]*px+s2tg[9]*py+s2tg[10]*pz+s2tg[11];
  float zt=fmaxf(tz,0.001f);
  float uu=(sK[0]*tx+sK[1]*ty+sK[2]*tz)/zt;
  float vv=(sK[4]*tx+sK[5]*ty+sK[6]*tz)/zt;
  float pred[3]; bool tval;
  bilin_img(ti, 300, 800, uu, vv, pred, &tval);
  float tvf = tval?1.0f:0.0f;
  pred[0]*=tvf; pred[1]*=tvf; pred[2]*=tvf;
  float mask = (tval && (tz>0.1f) && (depth<30.0f)) ? 1.0f : 0.0f;
  float l1 = (fabsf(pred[0]-csrc[0])+fabsf(pred[1]-csrc[1])+fabsf(pred[2]-csrc[2]))*(1.0f/3.0f);
  float* a = acc + cam*8;
  atomicAdd(&a[0], csum*rvr);
  atomicAdd(&a[1], klsum);
  atomicAdd(&a[2], mind);
  atomicAdd(&a[3], l1*mask);
  atomicAdd(&a[4], mask);
}

__global__ void zero_acc_k(float* a){ a[threadIdx.x] = 0.0f; }

__global__ void finalize_k(const float* __restrict__ acc, float* __restrict__ out){
  if (threadIdx.x==0 && blockIdx.x==0){
    float tot = 0.0f;
    for (int c=0;c<6;++c){
      const float* a = acc + c*8;
      float lc  = a[0] / 600.0f;
      float lkl = a[1] / 800.0f;
      float ld  = a[2] / 200.0f;
      float lr  = a[3] / (a[4] + 1e-6f);
      if (lr != lr) lr = 0.0f;
      tot += lc + lkl + 0.01f*ld + lr;
    }
    out[0] = tot / 6.0f;
  }
}

// ---------------- host-side MLP driver ----------------
static void run_mlp2(hipStream_t stream, int M,
   const unsigned short* WinT, const float* bin,
   const unsigned short* WzT,  const float* bz,
   const unsigned short* W0T,  const float* b0,
   const unsigned short* W1T,  const float* b1,
   const float* wout, const float* bout, int dout,
   const unsigned short* FEAT, const unsigned short* LAT,
   float* X, unsigned short* H, float* OUTB)
{
  dim3 grid(512/GBN, (M+GBM-1)/GBM);
  mgemm_k<0,0,0,0><<<grid,256,0,stream>>>(FEAT, WinT, bin, X, M, 512, 128);
  for (int i=0;i<3;++i){
    mgemm_k<0,1,0,0><<<grid,256,0,stream>>>(LAT, WzT + (size_t)i*512*768, bz + i*512, X, M, 512, 768);
    mgemm_k<1,0,1,1><<<grid,256,0,stream>>>(X,   W0T + (size_t)i*512*512, b0 + i*512, H, M, 512, 512);
    mgemm_k<0,1,0,0><<<grid,256,0,stream>>>(H,   W1T + (size_t)i*512*512, b1 + i*512, X, M, 512, 512);
  }
  outlayer_w_k<<<(M+3)/4, 256, 0, stream>>>(X, wout, bout, OUTB, M, dout);
}

extern "C" void kernel_launch(void* const* d_in, const int* in_sizes, int n_in,
                              void* d_out, int out_size, void* d_ws, size_t ws_size,
                              hipStream_t stream) {
  (void)in_sizes; (void)n_in; (void)out_size;
  const float* cam_feat = (const float*)d_in[0];
  const float* bev_feat = (const float*)d_in[1];
  const float* src_imgs = (const float*)d_in[2];
  const float* tgt_imgs = (const float*)d_in[3];
  const float* rK   = (const float*)d_in[4];
  const float* sK   = (const float*)d_in[5];
  const float* l2c  = (const float*)d_in[6];
  const float* s2in = (const float*)d_in[7];
  const float* s2tg = (const float*)d_in[8];
  const int*   pix  = (const int*)d_in[9];
  const float* mlp_win = (const float*)d_in[10];
  const float* mlp_bin = (const float*)d_in[11];
  const float* mlp_wz  = (const float*)d_in[12];
  const float* mlp_bz  = (const float*)d_in[13];
  const float* mlp_w0  = (const float*)d_in[14];
  const float* mlp_b0  = (const float*)d_in[15];
  const float* mlp_w1  = (const float*)d_in[16];
  const float* mlp_b1  = (const float*)d_in[17];
  const float* mlp_wout= (const float*)d_in[18];
  const float* mlp_bout= (const float*)d_in[19];
  const float* g_win = (const float*)d_in[20];
  const float* g_bin = (const float*)d_in[21];
  const float* g_wz  = (const float*)d_in[22];
  const float* g_bz  = (const float*)d_in[23];
  const float* g_w0  = (const float*)d_in[24];
  const float* g_b0  = (const float*)d_in[25];
  const float* g_w1  = (const float*)d_in[26];
  const float* g_b1  = (const float*)d_in[27];
  const float* g_wout= (const float*)d_in[28];
  const float* g_bout= (const float*)d_in[29];

  char* base = (char*)d_ws;
  size_t off = 0;
  auto alloc = [&](size_t bytes)->char*{
    char* p = base + off;
    off = (off + bytes + 255) & ~(size_t)255;
    return p;
  };
  float* ACC  = (float*)alloc(64*4);
  float* DIR  = (float*)alloc(3600*4);
  float* VD   = (float*)alloc(3600*4);
  float* VDL  = (float*)alloc(3600*4);
  float* MU   = (float*)alloc(4800*4);
  float* STD  = (float*)alloc(4800*4);
  unsigned short* bevT = (unsigned short*)alloc((size_t)40000*512*2);
  unsigned short* camT = (unsigned short*)alloc((size_t)6*5600*256*2);
  unsigned short* gWinT = (unsigned short*)alloc((size_t)512*128*2);
  unsigned short* mWinT = (unsigned short*)alloc((size_t)512*128*2);
  unsigned short* gWzT  = (unsigned short*)alloc((size_t)3*512*768*2);
  unsigned short* mWzT  = (unsigned short*)alloc((size_t)3*512*768*2);
  unsigned short* gW0T  = (unsigned short*)alloc((size_t)3*512*512*2);
  unsigned short* mW0T  = (unsigned short*)alloc((size_t)3*512*512*2);
  unsigned short* gW1T  = (unsigned short*)alloc((size_t)3*512*512*2);
  unsigned short* mW1T  = (unsigned short*)alloc((size_t)3*512*512*2);
  size_t fixed = off;
  const size_t perray = 256 + 16384 + 98304 + 131072 + 65536 + 1024 + 256;
  int Rc = 1200;
  {
    size_t need = fixed + (size_t)1200*perray + 8192;
    if (need > ws_size){
      size_t avail = (ws_size > fixed + 8192) ? (ws_size - fixed - 8192) : perray;
      Rc = (int)(avail / perray);
      if (Rc < 1) Rc = 1;
      if (Rc > 1200) Rc = 1200;
    }
  }
  float*          DALL = (float*)alloc((size_t)Rc*64*4);
  unsigned short* FEAT = (unsigned short*)alloc((size_t)Rc*64*128*2);
  unsigned short* LAT  = (unsigned short*)alloc((size_t)Rc*64*768*2);
  float*          X    = (float*)alloc((size_t)Rc*64*512*4);
  unsigned short* H    = (unsigned short*)alloc((size_t)Rc*64*512*2);
  float*          OUTB = (float*)alloc((size_t)Rc*64*4*4);
  float*          VF   = (float*)alloc((size_t)Rc*64*4);

  // ---- transposes ----
  { dim3 g((40000+31)/32, (512+31)/32, 1);
    transpose_cb_k<<<g,256,0,stream>>>(bev_feat, bevT, 512, 40000, 512, 0, 0); }
  { dim3 g((5600+31)/32, (256+31)/32, 6);
    transpose_cb_k<<<g,256,0,stream>>>(cam_feat, camT, 256, 5600, 256, (size_t)256*5600, (size_t)5600*256); }
  { dim3 g((512+31)/32, (128+31)/32, 1);
    transpose_cb_k<<<g,256,0,stream>>>(g_win,  gWinT, 84, 512, 128, 0, 0);
    transpose_cb_k<<<g,256,0,stream>>>(mlp_win, mWinT, 84, 512, 128, 0, 0); }
  { dim3 g((512+31)/32, (768+31)/32, 3);
    transpose_cb_k<<<g,256,0,stream>>>(g_wz,  gWzT, 768, 512, 768, (size_t)768*512, (size_t)512*768);
    transpose_cb_k<<<g,256,0,stream>>>(mlp_wz, mWzT, 768, 512, 768, (size_t)768*512, (size_t)512*768); }
  { dim3 g((512+31)/32, (512+31)/32, 3);
    transpose_cb_k<<<g,256,0,stream>>>(g_w0,  gW0T, 512, 512, 512, (size_t)512*512, (size_t)512*512);
    transpose_cb_k<<<g,256,0,stream>>>(mlp_w0, mW0T, 512, 512, 512, (size_t)512*512, (size_t)512*512);
    transpose_cb_k<<<g,256,0,stream>>>(g_w1,  gW1T, 512, 512, 512, (size_t)512*512, (size_t)512*512);
    transpose_cb_k<<<g,256,0,stream>>>(mlp_w1, mW1T, 512, 512, 512, (size_t)512*512, (size_t)512*512); }

  zero_acc_k<<<1,64,0,stream>>>(ACC);
  setup_rays_k<<<5,256,0,stream>>>(pix, sK, s2in, DIR, VD, VDL);

  for (int R0=0; R0<1200; R0+=Rc){
    int rn = (1200 - R0 < Rc) ? (1200 - R0) : Rc;
    int Pc = rn*32;
    eval2_k<<<Pc,256,0,stream>>>(camT, bevT, DIR, VD, VDL,
        nullptr, 32, R0, s2in, l2c, rK, FEAT, LAT, nullptr);
    run_mlp2(stream, Pc, gWinT,g_bin,gWzT,g_bz,gW0T,g_b0,gW1T,g_b1,g_wout,g_bout, 2,
             FEAT, LAT, X, H, OUTB);
    coarse_post_k<<<(rn+255)/256,256,0,stream>>>(OUTB, MU, STD, DALL, R0, rn);
    int Pf = rn*64;
    eval2_k<<<Pf,256,0,stream>>>(camT, bevT, DIR, VD, VDL,
        DALL, 64, R0, s2in, l2c, rK, FEAT, LAT, VF);
    run_mlp2(stream, Pf, mWinT,mlp_bin,mWzT,mlp_bz,mW0T,mlp_b0,mW1T,mlp_b1,mlp_wout,mlp_bout, 4,
             FEAT, LAT, X, H, OUTB);
    render_loss_w_k<<<(rn+3)/4,256,0,stream>>>(OUTB, VF, DALL, MU, STD,
        DIR, pix, src_imgs, tgt_imgs, s2tg, sK, ACC, R0, rn);
  }
  finalize_k<<<1,1,0,stream>>>(ACC, (float*)d_out);
}

// Round 4
// 3087.015 us; speedup vs baseline: 5.6176x; 1.3157x over previous
//
#include <hip/hip_runtime.h>
#include <math.h>

typedef unsigned int uint32;
typedef short bf16x8 __attribute__((ext_vector_type(8)));
typedef float f32x4 __attribute__((ext_vector_type(4)));
typedef uint32 u32x4 __attribute__((ext_vector_type(4)));

__device__ __forceinline__ float sigmoidf_(float x){ return 1.0f/(1.0f+expf(-x)); }
__device__ __forceinline__ float softplusf_(float x){ return x>20.0f ? x : log1pf(expf(x)); }
__device__ __forceinline__ int iclampi(int v,int lo,int hi){ return v<lo?lo:(v>hi?hi:v); }

__device__ __forceinline__ float bf2f(uint32 u){ return __uint_as_float(u<<16); }
__device__ __forceinline__ unsigned short f2bf(float f){
  uint32 x = __float_as_uint(f);
  uint32 r = (x + 0x7fffu + ((x>>16)&1u)) >> 16;
  return (unsigned short)r;
}
__device__ __forceinline__ uint32 relu_bf16x2(uint32 u){
  uint32 lo = (u & 0x8000u) ? 0u : (u & 0xffffu);
  uint32 hi = (u & 0x80000000u) ? 0u : (u & 0xffff0000u);
  return lo | hi;
}

__device__ __forceinline__ float pe_elem(int s, float vx, float vy, float vz){
  const float F0 = 3.14159265358979f;
  if (s < 3) return s==0?vx:(s==1?vy:vz);
  s -= 3;
  bool isCos = false;
  if (s >= 18){ s -= 18; isCos = true; }
  int fi = s/3, ci = s%3;
  float v = ci==0?vx:(ci==1?vy:vz);
  float f = F0 * (float)(1<<fi);
  return isCos ? cosf(f*v) : sinf(f*v);
}

// ---- transpose+convert: in f32 [C][S] -> out bf16 [S][rowStride], cols c<Cout (zero-pad c>=C) ----
__global__ __launch_bounds__(256) void transpose_cb_k(const float* __restrict__ in,
    unsigned short* __restrict__ out, int C, int S, int Cout,
    size_t inStride, size_t outStride, int rowStride)
{
  __shared__ float tile[32][33];
  int b = blockIdx.z;
  int s0 = blockIdx.x*32, c0 = blockIdx.y*32;
  int tx = threadIdx.x & 31, ty = threadIdx.x >> 5;
  #pragma unroll
  for (int i=0;i<32;i+=8){
    int c = c0+ty+i, s = s0+tx;
    tile[ty+i][tx] = (c<C && s<S) ? in[(size_t)b*inStride + (size_t)c*S + s] : 0.0f;
  }
  __syncthreads();
  #pragma unroll
  for (int i=0;i<32;i+=8){
    int s = s0+ty+i, c = c0+tx;
    if (s<S && c<Cout) out[(size_t)b*outStride + (size_t)s*rowStride + c] = f2bf(tile[tx][ty+i]);
  }
}

// ---- combine biases: CB[w][n] = b1[i][n] + bz[i+1][n], w = {mlp i0, mlp i1, g i0, g i1} ----
__global__ void combine_bias_k(const float* __restrict__ m_b1, const float* __restrict__ m_bz,
                               const float* __restrict__ g_b1, const float* __restrict__ g_bz,
                               float* __restrict__ CB)
{
  int idx = blockIdx.x*blockDim.x + threadIdx.x;
  if (idx >= 2048) return;
  int w = idx >> 9, n = idx & 511;
  const float* b1 = (w < 2) ? m_b1 : g_b1;
  const float* bz = (w < 2) ? m_bz : g_bz;
  int i = w & 1;
  CB[idx] = b1[i*512 + n] + bz[(i+1)*512 + n];
}

// ---------------- per-ray setup: all 1200 rays ----------------
__global__ void setup_rays_k(const int* __restrict__ pix, const float* __restrict__ sK_all,
                             const float* __restrict__ s2in_all,
                             float* __restrict__ dirs, float* __restrict__ vd,
                             float* __restrict__ vdl)
{
  int r = blockIdx.x*blockDim.x + threadIdx.x;
  if (r >= 1200) return;
  int cam = r / 200;
  const float* sK = sK_all + cam*16;
  const float* s2in = s2in_all + cam*16;
  float a=sK[0],b=sK[1],c=sK[2],d=sK[4],e=sK[5],f=sK[6],g=sK[8],h=sK[9],i=sK[10];
  float det = a*(e*i-f*h) - b*(d*i-f*g) + c*(d*h-e*g);
  float inv00=(e*i-f*h)/det, inv01=(c*h-b*i)/det, inv02=(b*f-c*e)/det;
  float inv10=(f*g-d*i)/det, inv11=(a*i-c*g)/det, inv12=(c*d-a*f)/det;
  float inv20=(d*h-e*g)/det, inv21=(b*g-a*h)/det, inv22=(a*e-b*d)/det;
  int idx = pix[r];
  float x = (float)(idx % 400) * 2.0f;
  float y = (float)(idx / 400) * 2.0f;
  float dx = inv00*x + inv01*y + inv02;
  float dy = inv10*x + inv11*y + inv12;
  float dz = inv20*x + inv21*y + inv22;
  dirs[r*3+0]=dx; dirs[r*3+1]=dy; dirs[r*3+2]=dz;
  float n = sqrtf(dx*dx+dy*dy+dz*dz);
  float vx=dx/n, vy=dy/n, vz=dz/n;
  vd[r*3+0]=vx; vd[r*3+1]=vy; vd[r*3+2]=vz;
  vdl[r*3+0]=s2in[0]*vx + s2in[1]*vy + s2in[2]*vz;
  vdl[r*3+1]=s2in[4]*vx + s2in[5]*vy + s2in[6]*vz;
  vdl[r*3+2]=s2in[8]*vx + s2in[9]*vy + s2in[10]*vz;
}

// ---- point eval: feat(bf16 [P][128]) + CAT latent cols 512..1279 (bf16 [P][1280]) ----
__global__ __launch_bounds__(256) void eval2_k(
    const unsigned short* __restrict__ camT,  // [6][5600][256] bf16
    const unsigned short* __restrict__ bevT,  // [40000][512] bf16
    const float* __restrict__ dirs, const float* __restrict__ vd, const float* __restrict__ vdl,
    const float* __restrict__ dall, int ndepth, int R0,
    const float* __restrict__ s2in_all, const float* __restrict__ l2c_all, const float* __restrict__ rK_all,
    unsigned short* __restrict__ feat, unsigned short* __restrict__ cat, float* __restrict__ vf)
{
  int p  = blockIdx.x;
  int rl = p / ndepth;
  int j  = p - rl*ndepth;
  int R  = R0 + rl;
  int cam = R / 200;
  const float* s2in = s2in_all + cam*16;
  const float* l2c  = l2c_all + cam*16;
  const float* rK   = rK_all + cam*16;
  float dx = dirs[R*3+0], dy = dirs[R*3+1], dz = dirs[R*3+2];
  float d = dall ? dall[(size_t)rl*ndepth + j] : (((float)j + 0.5f)/32.0f)*100.0f;
  float px = dx*d, py = dy*d, pz = dz*d;
  float lx = s2in[0]*px + s2in[1]*py + s2in[2]*pz + s2in[3];
  float ly = s2in[4]*px + s2in[5]*py + s2in[6]*pz + s2in[7];
  float lz = s2in[8]*px + s2in[9]*py + s2in[10]*pz + s2in[11];
  float ccx = l2c[0]*lx + l2c[1]*ly + l2c[2]*lz + l2c[3];
  float ccy = l2c[4]*lx + l2c[5]*ly + l2c[6]*lz + l2c[7];
  float ccz = l2c[8]*lx + l2c[9]*ly + l2c[10]*lz + l2c[11];
  float zs = fmaxf(ccz, 0.001f);
  float uu = rK[0]*ccx + rK[1]*ccy + rK[2]*ccz;
  float vv = rK[4]*ccx + rK[5]*ccy + rK[6]*ccz;
  float fu = uu/zs*(100.0f/1600.0f);
  float fv = vv/zs*(56.0f/900.0f);
  bool cvalid = (fu>=0.0f)&&(fu<=99.0f)&&(fv>=0.0f)&&(fv<=55.0f)&&(ccz>0.1f);
  float cfx0 = floorf(fu), cfy0 = floorf(fv);
  int cx0=iclampi((int)cfx0,0,99), cx1=iclampi(cx0+1,0,99);
  int cy0=iclampi((int)cfy0,0,55), cy1=iclampi(cy0+1,0,55);
  float cwx=fu-cfx0, cwy=fv-cfy0;
  float cw00=(1-cwx)*(1-cwy), cw01=cwx*(1-cwy), cw10=(1-cwx)*cwy, cw11=cwx*cwy;
  float bx = (lx+51.2f)/102.4f*199.0f;
  float by = (ly+51.2f)/102.4f*199.0f;
  bool bvalid = (bx>=0.0f)&&(bx<=199.0f)&&(by>=0.0f)&&(by<=199.0f);
  float bfx0=floorf(bx), bfy0=floorf(by);
  int bx0=iclampi((int)bfx0,0,199), bx1=iclampi(bx0+1,0,199);
  int by0=iclampi((int)bfy0,0,199), by1=iclampi(by0+1,0,199);
  float bwx=bx-bfx0, bwy=by-bfy0;
  float bw00=(1-bwx)*(1-bwy), bw01=bwx*(1-bwy), bw10=(1-bwx)*bwy, bw11=bwx*bwy;
  float vflag = (cvalid && bvalid) ? 1.0f : 0.0f;
  int t = threadIdx.x;
  uint32* catrow = (uint32*)(cat + (size_t)p*1280);
  { // bev -> CAT cols 512..1023 (u32 idx 256..511)
    size_t sb00 = (size_t)(by0*200+bx0)*512, sb01 = (size_t)(by0*200+bx1)*512;
    size_t sb10 = (size_t)(by1*200+bx0)*512, sb11 = (size_t)(by1*200+bx1)*512;
    uint32 u00 = ((const uint32*)(bevT + sb00))[t];
    uint32 u01 = ((const uint32*)(bevT + sb01))[t];
    uint32 u10 = ((const uint32*)(bevT + sb10))[t];
    uint32 u11 = ((const uint32*)(bevT + sb11))[t];
    float lo = bw00*bf2f(u00&0xffffu) + bw01*bf2f(u01&0xffffu) + bw10*bf2f(u10&0xffffu) + bw11*bf2f(u11&0xffffu);
    float hi = bw00*bf2f(u00>>16) + bw01*bf2f(u01>>16) + bw10*bf2f(u10>>16) + bw11*bf2f(u11>>16);
    lo *= vflag; hi *= vflag;
    catrow[256 + t] = (uint32)f2bf(lo) | ((uint32)f2bf(hi)<<16);
  }
  if (t < 128){ // cam -> CAT cols 1024..1279 (u32 idx 512..639)
    const unsigned short* cfT = camT + (size_t)cam*5600*256;
    size_t sc00 = (size_t)(cy0*100+cx0)*256, sc01 = (size_t)(cy0*100+cx1)*256;
    size_t sc10 = (size_t)(cy1*100+cx0)*256, sc11 = (size_t)(cy1*100+cx1)*256;
    uint32 u00 = ((const uint32*)(cfT + sc00))[t];
    uint32 u01 = ((const uint32*)(cfT + sc01))[t];
    uint32 u10 = ((const uint32*)(cfT + sc10))[t];
    uint32 u11 = ((const uint32*)(cfT + sc11))[t];
    float lo = cw00*bf2f(u00&0xffffu) + cw01*bf2f(u01&0xffffu) + cw10*bf2f(u10&0xffffu) + cw11*bf2f(u11&0xffffu);
    float hi = cw00*bf2f(u00>>16) + cw01*bf2f(u01>>16) + cw10*bf2f(u10>>16) + cw11*bf2f(u11>>16);
    lo *= vflag; hi *= vflag;
    catrow[512 + t] = (uint32)f2bf(lo) | ((uint32)f2bf(hi)<<16);
  }
  if (t < 128){
    float val = 0.0f;
    if (t < 84){
      float plx = lx/51.2f, ply = ly/51.2f, plz = (lz+1.0f)/4.0f;
      float pcx = px/100.0f, pcy = py/100.0f, pcz = pz/100.0f;
      float vx=vd[R*3], vy=vd[R*3+1], vz=vd[R*3+2];
      float wx=vdl[R*3], wy=vdl[R*3+1], wz=vdl[R*3+2];
      if (t < 39)      val = pe_elem(t, plx, ply, plz);
      else if (t < 42) val = (t==39)?wx:((t==40)?wy:wz);
      else if (t < 81) val = pe_elem(t-42, pcx, pcy, pcz);
      else             val = (t==81)?vx:((t==82)?vy:vz);
    }
    feat[(size_t)p*128 + t] = f2bf(val);
  }
  if (vf && t==0) vf[p] = vflag;
}

// ---------------- MFMA bf16 GEMM: C = [C +] [relu](A) @ BT^T + bias; all bf16, C bf16 ----------------
#define GBM 128
#define GBN 64
#define GBK 64
template<int RELU_A, int ACC, int RELU_OUT>
__global__ __launch_bounds__(256,4) void mgemm_k(
    const unsigned short* __restrict__ A, int lda,
    const unsigned short* __restrict__ BT,
    const float* __restrict__ bias,
    unsigned short* __restrict__ C, int ldc,
    int M, int N, int K)
{
  __shared__ unsigned short As[GBM*GBK];  // 16 KB
  __shared__ unsigned short Bs[GBN*GBK];  // 8 KB
  int tid = threadIdx.x;
  int row0 = blockIdx.y*GBM, col0 = blockIdx.x*GBN;
  int lane = tid & 63, wave = tid >> 6;
  int wm = wave >> 1, wn = wave & 1;     // 2x2 waves: wave tile 64 rows x 32 cols
  int l15 = lane & 15, l4 = lane >> 4;
  f32x4 acc[4][2];
  #pragma unroll
  for (int mi=0;mi<4;++mi)
    #pragma unroll
    for (int nj=0;nj<2;++nj){ f32x4 z = {0.f,0.f,0.f,0.f}; acc[mi][nj] = z; }

  for (int k0 = 0; k0 < K; k0 += GBK){
    #pragma unroll
    for (int it=0; it<4; ++it){       // A tile: 128 rows x 8 chunks
      int id = it*256 + tid;
      int rr = id >> 3, ch = id & 7;
      int gr = row0 + rr;
      bf16x8 val = {0,0,0,0,0,0,0,0};
      if (gr < M) val = *(const bf16x8*)(A + (size_t)gr*lda + k0 + ch*8);
      if (RELU_A){
        u32x4 u = *(u32x4*)&val;
        #pragma unroll
        for (int q=0;q<4;++q) u[q] = relu_bf16x2(u[q]);
        val = *(bf16x8*)&u;
      }
      *(bf16x8*)&As[rr*64 + ((ch ^ (rr&7))<<3)] = val;
    }
    #pragma unroll
    for (int it=0; it<2; ++it){       // B tile: 64 rows x 8 chunks
      int id = it*256 + tid;
      int rr = id >> 3, ch = id & 7;
      int gc = col0 + rr;
      bf16x8 val = {0,0,0,0,0,0,0,0};
      if (gc < N) val = *(const bf16x8*)(BT + (size_t)gc*K + k0 + ch*8);
      *(bf16x8*)&Bs[rr*64 + ((ch ^ (rr&7))<<3)] = val;
    }
    __syncthreads();
    #pragma unroll
    for (int ks=0; ks<2; ++ks){
      bf16x8 a[4], b[2];
      #pragma unroll
      for (int mi=0;mi<4;++mi){
        int row = wm*64 + mi*16 + l15;
        int sc = (ks*4 + l4) ^ (row&7);
        a[mi] = *(const bf16x8*)&As[row*64 + sc*8];
      }
      #pragma unroll
      for (int nj=0;nj<2;++nj){
        int colr = wn*32 + nj*16 + l15;
        int sc = (ks*4 + l4) ^ (colr&7);
        b[nj] = *(const bf16x8*)&Bs[colr*64 + sc*8];
      }
      #pragma unroll
      for (int mi=0;mi<4;++mi)
        #pragma unroll
        for (int nj=0;nj<2;++nj)
          acc[mi][nj] = __builtin_amdgcn_mfma_f32_16x16x32_bf16(a[mi], b[nj], acc[mi][nj], 0,0,0);
    }
    __syncthreads();
  }
  #pragma unroll
  for (int mi=0;mi<4;++mi){
    int gr0 = row0 + wm*64 + mi*16 + l4*4;
    #pragma unroll
    for (int nj=0;nj<2;++nj){
      int gc = col0 + wn*32 + nj*16 + l15;
      if (gc >= N) continue;
      float bv = bias[gc];
      #pragma unroll
      for (int i=0;i<4;++i){
        int gr = gr0 + i;
        if (gr >= M) continue;
        float v = acc[mi][nj][i] + bv;
        if (ACC) v += bf2f((uint32)C[(size_t)gr*ldc + gc]);
        if (RELU_OUT) v = fmaxf(v, 0.0f);
        C[(size_t)gr*ldc + gc] = f2bf(v);
      }
    }
  }
}

// ---------------- out layer, wave per row: O[row][c] = relu(X[row]) . W[:,c] + b[c] ----------------
__global__ __launch_bounds__(256) void outlayer_w_k(const unsigned short* __restrict__ X,
    const float* __restrict__ W, const float* __restrict__ b, float* __restrict__ O,
    int M, int dout)
{
  int wid = threadIdx.x >> 6, lane = threadIdx.x & 63;
  int row = blockIdx.x*4 + wid;
  if (row >= M) return;
  const unsigned short* xr = X + (size_t)row*512;
  float s[4] = {0,0,0,0};
  for (int k=lane; k<512; k+=64){
    float xv = fmaxf(bf2f((uint32)xr[k]), 0.0f);
    #pragma unroll
    for (int c=0;c<4;++c)
      if (c < dout) s[c] += xv * W[(size_t)k*dout + c];
  }
  #pragma unroll
  for (int c=0;c<4;++c)
    #pragma unroll
    for (int m=32;m;m>>=1) s[c] += __shfl_xor(s[c], m, 64);
  if (lane == 0)
    for (int c=0;c<dout;++c) O[(size_t)row*dout + c] = s[c] + b[c];
}

// ---------------- coarse post ----------------
__global__ void coarse_post_k(const float* __restrict__ OUTB, float* __restrict__ MU,
                              float* __restrict__ STD, float* __restrict__ DALL,
                              int R0, int rn)
{
  int rl = blockIdx.x*blockDim.x + threadIdx.x;
  if (rl >= rn) return;
  int R = R0 + rl;
  float mu[4], sd[4];
  for (int g=0; g<4; ++g){
    float lg[8], sv[8], mx = -1e30f;
    for (int pp=0; pp<8; ++pp){
      int j = g*8+pp;
      lg[pp] = OUTB[((size_t)rl*32 + j)*2 + 0];
      sv[pp] = OUTB[((size_t)rl*32 + j)*2 + 1];
      mx = fmaxf(mx, lg[pp]);
    }
    float se = 0.0f;
    for (int pp=0; pp<8; ++pp){ lg[pp] = expf(lg[pp]-mx); se += lg[pp]; }
    float m=0.0f, s=0.0f;
    for (int pp=0; pp<8; ++pp){
      float wgt = lg[pp]/se;
      float du = (((float)(g*8+pp)+0.5f)/32.0f)*100.0f;
      m += wgt*du; s += wgt*sv[pp];
    }
    mu[g]=m; sd[g]=softplusf_(s)+0.1f;
    MU[R*4+g]=mu[g]; STD[R*4+g]=sd[g];
  }
  float da[64];
  for (int j=0;j<32;++j) da[j] = (((float)j+0.5f)/32.0f)*100.0f;
  for (int g=0; g<4; ++g)
    for (int pp=0; pp<8; ++pp){
      float off = -2.0f + (4.0f/7.0f)*(float)pp;
      float v = mu[g] + sd[g]*off;
      v = fminf(fmaxf(v, 0.5f), 100.0f);
      da[32 + g*8+pp] = v;
    }
  for (int i=1;i<64;++i){ float key=da[i]; int k=i-1;
    while (k>=0 && da[k]>key){ da[k+1]=da[k]; --k; } da[k+1]=key; }
  for (int j=0;j<64;++j) DALL[(size_t)rl*64+j] = da[j];
}

__device__ __forceinline__ void bilin_img(const float* __restrict__ img, int H, int W,
                                          float u, float v, float* out3, bool* valid)
{
  *valid = (u>=0.0f)&&(u<=(float)(W-1))&&(v>=0.0f)&&(v<=(float)(H-1));
  float fx0=floorf(u), fy0=floorf(v);
  int x0=iclampi((int)fx0,0,W-1), x1=iclampi(x0+1,0,W-1);
  int y0=iclampi((int)fy0,0,H-1), y1=iclampi(y0+1,0,H-1);
  float wx=u-fx0, wy=v-fy0;
  float w00=(1-wx)*(1-wy), w01=wx*(1-wy), w10=(1-wx)*wy, w11=wx*wy;
  for (int ch=0; ch<3; ++ch){
    const float* p = img + (size_t)ch*H*W;
    out3[ch] = w00*p[y0*W+x0] + w01*p[y0*W+x1] + w10*p[y1*W+x0] + w11*p[y1*W+x1];
  }
}

// ---------------- render + losses, one wave per ray ----------------
__global__ __launch_bounds__(256) void render_loss_w_k(
  const float* __restrict__ OUTB, const float* __restrict__ VF,
  const float* __restrict__ DALL, const float* __restrict__ MU, const float* __restrict__ STD,
  const float* __restrict__ dirs, const int* __restrict__ pix,
  const float* __restrict__ src_imgs, const float* __restrict__ tgt_imgs,
  const float* __restrict__ s2tg_all, const float* __restrict__ sK_all,
  float* __restrict__ acc, int R0, int rn)
{
  int wid = threadIdx.x >> 6, lane = threadIdx.x & 63;
  int rl = blockIdx.x*4 + wid;
  if (rl >= rn) return;
  int R = R0 + rl;
  int cam = R / 200;
  int j = lane;
  float dj = DALL[(size_t)rl*64 + j];
  float delta = (j<63) ? (DALL[(size_t)rl*64 + j + 1] - dj) : 1000.0f;
  f32x4 o = *(const f32x4*)(OUTB + ((size_t)rl*64 + j)*4);
  float vfp = VF[(size_t)rl*64 + j];
  float sg = softplusf_(o[3])*vfp;
  float alpha = 1.0f - expf(-sg*delta);
  float prod = 1.0f - alpha + 1e-10f;
  #pragma unroll
  for (int dstep=1; dstep<64; dstep<<=1){
    float v = __shfl_up(prod, dstep, 64);
    if (lane >= dstep) prod *= v;
  }
  float T = __shfl_up(prod, 1, 64);
  if (lane == 0) T = 1.0f;
  float w = alpha*T;
  float c0 = w*sigmoidf_(o[0]), c1 = w*sigmoidf_(o[1]), c2 = w*sigmoidf_(o[2]);
  float dsum = w*dj, vs = vfp;
  #pragma unroll
  for (int m=32;m;m>>=1){
    c0 += __shfl_xor(c0,m,64); c1 += __shfl_xor(c1,m,64); c2 += __shfl_xor(c2,m,64);
    dsum += __shfl_xor(dsum,m,64); vs += __shfl_xor(vs,m,64);
  }
  float depth = dsum, rvr = vs/64.0f;
  float mu[4], sd[4];
  #pragma unroll
  for (int g=0;g<4;++g){ mu[g]=MU[R*4+g]; sd[g]=STD[R*4+g]; }
  float e[4], mx=-1e30f;
  #pragma unroll
  for (int g=0;g<4;++g){ float dd=dj-mu[g]; e[g]=-dd*dd*0.125f; mx=fmaxf(mx,e[g]); }
  float se=0;
  #pragma unroll
  for (int g=0;g<4;++g){ e[g]=expf(e[g]-mx); se+=e[g]; }
  float rw[4];
  #pragma unroll
  for (int g=0;g<4;++g) rw[g] = e[g]/se*w + 1e-8f;
  float srw[4], srwd[4];
  #pragma unroll
  for (int g=0;g<4;++g){ srw[g]=rw[g]; srwd[g]=rw[g]*dj; }
  #pragma unroll
  for (int m=32;m;m>>=1){
    #pragma unroll
    for (int g=0;g<4;++g){ srw[g]+=__shfl_xor(srw[g],m,64); srwd[g]+=__shfl_xor(srwd[g],m,64); }
  }
  float smean[4];
  #pragma unroll
  for (int g=0;g<4;++g) smean[g]=srwd[g]/srw[g];
  float sv[4];
  #pragma unroll
  for (int g=0;g<4;++g){ float dd=dj-smean[g]; sv[g]=rw[g]*dd*dd; }
  #pragma unroll
  for (int m=32;m;m>>=1){
    #pragma unroll
    for (int g=0;g<4;++g) sv[g]+=__shfl_xor(sv[g],m,64);
  }
  if (lane != 0) return;
  float klsum=0;
  #pragma unroll
  for (int g=0;g<4;++g){
    float var = sv[g]/srw[g];
    float sstd = sqrtf(var + 1e-6f);
    float dm = mu[g]-smean[g];
    klsum += logf(sstd/sd[g]) + (sd[g]*sd[g] + dm*dm)/(2.0f*(var+1e-6f)) - 0.5f;
  }
  float mind=1e30f;
  #pragma unroll
  for (int g=0;g<4;++g) mind = fminf(mind, fabsf(mu[g]-depth));
  const float* si = src_imgs + (size_t)cam*3*300*800;
  const float* ti = tgt_imgs + (size_t)cam*3*300*800;
  const float* s2tg = s2tg_all + cam*16;
  const float* sK = sK_all + cam*16;
  int idx = pix[R];
  float x = (float)(idx % 400) * 2.0f;
  float y = (float)(idx / 400) * 2.0f;
  float csrc[3]; bool sval;
  bilin_img(si, 300, 800, x, y, csrc, &sval);
  if (!sval){ csrc[0]=0; csrc[1]=0; csrc[2]=0; }
  float csum = fabsf(csrc[0]-c0)+fabsf(csrc[1]-c1)+fabsf(csrc[2]-c2);
  float dx=dirs[R*3], dy=dirs[R*3+1], dz=dirs[R*3+2];
  float px=dx*depth, py=dy*depth, pz=dz*depth;
  float tx=s2tg[0]*px+s2tg[1]*py+s2tg[2]*pz+s2tg[3];
  float ty=s2tg[4]*px+s2tg[5]*py+s2tg[6]*pz+s2tg[7];
  float tz=s2tg[8]*px+s2tg[9]*py+s2tg[10]*pz+s2tg[11];
  float zt=fmaxf(tz,0.001f);
  float uu=(sK[0]*tx+sK[1]*ty+sK[2]*tz)/zt;
  float vv=(sK[4]*tx+sK[5]*ty+sK[6]*tz)/zt;
  float pred[3]; bool tval;
  bilin_img(ti, 300, 800, uu, vv, pred, &tval);
  float tvf = tval?1.0f:0.0f;
  pred[0]*=tvf; pred[1]*=tvf; pred[2]*=tvf;
  float mask = (tval && (tz>0.1f) && (depth<30.0f)) ? 1.0f : 0.0f;
  float l1 = (fabsf(pred[0]-csrc[0])+fabsf(pred[1]-csrc[1])+fabsf(pred[2]-csrc[2]))*(1.0f/3.0f);
  float* a = acc + cam*8;
  atomicAdd(&a[0], csum*rvr);
  atomicAdd(&a[1], klsum);
  atomicAdd(&a[2], mind);
  atomicAdd(&a[3], l1*mask);
  atomicAdd(&a[4], mask);
}

__global__ void zero_acc_k(float* a){ a[threadIdx.x] = 0.0f; }

__global__ void finalize_k(const float* __restrict__ acc, float* __restrict__ out){
  if (threadIdx.x==0 && blockIdx.x==0){
    float tot = 0.0f;
    for (int c=0;c<6;++c){
      const float* a = acc + c*8;
      float lc  = a[0] / 600.0f;
      float lkl = a[1] / 800.0f;
      float ld  = a[2] / 200.0f;
      float lr  = a[3] / (a[4] + 1e-6f);
      if (lr != lr) lr = 0.0f;
      tot += lc + lkl + 0.01f*ld + lr;
    }
    out[0] = tot / 6.0f;
  }
}

// ---------------- host-side MLP driver ----------------
// CAT layout: [H(512) | bev(512) | cam(256)] bf16, row stride 1280. X: [M][512] bf16.
static void run_mlp3(hipStream_t stream, int M,
   const unsigned short* WinT, const float* bin,
   const unsigned short* WzT,  const float* bz,     // wz[0] only
   const unsigned short* W0T,  const float* b0,     // 3 blocks
   const unsigned short* W1Wz, const float* CB,     // 2 merged blocks + combined biases
   const unsigned short* W1T2, const float* b1,     // w1[2]
   const float* wout, const float* bout, int dout,
   const unsigned short* FEAT, unsigned short* CAT,
   unsigned short* X, float* OUTB)
{
  dim3 grid(512/GBN, (M+GBM-1)/GBM);
  mgemm_k<0,0,0><<<grid,256,0,stream>>>(FEAT, 128, WinT, bin, X, 512, M, 512, 128);
  mgemm_k<0,1,0><<<grid,256,0,stream>>>(CAT+512, 1280, WzT, bz, X, 512, M, 512, 768);
  for (int i=0;i<2;++i){
    mgemm_k<1,0,1><<<grid,256,0,stream>>>(X, 512, W0T + (size_t)i*512*512, b0 + i*512, CAT, 1280, M, 512, 512);
    mgemm_k<0,1,0><<<grid,256,0,stream>>>(CAT, 1280, W1Wz + (size_t)i*512*1280, CB + i*512, X, 512, M, 512, 1280);
  }
  mgemm_k<1,0,1><<<grid,256,0,stream>>>(X, 512, W0T + (size_t)2*512*512, b0 + 2*512, CAT, 1280, M, 512, 512);
  mgemm_k<0,1,0><<<grid,256,0,stream>>>(CAT, 1280, W1T2, b1 + 2*512, X, 512, M, 512, 512);
  outlayer_w_k<<<(M+3)/4, 256, 0, stream>>>(X, wout, bout, OUTB, M, dout);
}

extern "C" void kernel_launch(void* const* d_in, const int* in_sizes, int n_in,
                              void* d_out, int out_size, void* d_ws, size_t ws_size,
                              hipStream_t stream) {
  (void)in_sizes; (void)n_in; (void)out_size;
  const float* cam_feat = (const float*)d_in[0];
  const float* bev_feat = (const float*)d_in[1];
  const float* src_imgs = (const float*)d_in[2];
  const float* tgt_imgs = (const float*)d_in[3];
  const float* rK   = (const float*)d_in[4];
  const float* sK   = (const float*)d_in[5];
  const float* l2c  = (const float*)d_in[6];
  const float* s2in = (const float*)d_in[7];
  const float* s2tg = (const float*)d_in[8];
  const int*   pix  = (const int*)d_in[9];
  const float* mlp_win = (const float*)d_in[10];
  const float* mlp_bin = (const float*)d_in[11];
  const float* mlp_wz  = (const float*)d_in[12];
  const float* mlp_bz  = (const float*)d_in[13];
  const float* mlp_w0  = (const float*)d_in[14];
  const float* mlp_b0  = (const float*)d_in[15];
  const float* mlp_w1  = (const float*)d_in[16];
  const float* mlp_b1  = (const float*)d_in[17];
  const float* mlp_wout= (const float*)d_in[18];
  const float* mlp_bout= (const float*)d_in[19];
  const float* g_win = (const float*)d_in[20];
  const float* g_bin = (const float*)d_in[21];
  const float* g_wz  = (const float*)d_in[22];
  const float* g_bz  = (const float*)d_in[23];
  const float* g_w0  = (const float*)d_in[24];
  const float* g_b0  = (const float*)d_in[25];
  const float* g_w1  = (const float*)d_in[26];
  const float* g_b1  = (const float*)d_in[27];
  const float* g_wout= (const float*)d_in[28];
  const float* g_bout= (const float*)d_in[29];

  char* base = (char*)d_ws;
  size_t off = 0;
  auto alloc = [&](size_t bytes)->char*{
    char* p = base + off;
    off = (off + bytes + 255) & ~(size_t)255;
    return p;
  };
  float* ACC  = (float*)alloc(64*4);
  float* DIR  = (float*)alloc(3600*4);
  float* VD   = (float*)alloc(3600*4);
  float* VDL  = (float*)alloc(3600*4);
  float* MU   = (float*)alloc(4800*4);
  float* STD  = (float*)alloc(4800*4);
  float* CBm  = (float*)alloc(2048*4);   // [mlp i0, mlp i1, g i0, g i1] x 512
  unsigned short* bevT = (unsigned short*)alloc((size_t)40000*512*2);
  unsigned short* camT = (unsigned short*)alloc((size_t)6*5600*256*2);
  unsigned short* gWinT = (unsigned short*)alloc((size_t)512*128*2);
  unsigned short* mWinT = (unsigned short*)alloc((size_t)512*128*2);
  unsigned short* gWzT  = (unsigned short*)alloc((size_t)512*768*2);
  unsigned short* mWzT  = (unsigned short*)alloc((size_t)512*768*2);
  unsigned short* gW0T  = (unsigned short*)alloc((size_t)3*512*512*2);
  unsigned short* mW0T  = (unsigned short*)alloc((size_t)3*512*512*2);
  unsigned short* gW1Wz = (unsigned short*)alloc((size_t)2*512*1280*2);
  unsigned short* mW1Wz = (unsigned short*)alloc((size_t)2*512*1280*2);
  unsigned short* gW1T2 = (unsigned short*)alloc((size_t)512*512*2);
  unsigned short* mW1T2 = (unsigned short*)alloc((size_t)512*512*2);
  size_t fixed = off;
  const size_t perray = 256 + 16384 + 163840 + 65536 + 1024 + 256; // dall,feat,cat,x,out,vf
  int Rc = 1200;
  {
    size_t need = fixed + (size_t)1200*perray + 8192;
    if (need > ws_size){
      size_t avail = (ws_size > fixed + 8192) ? (ws_size - fixed - 8192) : perray;
      Rc = (int)(avail / perray);
      if (Rc < 1) Rc = 1;
      if (Rc > 1200) Rc = 1200;
    }
  }
  float*          DALL = (float*)alloc((size_t)Rc*64*4);
  unsigned short* FEAT = (unsigned short*)alloc((size_t)Rc*64*128*2);
  unsigned short* CAT  = (unsigned short*)alloc((size_t)Rc*64*1280*2);
  unsigned short* X    = (unsigned short*)alloc((size_t)Rc*64*512*2);
  float*          OUTB = (float*)alloc((size_t)Rc*64*4*4);
  float*          VF   = (float*)alloc((size_t)Rc*64*4);

  // ---- transposes / weight prep ----
  { dim3 g((40000+31)/32, (512+31)/32, 1);
    transpose_cb_k<<<g,256,0,stream>>>(bev_feat, bevT, 512, 40000, 512, 0, 0, 512); }
  { dim3 g((5600+31)/32, (256+31)/32, 6);
    transpose_cb_k<<<g,256,0,stream>>>(cam_feat, camT, 256, 5600, 256, (size_t)256*5600, (size_t)5600*256, 256); }
  { dim3 g((512+31)/32, (128+31)/32, 1);
    transpose_cb_k<<<g,256,0,stream>>>(g_win,  gWinT, 84, 512, 128, 0, 0, 128);
    transpose_cb_k<<<g,256,0,stream>>>(mlp_win, mWinT, 84, 512, 128, 0, 0, 128); }
  { dim3 g((512+31)/32, (768+31)/32, 1);  // wz[0] -> [512][768]
    transpose_cb_k<<<g,256,0,stream>>>(g_wz,  gWzT, 768, 512, 768, 0, 0, 768);
    transpose_cb_k<<<g,256,0,stream>>>(mlp_wz, mWzT, 768, 512, 768, 0, 0, 768); }
  { dim3 g((512+31)/32, (512+31)/32, 3);  // w0 all 3 -> [512][512] each
    transpose_cb_k<<<g,256,0,stream>>>(g_w0,  gW0T, 512, 512, 512, (size_t)512*512, (size_t)512*512, 512);
    transpose_cb_k<<<g,256,0,stream>>>(mlp_w0, mW0T, 512, 512, 512, (size_t)512*512, (size_t)512*512, 512); }
  { dim3 g((512+31)/32, (512+31)/32, 2);  // w1[0..1] -> W1Wz cols 0..511
    transpose_cb_k<<<g,256,0,stream>>>(g_w1,  gW1Wz, 512, 512, 512, (size_t)512*512, (size_t)512*1280, 1280);
    transpose_cb_k<<<g,256,0,stream>>>(mlp_w1, mW1Wz, 512, 512, 512, (size_t)512*512, (size_t)512*1280, 1280); }
  { dim3 g((512+31)/32, (768+31)/32, 2);  // wz[1..2] -> W1Wz cols 512..1279
    transpose_cb_k<<<g,256,0,stream>>>(g_wz + (size_t)768*512,  gW1Wz + 512, 768, 512, 768, (size_t)768*512, (size_t)512*1280, 1280);
    transpose_cb_k<<<g,256,0,stream>>>(mlp_wz + (size_t)768*512, mW1Wz + 512, 768, 512, 768, (size_t)768*512, (size_t)512*1280, 1280); }
  { dim3 g((512+31)/32, (512+31)/32, 1);  // w1[2]
    transpose_cb_k<<<g,256,0,stream>>>(g_w1 + (size_t)2*512*512,  gW1T2, 512, 512, 512, 0, 0, 512);
    transpose_cb_k<<<g,256,0,stream>>>(mlp_w1 + (size_t)2*512*512, mW1T2, 512, 512, 512, 0, 0, 512); }
  combine_bias_k<<<8,256,0,stream>>>(mlp_b1, mlp_bz, g_b1, g_bz, CBm);

  zero_acc_k<<<1,64,0,stream>>>(ACC);
  setup_rays_k<<<5,256,0,stream>>>(pix, sK, s2in, DIR, VD, VDL);

  for (int R0=0; R0<1200; R0+=Rc){
    int rn = (1200 - R0 < Rc) ? (1200 - R0) : Rc;
    int Pc = rn*32;
    eval2_k<<<Pc,256,0,stream>>>(camT, bevT, DIR, VD, VDL,
        nullptr, 32, R0, s2in, l2c, rK, FEAT, CAT, nullptr);
    run_mlp3(stream, Pc, gWinT,g_bin, gWzT,g_bz, gW0T,g_b0, gW1Wz, CBm+1024,
             gW1T2, g_b1, g_wout, g_bout, 2, FEAT, CAT, X, OUTB);
    coarse_post_k<<<(rn+255)/256,256,0,stream>>>(OUTB, MU, STD, DALL, R0, rn);
    int Pf = rn*64;
    eval2_k<<<Pf,256,0,stream>>>(camT, bevT, DIR, VD, VDL,
        DALL, 64, R0, s2in, l2c, rK, FEAT, CAT, VF);
    run_mlp3(stream, Pf, mWinT,mlp_bin, mWzT,mlp_bz, mW0T,mlp_b0, mW1Wz, CBm,
             mW1T2, mlp_b1, mlp_wout, mlp_bout, 4, FEAT, CAT, X, OUTB);
    render_loss_w_k<<<(rn+3)/4,256,0,stream>>>(OUTB, VF, DALL, MU, STD,
        DIR, pix, src_imgs, tgt_imgs, s2tg, sK, ACC, R0, rn);
  }
  finalize_k<<<1,1,0,stream>>>(ACC, (float*)d_out);
}

// Round 5
// 2698.078 us; speedup vs baseline: 6.4274x; 1.1442x over previous
//
#include <hip/hip_runtime.h>
#include <math.h>

typedef unsigned int uint32;
typedef short bf16x8 __attribute__((ext_vector_type(8)));
typedef float f32x4 __attribute__((ext_vector_type(4)));
typedef uint32 u32x4 __attribute__((ext_vector_type(4)));

__device__ __forceinline__ float sigmoidf_(float x){ return 1.0f/(1.0f+expf(-x)); }
__device__ __forceinline__ float softplusf_(float x){ return x>20.0f ? x : log1pf(expf(x)); }
__device__ __forceinline__ int iclampi(int v,int lo,int hi){ return v<lo?lo:(v>hi?hi:v); }

__device__ __forceinline__ float bf2f(uint32 u){ return __uint_as_float(u<<16); }
__device__ __forceinline__ unsigned short f2bf(float f){
  uint32 x = __float_as_uint(f);
  uint32 r = (x + 0x7fffu + ((x>>16)&1u)) >> 16;
  return (unsigned short)r;
}
__device__ __forceinline__ uint32 relu_bf16x2(uint32 u){
  uint32 lo = (u & 0x8000u) ? 0u : (u & 0xffffu);
  uint32 hi = (u & 0x80000000u) ? 0u : (u & 0xffff0000u);
  return lo | hi;
}

__device__ __forceinline__ float pe_elem(int s, float vx, float vy, float vz){
  const float F0 = 3.14159265358979f;
  if (s < 3) return s==0?vx:(s==1?vy:vz);
  s -= 3;
  bool isCos = false;
  if (s >= 18){ s -= 18; isCos = true; }
  int fi = s/3, ci = s%3;
  float v = ci==0?vx:(ci==1?vy:vz);
  float f = F0 * (float)(1<<fi);
  return isCos ? cosf(f*v) : sinf(f*v);
}

// ---- transpose+convert: in f32 [C][S] -> out bf16 [S][rowStride], cols c<Cout (zero-pad c>=C) ----
__global__ __launch_bounds__(256) void transpose_cb_k(const float* __restrict__ in,
    unsigned short* __restrict__ out, int C, int S, int Cout,
    size_t inStride, size_t outStride, int rowStride)
{
  __shared__ float tile[32][33];
  int b = blockIdx.z;
  int s0 = blockIdx.x*32, c0 = blockIdx.y*32;
  int tx = threadIdx.x & 31, ty = threadIdx.x >> 5;
  #pragma unroll
  for (int i=0;i<32;i+=8){
    int c = c0+ty+i, s = s0+tx;
    tile[ty+i][tx] = (c<C && s<S) ? in[(size_t)b*inStride + (size_t)c*S + s] : 0.0f;
  }
  __syncthreads();
  #pragma unroll
  for (int i=0;i<32;i+=8){
    int s = s0+ty+i, c = c0+tx;
    if (s<S && c<Cout) out[(size_t)b*outStride + (size_t)s*rowStride + c] = f2bf(tile[tx][ty+i]);
  }
}

// ---- combine biases: CB[w][n] = b1[i][n] + bz[i+1][n], w = {mlp i0, mlp i1, g i0, g i1} ----
__global__ void combine_bias_k(const float* __restrict__ m_b1, const float* __restrict__ m_bz,
                               const float* __restrict__ g_b1, const float* __restrict__ g_bz,
                               float* __restrict__ CB)
{
  int idx = blockIdx.x*blockDim.x + threadIdx.x;
  if (idx >= 2048) return;
  int w = idx >> 9, n = idx & 511;
  const float* b1 = (w < 2) ? m_b1 : g_b1;
  const float* bz = (w < 2) ? m_bz : g_bz;
  int i = w & 1;
  CB[idx] = b1[i*512 + n] + bz[(i+1)*512 + n];
}

// ---------------- per-ray setup: all 1200 rays ----------------
__global__ void setup_rays_k(const int* __restrict__ pix, const float* __restrict__ sK_all,
                             const float* __restrict__ s2in_all,
                             float* __restrict__ dirs, float* __restrict__ vd,
                             float* __restrict__ vdl)
{
  int r = blockIdx.x*blockDim.x + threadIdx.x;
  if (r >= 1200) return;
  int cam = r / 200;
  const float* sK = sK_all + cam*16;
  const float* s2in = s2in_all + cam*16;
  float a=sK[0],b=sK[1],c=sK[2],d=sK[4],e=sK[5],f=sK[6],g=sK[8],h=sK[9],i=sK[10];
  float det = a*(e*i-f*h) - b*(d*i-f*g) + c*(d*h-e*g);
  float inv00=(e*i-f*h)/det, inv01=(c*h-b*i)/det, inv02=(b*f-c*e)/det;
  float inv10=(f*g-d*i)/det, inv11=(a*i-c*g)/det, inv12=(c*d-a*f)/det;
  float inv20=(d*h-e*g)/det, inv21=(b*g-a*h)/det, inv22=(a*e-b*d)/det;
  int idx = pix[r];
  float x = (float)(idx % 400) * 2.0f;
  float y = (float)(idx / 400) * 2.0f;
  float dx = inv00*x + inv01*y + inv02;
  float dy = inv10*x + inv11*y + inv12;
  float dz = inv20*x + inv21*y + inv22;
  dirs[r*3+0]=dx; dirs[r*3+1]=dy; dirs[r*3+2]=dz;
  float n = sqrtf(dx*dx+dy*dy+dz*dz);
  float vx=dx/n, vy=dy/n, vz=dz/n;
  vd[r*3+0]=vx; vd[r*3+1]=vy; vd[r*3+2]=vz;
  vdl[r*3+0]=s2in[0]*vx + s2in[1]*vy + s2in[2]*vz;
  vdl[r*3+1]=s2in[4]*vx + s2in[5]*vy + s2in[6]*vz;
  vdl[r*3+2]=s2in[8]*vx + s2in[9]*vy + s2in[10]*vz;
}

// ---- point eval: feat(bf16 [P][128]) + CAT latent cols 512..1279 (bf16 [P][1280]) ----
__global__ __launch_bounds__(256) void eval2_k(
    const unsigned short* __restrict__ camT,  // [6][5600][256] bf16
    const unsigned short* __restrict__ bevT,  // [40000][512] bf16
    const float* __restrict__ dirs, const float* __restrict__ vd, const float* __restrict__ vdl,
    const float* __restrict__ dall, int ndepth, int R0,
    const float* __restrict__ s2in_all, const float* __restrict__ l2c_all, const float* __restrict__ rK_all,
    unsigned short* __restrict__ feat, unsigned short* __restrict__ cat, float* __restrict__ vf)
{
  int p  = blockIdx.x;
  int rl = p / ndepth;
  int j  = p - rl*ndepth;
  int R  = R0 + rl;
  int cam = R / 200;
  const float* s2in = s2in_all + cam*16;
  const float* l2c  = l2c_all + cam*16;
  const float* rK   = rK_all + cam*16;
  float dx = dirs[R*3+0], dy = dirs[R*3+1], dz = dirs[R*3+2];
  float d = dall ? dall[(size_t)rl*ndepth + j] : (((float)j + 0.5f)/32.0f)*100.0f;
  float px = dx*d, py = dy*d, pz = dz*d;
  float lx = s2in[0]*px + s2in[1]*py + s2in[2]*pz + s2in[3];
  float ly = s2in[4]*px + s2in[5]*py + s2in[6]*pz + s2in[7];
  float lz = s2in[8]*px + s2in[9]*py + s2in[10]*pz + s2in[11];
  float ccx = l2c[0]*lx + l2c[1]*ly + l2c[2]*lz + l2c[3];
  float ccy = l2c[4]*lx + l2c[5]*ly + l2c[6]*lz + l2c[7];
  float ccz = l2c[8]*lx + l2c[9]*ly + l2c[10]*lz + l2c[11];
  float zs = fmaxf(ccz, 0.001f);
  float uu = rK[0]*ccx + rK[1]*ccy + rK[2]*ccz;
  float vv = rK[4]*ccx + rK[5]*ccy + rK[6]*ccz;
  float fu = uu/zs*(100.0f/1600.0f);
  float fv = vv/zs*(56.0f/900.0f);
  bool cvalid = (fu>=0.0f)&&(fu<=99.0f)&&(fv>=0.0f)&&(fv<=55.0f)&&(ccz>0.1f);
  float cfx0 = floorf(fu), cfy0 = floorf(fv);
  int cx0=iclampi((int)cfx0,0,99), cx1=iclampi(cx0+1,0,99);
  int cy0=iclampi((int)cfy0,0,55), cy1=iclampi(cy0+1,0,55);
  float cwx=fu-cfx0, cwy=fv-cfy0;
  float cw00=(1-cwx)*(1-cwy), cw01=cwx*(1-cwy), cw10=(1-cwx)*cwy, cw11=cwx*cwy;
  float bx = (lx+51.2f)/102.4f*199.0f;
  float by = (ly+51.2f)/102.4f*199.0f;
  bool bvalid = (bx>=0.0f)&&(bx<=199.0f)&&(by>=0.0f)&&(by<=199.0f);
  float bfx0=floorf(bx), bfy0=floorf(by);
  int bx0=iclampi((int)bfx0,0,199), bx1=iclampi(bx0+1,0,199);
  int by0=iclampi((int)bfy0,0,199), by1=iclampi(by0+1,0,199);
  float bwx=bx-bfx0, bwy=by-bfy0;
  float bw00=(1-bwx)*(1-bwy), bw01=bwx*(1-bwy), bw10=(1-bwx)*bwy, bw11=bwx*bwy;
  float vflag = (cvalid && bvalid) ? 1.0f : 0.0f;
  int t = threadIdx.x;
  uint32* catrow = (uint32*)(cat + (size_t)p*1280);
  { // bev -> CAT cols 512..1023
    size_t sb00 = (size_t)(by0*200+bx0)*512, sb01 = (size_t)(by0*200+bx1)*512;
    size_t sb10 = (size_t)(by1*200+bx0)*512, sb11 = (size_t)(by1*200+bx1)*512;
    uint32 u00 = ((const uint32*)(bevT + sb00))[t];
    uint32 u01 = ((const uint32*)(bevT + sb01))[t];
    uint32 u10 = ((const uint32*)(bevT + sb10))[t];
    uint32 u11 = ((const uint32*)(bevT + sb11))[t];
    float lo = bw00*bf2f(u00&0xffffu) + bw01*bf2f(u01&0xffffu) + bw10*bf2f(u10&0xffffu) + bw11*bf2f(u11&0xffffu);
    float hi = bw00*bf2f(u00>>16) + bw01*bf2f(u01>>16) + bw10*bf2f(u10>>16) + bw11*bf2f(u11>>16);
    lo *= vflag; hi *= vflag;
    catrow[256 + t] = (uint32)f2bf(lo) | ((uint32)f2bf(hi)<<16);
  }
  if (t < 128){ // cam -> CAT cols 1024..1279
    const unsigned short* cfT = camT + (size_t)cam*5600*256;
    size_t sc00 = (size_t)(cy0*100+cx0)*256, sc01 = (size_t)(cy0*100+cx1)*256;
    size_t sc10 = (size_t)(cy1*100+cx0)*256, sc11 = (size_t)(cy1*100+cx1)*256;
    uint32 u00 = ((const uint32*)(cfT + sc00))[t];
    uint32 u01 = ((const uint32*)(cfT + sc01))[t];
    uint32 u10 = ((const uint32*)(cfT + sc10))[t];
    uint32 u11 = ((const uint32*)(cfT + sc11))[t];
    float lo = cw00*bf2f(u00&0xffffu) + cw01*bf2f(u01&0xffffu) + cw10*bf2f(u10&0xffffu) + cw11*bf2f(u11&0xffffu);
    float hi = cw00*bf2f(u00>>16) + cw01*bf2f(u01>>16) + cw10*bf2f(u10>>16) + cw11*bf2f(u11>>16);
    lo *= vflag; hi *= vflag;
    catrow[512 + t] = (uint32)f2bf(lo) | ((uint32)f2bf(hi)<<16);
  }
  if (t < 128){
    float val = 0.0f;
    if (t < 84){
      float plx = lx/51.2f, ply = ly/51.2f, plz = (lz+1.0f)/4.0f;
      float pcx = px/100.0f, pcy = py/100.0f, pcz = pz/100.0f;
      float vx=vd[R*3], vy=vd[R*3+1], vz=vd[R*3+2];
      float wx=vdl[R*3], wy=vdl[R*3+1], wz=vdl[R*3+2];
      if (t < 39)      val = pe_elem(t, plx, ply, plz);
      else if (t < 42) val = (t==39)?wx:((t==40)?wy:wz);
      else if (t < 81) val = pe_elem(t-42, pcx, pcy, pcz);
      else             val = (t==81)?vx:((t==82)?vy:vz);
    }
    feat[(size_t)p*128 + t] = f2bf(val);
  }
  if (vf && t==0) vf[p] = vflag;
}

// ---------------- MFMA bf16 GEMM: C = [C +] [relu](A) @ BT^T + bias; all bf16 ----------------
// N must be 512 (8 col tiles). 1-D grid, XCD-aware swizzle: the 8 col tiles of
// one 128-row panel map to the SAME XCD and are adjacent in its dispatch
// stream -> A panel fetched once into that XCD's L2 (was 3.5x HBM re-fetch).
#define GBM 128
#define GBN 64
#define GBK 64
template<int RELU_A, int ACC, int RELU_OUT>
__global__ __launch_bounds__(256,4) void mgemm_k(
    const unsigned short* __restrict__ A, int lda,
    const unsigned short* __restrict__ BT,
    const float* __restrict__ bias,
    unsigned short* __restrict__ C, int ldc,
    int M, int N, int K)
{
  __shared__ unsigned short As[GBM*GBK];  // 16 KB
  __shared__ unsigned short Bs[GBN*GBK];  // 8 KB
  int w = blockIdx.x;
  int xcd = w & 7, ii = w >> 3;
  int colp = ii & 7, rgrp = ii >> 3;
  int rowp = rgrp*8 + xcd;
  int row0 = rowp*GBM, col0 = colp*GBN;
  if (row0 >= M) return;              // padded row panels idle out
  int tid = threadIdx.x;
  int lane = tid & 63, wave = tid >> 6;
  int wm = wave >> 1, wn = wave & 1;  // 2x2 waves: wave tile 64 rows x 32 cols
  int l15 = lane & 15, l4 = lane >> 4;
  f32x4 acc[4][2];
  #pragma unroll
  for (int mi=0;mi<4;++mi)
    #pragma unroll
    for (int nj=0;nj<2;++nj){ f32x4 z = {0.f,0.f,0.f,0.f}; acc[mi][nj] = z; }

  for (int k0 = 0; k0 < K; k0 += GBK){
    #pragma unroll
    for (int it=0; it<4; ++it){       // A tile: 128 rows x 8 chunks
      int id = it*256 + tid;
      int rr = id >> 3, ch = id & 7;
      int gr = row0 + rr;
      bf16x8 val = {0,0,0,0,0,0,0,0};
      if (gr < M) val = *(const bf16x8*)(A + (size_t)gr*lda + k0 + ch*8);
      if (RELU_A){
        u32x4 u = *(u32x4*)&val;
        #pragma unroll
        for (int q=0;q<4;++q) u[q] = relu_bf16x2(u[q]);
        val = *(bf16x8*)&u;
      }
      *(bf16x8*)&As[rr*64 + ((ch ^ (rr&7))<<3)] = val;
    }
    #pragma unroll
    for (int it=0; it<2; ++it){       // B tile: 64 rows x 8 chunks
      int id = it*256 + tid;
      int rr = id >> 3, ch = id & 7;
      int gc = col0 + rr;
      bf16x8 val = {0,0,0,0,0,0,0,0};
      if (gc < N) val = *(const bf16x8*)(BT + (size_t)gc*K + k0 + ch*8);
      *(bf16x8*)&Bs[rr*64 + ((ch ^ (rr&7))<<3)] = val;
    }
    __syncthreads();
    #pragma unroll
    for (int ks=0; ks<2; ++ks){
      bf16x8 a[4], b[2];
      #pragma unroll
      for (int mi=0;mi<4;++mi){
        int row = wm*64 + mi*16 + l15;
        int sc = (ks*4 + l4) ^ (row&7);
        a[mi] = *(const bf16x8*)&As[row*64 + sc*8];
      }
      #pragma unroll
      for (int nj=0;nj<2;++nj){
        int colr = wn*32 + nj*16 + l15;
        int sc = (ks*4 + l4) ^ (colr&7);
        b[nj] = *(const bf16x8*)&Bs[colr*64 + sc*8];
      }
      #pragma unroll
      for (int mi=0;mi<4;++mi)
        #pragma unroll
        for (int nj=0;nj<2;++nj)
          acc[mi][nj] = __builtin_amdgcn_mfma_f32_16x16x32_bf16(a[mi], b[nj], acc[mi][nj], 0,0,0);
    }
    __syncthreads();
  }
  #pragma unroll
  for (int mi=0;mi<4;++mi){
    int gr0 = row0 + wm*64 + mi*16 + l4*4;
    #pragma unroll
    for (int nj=0;nj<2;++nj){
      int gc = col0 + wn*32 + nj*16 + l15;
      if (gc >= N) continue;
      float bv = bias[gc];
      #pragma unroll
      for (int i=0;i<4;++i){
        int gr = gr0 + i;
        if (gr >= M) continue;
        float v = acc[mi][nj][i] + bv;
        if (ACC) v += bf2f((uint32)C[(size_t)gr*ldc + gc]);
        if (RELU_OUT) v = fmaxf(v, 0.0f);
        C[(size_t)gr*ldc + gc] = f2bf(v);
      }
    }
  }
}

static inline int gemm_grid(int M){
  int nrow = (M + GBM - 1)/GBM;
  int nrowp = (nrow + 7) & ~7;   // pad to multiple of 8 for bijective swizzle
  return nrowp * 8;
}

// ---------------- out layer, wave per row ----------------
__global__ __launch_bounds__(256) void outlayer_w_k(const unsigned short* __restrict__ X,
    const float* __restrict__ W, const float* __restrict__ b, float* __restrict__ O,
    int M, int dout)
{
  int wid = threadIdx.x >> 6, lane = threadIdx.x & 63;
  int row = blockIdx.x*4 + wid;
  if (row >= M) return;
  const unsigned short* xr = X + (size_t)row*512;
  float s[4] = {0,0,0,0};
  for (int k=lane; k<512; k+=64){
    float xv = fmaxf(bf2f((uint32)xr[k]), 0.0f);
    #pragma unroll
    for (int c=0;c<4;++c)
      if (c < dout) s[c] += xv * W[(size_t)k*dout + c];
  }
  #pragma unroll
  for (int c=0;c<4;++c)
    #pragma unroll
    for (int m=32;m;m>>=1) s[c] += __shfl_xor(s[c], m, 64);
  if (lane == 0)
    for (int c=0;c<dout;++c) O[(size_t)row*dout + c] = s[c] + b[c];
}

// ---------------- coarse post ----------------
__global__ void coarse_post_k(const float* __restrict__ OUTB, float* __restrict__ MU,
                              float* __restrict__ STD, float* __restrict__ DALL,
                              int R0, int rn)
{
  int rl = blockIdx.x*blockDim.x + threadIdx.x;
  if (rl >= rn) return;
  int R = R0 + rl;
  float mu[4], sd[4];
  for (int g=0; g<4; ++g){
    float lg[8], sv[8], mx = -1e30f;
    for (int pp=0; pp<8; ++pp){
      int j = g*8+pp;
      lg[pp] = OUTB[((size_t)rl*32 + j)*2 + 0];
      sv[pp] = OUTB[((size_t)rl*32 + j)*2 + 1];
      mx = fmaxf(mx, lg[pp]);
    }
    float se = 0.0f;
    for (int pp=0; pp<8; ++pp){ lg[pp] = expf(lg[pp]-mx); se += lg[pp]; }
    float m=0.0f, s=0.0f;
    for (int pp=0; pp<8; ++pp){
      float wgt = lg[pp]/se;
      float du = (((float)(g*8+pp)+0.5f)/32.0f)*100.0f;
      m += wgt*du; s += wgt*sv[pp];
    }
    mu[g]=m; sd[g]=softplusf_(s)+0.1f;
    MU[R*4+g]=mu[g]; STD[R*4+g]=sd[g];
  }
  float da[64];
  for (int j=0;j<32;++j) da[j] = (((float)j+0.5f)/32.0f)*100.0f;
  for (int g=0; g<4; ++g)
    for (int pp=0; pp<8; ++pp){
      float off = -2.0f + (4.0f/7.0f)*(float)pp;
      float v = mu[g] + sd[g]*off;
      v = fminf(fmaxf(v, 0.5f), 100.0f);
      da[32 + g*8+pp] = v;
    }
  for (int i=1;i<64;++i){ float key=da[i]; int k=i-1;
    while (k>=0 && da[k]>key){ da[k+1]=da[k]; --k; } da[k+1]=key; }
  for (int j=0;j<64;++j) DALL[(size_t)rl*64+j] = da[j];
}

__device__ __forceinline__ void bilin_img(const float* __restrict__ img, int H, int W,
                                          float u, float v, float* out3, bool* valid)
{
  *valid = (u>=0.0f)&&(u<=(float)(W-1))&&(v>=0.0f)&&(v<=(float)(H-1));
  float fx0=floorf(u), fy0=floorf(v);
  int x0=iclampi((int)fx0,0,W-1), x1=iclampi(x0+1,0,W-1);
  int y0=iclampi((int)fy0,0,H-1), y1=iclampi(y0+1,0,H-1);
  float wx=u-fx0, wy=v-fy0;
  float w00=(1-wx)*(1-wy), w01=wx*(1-wy), w10=(1-wx)*wy, w11=wx*wy;
  for (int ch=0; ch<3; ++ch){
    const float* p = img + (size_t)ch*H*W;
    out3[ch] = w00*p[y0*W+x0] + w01*p[y0*W+x1] + w10*p[y1*W+x0] + w11*p[y1*W+x1];
  }
}

// ---------------- render + losses, one wave per ray ----------------
__global__ __launch_bounds__(256) void render_loss_w_k(
  const float* __restrict__ OUTB, const float* __restrict__ VF,
  const float* __restrict__ DALL, const float* __restrict__ MU, const float* __restrict__ STD,
  const float* __restrict__ dirs, const int* __restrict__ pix,
  const float* __restrict__ src_imgs, const float* __restrict__ tgt_imgs,
  const float* __restrict__ s2tg_all, const float* __restrict__ sK_all,
  float* __restrict__ acc, int R0, int rn)
{
  int wid = threadIdx.x >> 6, lane = threadIdx.x & 63;
  int rl = blockIdx.x*4 + wid;
  if (rl >= rn) return;
  int R = R0 + rl;
  int cam = R / 200;
  int j = lane;
  float dj = DALL[(size_t)rl*64 + j];
  float delta = (j<63) ? (DALL[(size_t)rl*64 + j + 1] - dj) : 1000.0f;
  f32x4 o = *(const f32x4*)(OUTB + ((size_t)rl*64 + j)*4);
  float vfp = VF[(size_t)rl*64 + j];
  float sg = softplusf_(o[3])*vfp;
  float alpha = 1.0f - expf(-sg*delta);
  float prod = 1.0f - alpha + 1e-10f;
  #pragma unroll
  for (int dstep=1; dstep<64; dstep<<=1){
    float v = __shfl_up(prod, dstep, 64);
    if (lane >= dstep) prod *= v;
  }
  float T = __shfl_up(prod, 1, 64);
  if (lane == 0) T = 1.0f;
  float w = alpha*T;
  float c0 = w*sigmoidf_(o[0]), c1 = w*sigmoidf_(o[1]), c2 = w*sigmoidf_(o[2]);
  float dsum = w*dj, vs = vfp;
  #pragma unroll
  for (int m=32;m;m>>=1){
    c0 += __shfl_xor(c0,m,64); c1 += __shfl_xor(c1,m,64); c2 += __shfl_xor(c2,m,64);
    dsum += __shfl_xor(dsum,m,64); vs += __shfl_xor(vs,m,64);
  }
  float depth = dsum, rvr = vs/64.0f;
  float mu[4], sd[4];
  #pragma unroll
  for (int g=0;g<4;++g){ mu[g]=MU[R*4+g]; sd[g]=STD[R*4+g]; }
  float e[4], mx=-1e30f;
  #pragma unroll
  for (int g=0;g<4;++g){ float dd=dj-mu[g]; e[g]=-dd*dd*0.125f; mx=fmaxf(mx,e[g]); }
  float se=0;
  #pragma unroll
  for (int g=0;g<4;++g){ e[g]=expf(e[g]-mx); se+=e[g]; }
  float rw[4];
  #pragma unroll
  for (int g=0;g<4;++g) rw[g] = e[g]/se*w + 1e-8f;
  float srw[4], srwd[4];
  #pragma unroll
  for (int g=0;g<4;++g){ srw[g]=rw[g]; srwd[g]=rw[g]*dj; }
  #pragma unroll
  for (int m=32;m;m>>=1){
    #pragma unroll
    for (int g=0;g<4;++g){ srw[g]+=__shfl_xor(srw[g],m,64); srwd[g]+=__shfl_xor(srwd[g],m,64); }
  }
  float smean[4];
  #pragma unroll
  for (int g=0;g<4;++g) smean[g]=srwd[g]/srw[g];
  float sv[4];
  #pragma unroll
  for (int g=0;g<4;++g){ float dd=dj-smean[g]; sv[g]=rw[g]*dd*dd; }
  #pragma unroll
  for (int m=32;m;m>>=1){
    #pragma unroll
    for (int g=0;g<4;++g) sv[g]+=__shfl_xor(sv[g],m,64);
  }
  if (lane != 0) return;
  float klsum=0;
  #pragma unroll
  for (int g=0;g<4;++g){
    float var = sv[g]/srw[g];
    float sstd = sqrtf(var + 1e-6f);
    float dm = mu[g]-smean[g];
    klsum += logf(sstd/sd[g]) + (sd[g]*sd[g] + dm*dm)/(2.0f*(var+1e-6f)) - 0.5f;
  }
  float mind=1e30f;
  #pragma unroll
  for (int g=0;g<4;++g) mind = fminf(mind, fabsf(mu[g]-depth));
  const float* si = src_imgs + (size_t)cam*3*300*800;
  const float* ti = tgt_imgs + (size_t)cam*3*300*800;
  const float* s2tg = s2tg_all + cam*16;
  const float* sK = sK_all + cam*16;
  int idx = pix[R];
  float x = (float)(idx % 400) * 2.0f;
  float y = (float)(idx / 400) * 2.0f;
  float csrc[3]; bool sval;
  bilin_img(si, 300, 800, x, y, csrc, &sval);
  if (!sval){ csrc[0]=0; csrc[1]=0; csrc[2]=0; }
  float csum = fabsf(csrc[0]-c0)+fabsf(csrc[1]-c1)+fabsf(csrc[2]-c2);
  float dx=dirs[R*3], dy=dirs[R*3+1], dz=dirs[R*3+2];
  float px=dx*depth, py=dy*depth, pz=dz*depth;
  float tx=s2tg[0]*px+s2tg[1]*py+s2tg[2]*pz+s2tg[3];
  float ty=s2tg[4]*px+s2tg[5]*py+s2tg[6]*pz+s2tg[7];
  float tz=s2tg[8]*px+s2tg[9]*py+s2tg[10]*pz+s2tg[11];
  float zt=fmaxf(tz,0.001f);
  float uu=(sK[0]*tx+sK[1]*ty+sK[2]*tz)/zt;
  float vv=(sK[4]*tx+sK[5]*ty+sK[6]*tz)/zt;
  float pred[3]; bool tval;
  bilin_img(ti, 300, 800, uu, vv, pred, &tval);
  float tvf = tval?1.0f:0.0f;
  pred[0]*=tvf; pred[1]*=tvf; pred[2]*=tvf;
  float mask = (tval && (tz>0.1f) && (depth<30.0f)) ? 1.0f : 0.0f;
  float l1 = (fabsf(pred[0]-csrc[0])+fabsf(pred[1]-csrc[1])+fabsf(pred[2]-csrc[2]))*(1.0f/3.0f);
  float* a = acc + cam*8;
  atomicAdd(&a[0], csum*rvr);
  atomicAdd(&a[1], klsum);
  atomicAdd(&a[2], mind);
  atomicAdd(&a[3], l1*mask);
  atomicAdd(&a[4], mask);
}

__global__ void zero_acc_k(float* a){ a[threadIdx.x] = 0.0f; }

__global__ void finalize_k(const float* __restrict__ acc, float* __restrict__ out){
  if (threadIdx.x==0 && blockIdx.x==0){
    float tot = 0.0f;
    for (int c=0;c<6;++c){
      const float* a = acc + c*8;
      float lc  = a[0] / 600.0f;
      float lkl = a[1] / 800.0f;
      float ld  = a[2] / 200.0f;
      float lr  = a[3] / (a[4] + 1e-6f);
      if (lr != lr) lr = 0.0f;
      tot += lc + lkl + 0.01f*ld + lr;
    }
    out[0] = tot / 6.0f;
  }
}

// ---------------- host-side MLP driver ----------------
// CAT layout: [H(512) | bev(512) | cam(256)] bf16, row stride 1280. X: [M][512] bf16.
static void run_mlp3(hipStream_t stream, int M,
   const unsigned short* WinT, const float* bin,
   const unsigned short* WzT,  const float* bz,
   const unsigned short* W0T,  const float* b0,
   const unsigned short* W1Wz, const float* CB,
   const unsigned short* W1T2, const float* b1,
   const float* wout, const float* bout, int dout,
   const unsigned short* FEAT, unsigned short* CAT,
   unsigned short* X, float* OUTB)
{
  int g = gemm_grid(M);
  mgemm_k<0,0,0><<<g,256,0,stream>>>(FEAT, 128, WinT, bin, X, 512, M, 512, 128);
  mgemm_k<0,1,0><<<g,256,0,stream>>>(CAT+512, 1280, WzT, bz, X, 512, M, 512, 768);
  for (int i=0;i<2;++i){
    mgemm_k<1,0,1><<<g,256,0,stream>>>(X, 512, W0T + (size_t)i*512*512, b0 + i*512, CAT, 1280, M, 512, 512);
    mgemm_k<0,1,0><<<g,256,0,stream>>>(CAT, 1280, W1Wz + (size_t)i*512*1280, CB + i*512, X, 512, M, 512, 1280);
  }
  mgemm_k<1,0,1><<<g,256,0,stream>>>(X, 512, W0T + (size_t)2*512*512, b0 + 2*512, CAT, 1280, M, 512, 512);
  mgemm_k<0,1,0><<<g,256,0,stream>>>(CAT, 1280, W1T2, b1 + 2*512, X, 512, M, 512, 512);
  outlayer_w_k<<<(M+3)/4, 256, 0, stream>>>(X, wout, bout, OUTB, M, dout);
}

extern "C" void kernel_launch(void* const* d_in, const int* in_sizes, int n_in,
                              void* d_out, int out_size, void* d_ws, size_t ws_size,
                              hipStream_t stream) {
  (void)in_sizes; (void)n_in; (void)out_size;
  const float* cam_feat = (const float*)d_in[0];
  const float* bev_feat = (const float*)d_in[1];
  const float* src_imgs = (const float*)d_in[2];
  const float* tgt_imgs = (const float*)d_in[3];
  const float* rK   = (const float*)d_in[4];
  const float* sK   = (const float*)d_in[5];
  const float* l2c  = (const float*)d_in[6];
  const float* s2in = (const float*)d_in[7];
  const float* s2tg = (const float*)d_in[8];
  const int*   pix  = (const int*)d_in[9];
  const float* mlp_win = (const float*)d_in[10];
  const float* mlp_bin = (const float*)d_in[11];
  const float* mlp_wz  = (const float*)d_in[12];
  const float* mlp_bz  = (const float*)d_in[13];
  const float* mlp_w0  = (const float*)d_in[14];
  const float* mlp_b0  = (const float*)d_in[15];
  const float* mlp_w1  = (const float*)d_in[16];
  const float* mlp_b1  = (const float*)d_in[17];
  const float* mlp_wout= (const float*)d_in[18];
  const float* mlp_bout= (const float*)d_in[19];
  const float* g_win = (const float*)d_in[20];
  const float* g_bin = (const float*)d_in[21];
  const float* g_wz  = (const float*)d_in[22];
  const float* g_bz  = (const float*)d_in[23];
  const float* g_w0  = (const float*)d_in[24];
  const float* g_b0  = (const float*)d_in[25];
  const float* g_w1  = (const float*)d_in[26];
  const float* g_b1  = (const float*)d_in[27];
  const float* g_wout= (const float*)d_in[28];
  const float* g_bout= (const float*)d_in[29];

  char* base = (char*)d_ws;
  size_t off = 0;
  auto alloc = [&](size_t bytes)->char*{
    char* p = base + off;
    off = (off + bytes + 255) & ~(size_t)255;
    return p;
  };
  float* ACC  = (float*)alloc(64*4);
  float* DIR  = (float*)alloc(3600*4);
  float* VD   = (float*)alloc(3600*4);
  float* VDL  = (float*)alloc(3600*4);
  float* MU   = (float*)alloc(4800*4);
  float* STD  = (float*)alloc(4800*4);
  float* CBm  = (float*)alloc(2048*4);
  unsigned short* bevT = (unsigned short*)alloc((size_t)40000*512*2);
  unsigned short* camT = (unsigned short*)alloc((size_t)6*5600*256*2);
  unsigned short* gWinT = (unsigned short*)alloc((size_t)512*128*2);
  unsigned short* mWinT = (unsigned short*)alloc((size_t)512*128*2);
  unsigned short* gWzT  = (unsigned short*)alloc((size_t)512*768*2);
  unsigned short* mWzT  = (unsigned short*)alloc((size_t)512*768*2);
  unsigned short* gW0T  = (unsigned short*)alloc((size_t)3*512*512*2);
  unsigned short* mW0T  = (unsigned short*)alloc((size_t)3*512*512*2);
  unsigned short* gW1Wz = (unsigned short*)alloc((size_t)2*512*1280*2);
  unsigned short* mW1Wz = (unsigned short*)alloc((size_t)2*512*1280*2);
  unsigned short* gW1T2 = (unsigned short*)alloc((size_t)512*512*2);
  unsigned short* mW1T2 = (unsigned short*)alloc((size_t)512*512*2);
  size_t fixed = off;
  const size_t perray = 256 + 16384 + 163840 + 65536 + 1024 + 256;
  int Rc = 1200;
  {
    size_t need = fixed + (size_t)1200*perray + 8192;
    if (need > ws_size){
      size_t avail = (ws_size > fixed + 8192) ? (ws_size - fixed - 8192) : perray;
      Rc = (int)(avail / perray);
      if (Rc < 1) Rc = 1;
      if (Rc > 1200) Rc = 1200;
    }
  }
  float*          DALL = (float*)alloc((size_t)Rc*64*4);
  unsigned short* FEAT = (unsigned short*)alloc((size_t)Rc*64*128*2);
  unsigned short* CAT  = (unsigned short*)alloc((size_t)Rc*64*1280*2);
  unsigned short* X    = (unsigned short*)alloc((size_t)Rc*64*512*2);
  float*          OUTB = (float*)alloc((size_t)Rc*64*4*4);
  float*          VF   = (float*)alloc((size_t)Rc*64*4);

  // ---- transposes / weight prep ----
  { dim3 g((40000+31)/32, (512+31)/32, 1);
    transpose_cb_k<<<g,256,0,stream>>>(bev_feat, bevT, 512, 40000, 512, 0, 0, 512); }
  { dim3 g((5600+31)/32, (256+31)/32, 6);
    transpose_cb_k<<<g,256,0,stream>>>(cam_feat, camT, 256, 5600, 256, (size_t)256*5600, (size_t)5600*256, 256); }
  { dim3 g((512+31)/32, (128+31)/32, 1);
    transpose_cb_k<<<g,256,0,stream>>>(g_win,  gWinT, 84, 512, 128, 0, 0, 128);
    transpose_cb_k<<<g,256,0,stream>>>(mlp_win, mWinT, 84, 512, 128, 0, 0, 128); }
  { dim3 g((512+31)/32, (768+31)/32, 1);
    transpose_cb_k<<<g,256,0,stream>>>(g_wz,  gWzT, 768, 512, 768, 0, 0, 768);
    transpose_cb_k<<<g,256,0,stream>>>(mlp_wz, mWzT, 768, 512, 768, 0, 0, 768); }
  { dim3 g((512+31)/32, (512+31)/32, 3);
    transpose_cb_k<<<g,256,0,stream>>>(g_w0,  gW0T, 512, 512, 512, (size_t)512*512, (size_t)512*512, 512);
    transpose_cb_k<<<g,256,0,stream>>>(mlp_w0, mW0T, 512, 512, 512, (size_t)512*512, (size_t)512*512, 512); }
  { dim3 g((512+31)/32, (512+31)/32, 2);
    transpose_cb_k<<<g,256,0,stream>>>(g_w1,  gW1Wz, 512, 512, 512, (size_t)512*512, (size_t)512*1280, 1280);
    transpose_cb_k<<<g,256,0,stream>>>(mlp_w1, mW1Wz, 512, 512, 512, (size_t)512*512, (size_t)512*1280, 1280); }
  { dim3 g((512+31)/32, (768+31)/32, 2);
    transpose_cb_k<<<g,256,0,stream>>>(g_wz + (size_t)768*512,  gW1Wz + 512, 768, 512, 768, (size_t)768*512, (size_t)512*1280, 1280);
    transpose_cb_k<<<g,256,0,stream>>>(mlp_wz + (size_t)768*512, mW1Wz + 512, 768, 512, 768, (size_t)768*512, (size_t)512*1280, 1280); }
  { dim3 g((512+31)/32, (512+31)/32, 1);
    transpose_cb_k<<<g,256,0,stream>>>(g_w1 + (size_t)2*512*512,  gW1T2, 512, 512, 512, 0, 0, 512);
    transpose_cb_k<<<g,256,0,stream>>>(mlp_w1 + (size_t)2*512*512, mW1T2, 512, 512, 512, 0, 0, 512); }
  combine_bias_k<<<8,256,0,stream>>>(mlp_b1, mlp_bz, g_b1, g_bz, CBm);

  zero_acc_k<<<1,64,0,stream>>>(ACC);
  setup_rays_k<<<5,256,0,stream>>>(pix, sK, s2in, DIR, VD, VDL);

  for (int R0=0; R0<1200; R0+=Rc){
    int rn = (1200 - R0 < Rc) ? (1200 - R0) : Rc;
    int Pc = rn*32;
    eval2_k<<<Pc,256,0,stream>>>(camT, bevT, DIR, VD, VDL,
        nullptr, 32, R0, s2in, l2c, rK, FEAT, CAT, nullptr);
    run_mlp3(stream, Pc, gWinT,g_bin, gWzT,g_bz, gW0T,g_b0, gW1Wz, CBm+1024,
             gW1T2, g_b1, g_wout, g_bout, 2, FEAT, CAT, X, OUTB);
    coarse_post_k<<<(rn+255)/256,256,0,stream>>>(OUTB, MU, STD, DALL, R0, rn);
    int Pf = rn*64;
    eval2_k<<<Pf,256,0,stream>>>(camT, bevT, DIR, VD, VDL,
        DALL, 64, R0, s2in, l2c, rK, FEAT, CAT, VF);
    run_mlp3(stream, Pf, mWinT,mlp_bin, mWzT,mlp_bz, mW0T,mlp_b0, mW1Wz, CBm,
             mW1T2, mlp_b1, mlp_wout, mlp_bout, 4, FEAT, CAT, X, OUTB);
    render_loss_w_k<<<(rn+3)/4,256,0,stream>>>(OUTB, VF, DALL, MU, STD,
        DIR, pix, src_imgs, tgt_imgs, s2tg, sK, ACC, R0, rn);
  }
  finalize_k<<<1,1,0,stream>>>(ACC, (float*)d_out);
}

// Round 6
// 2463.174 us; speedup vs baseline: 7.0403x; 1.0954x over previous
//
#include <hip/hip_runtime.h>
#include <math.h>

typedef unsigned int uint32;
typedef short bf16x8 __attribute__((ext_vector_type(8)));
typedef float f32x4 __attribute__((ext_vector_type(4)));

__device__ __forceinline__ float sigmoidf_(float x){ return 1.0f/(1.0f+expf(-x)); }
__device__ __forceinline__ float softplusf_(float x){ return x>20.0f ? x : log1pf(expf(x)); }
__device__ __forceinline__ int iclampi(int v,int lo,int hi){ return v<lo?lo:(v>hi?hi:v); }

__device__ __forceinline__ float bf2f(uint32 u){ return __uint_as_float(u<<16); }
__device__ __forceinline__ unsigned short f2bf(float f){
  uint32 x = __float_as_uint(f);
  uint32 r = (x + 0x7fffu + ((x>>16)&1u)) >> 16;
  return (unsigned short)r;
}

typedef __attribute__((address_space(1))) const unsigned int ga_u32;
typedef __attribute__((address_space(3))) unsigned int ls_u32;
__device__ __forceinline__ void gl_lds16(const unsigned short* g, unsigned short* l){
  __builtin_amdgcn_global_load_lds((ga_u32*)g, (ls_u32*)l, 16, 0, 0);
}

__device__ __forceinline__ float pe_elem(int s, float vx, float vy, float vz){
  const float F0 = 3.14159265358979f;
  if (s < 3) return s==0?vx:(s==1?vy:vz);
  s -= 3;
  bool isCos = false;
  if (s >= 18){ s -= 18; isCos = true; }
  int fi = s/3, ci = s%3;
  float v = ci==0?vx:(ci==1?vy:vz);
  float f = F0 * (float)(1<<fi);
  return isCos ? cosf(f*v) : sinf(f*v);
}

// ---- transpose+convert: in f32 [C][S] -> out bf16 [S][rowStride], cols c<Cout (zero-pad c>=C) ----
__global__ __launch_bounds__(256) void transpose_cb_k(const float* __restrict__ in,
    unsigned short* __restrict__ out, int C, int S, int Cout,
    size_t inStride, size_t outStride, int rowStride)
{
  __shared__ float tile[32][33];
  int b = blockIdx.z;
  int s0 = blockIdx.x*32, c0 = blockIdx.y*32;
  int tx = threadIdx.x & 31, ty = threadIdx.x >> 5;
  #pragma unroll
  for (int i=0;i<32;i+=8){
    int c = c0+ty+i, s = s0+tx;
    tile[ty+i][tx] = (c<C && s<S) ? in[(size_t)b*inStride + (size_t)c*S + s] : 0.0f;
  }
  __syncthreads();
  #pragma unroll
  for (int i=0;i<32;i+=8){
    int s = s0+ty+i, c = c0+tx;
    if (s<S && c<Cout) out[(size_t)b*outStride + (size_t)s*rowStride + c] = f2bf(tile[tx][ty+i]);
  }
}

// ---- combine biases: CB[w][n] = b1[i][n] + bz[i+1][n], w = {mlp i0, mlp i1, g i0, g i1} ----
__global__ void combine_bias_k(const float* __restrict__ m_b1, const float* __restrict__ m_bz,
                               const float* __restrict__ g_b1, const float* __restrict__ g_bz,
                               float* __restrict__ CB)
{
  int idx = blockIdx.x*blockDim.x + threadIdx.x;
  if (idx >= 2048) return;
  int w = idx >> 9, n = idx & 511;
  const float* b1 = (w < 2) ? m_b1 : g_b1;
  const float* bz = (w < 2) ? m_bz : g_bz;
  int i = w & 1;
  CB[idx] = b1[i*512 + n] + bz[(i+1)*512 + n];
}

// ---------------- per-ray setup: all 1200 rays ----------------
__global__ void setup_rays_k(const int* __restrict__ pix, const float* __restrict__ sK_all,
                             const float* __restrict__ s2in_all,
                             float* __restrict__ dirs, float* __restrict__ vd,
                             float* __restrict__ vdl)
{
  int r = blockIdx.x*blockDim.x + threadIdx.x;
  if (r >= 1200) return;
  int cam = r / 200;
  const float* sK = sK_all + cam*16;
  const float* s2in = s2in_all + cam*16;
  float a=sK[0],b=sK[1],c=sK[2],d=sK[4],e=sK[5],f=sK[6],g=sK[8],h=sK[9],i=sK[10];
  float det = a*(e*i-f*h) - b*(d*i-f*g) + c*(d*h-e*g);
  float inv00=(e*i-f*h)/det, inv01=(c*h-b*i)/det, inv02=(b*f-c*e)/det;
  float inv10=(f*g-d*i)/det, inv11=(a*i-c*g)/det, inv12=(c*d-a*f)/det;
  float inv20=(d*h-e*g)/det, inv21=(b*g-a*h)/det, inv22=(a*e-b*d)/det;
  int idx = pix[r];
  float x = (float)(idx % 400) * 2.0f;
  float y = (float)(idx / 400) * 2.0f;
  float dx = inv00*x + inv01*y + inv02;
  float dy = inv10*x + inv11*y + inv12;
  float dz = inv20*x + inv21*y + inv22;
  dirs[r*3+0]=dx; dirs[r*3+1]=dy; dirs[r*3+2]=dz;
  float n = sqrtf(dx*dx+dy*dy+dz*dz);
  float vx=dx/n, vy=dy/n, vz=dz/n;
  vd[r*3+0]=vx; vd[r*3+1]=vy; vd[r*3+2]=vz;
  vdl[r*3+0]=s2in[0]*vx + s2in[1]*vy + s2in[2]*vz;
  vdl[r*3+1]=s2in[4]*vx + s2in[5]*vy + s2in[6]*vz;
  vdl[r*3+2]=s2in[8]*vx + s2in[9]*vy + s2in[10]*vz;
}

// ---- point eval: feat(bf16 [P][128]) + CAT latent cols 512..1279 (bf16 [P][1280]) ----
__global__ __launch_bounds__(256) void eval2_k(
    const unsigned short* __restrict__ camT,  // [6][5600][256] bf16
    const unsigned short* __restrict__ bevT,  // [40000][512] bf16
    const float* __restrict__ dirs, const float* __restrict__ vd, const float* __restrict__ vdl,
    const float* __restrict__ dall, int ndepth, int R0,
    const float* __restrict__ s2in_all, const float* __restrict__ l2c_all, const float* __restrict__ rK_all,
    unsigned short* __restrict__ feat, unsigned short* __restrict__ cat, float* __restrict__ vf)
{
  int p  = blockIdx.x;
  int rl = p / ndepth;
  int j  = p - rl*ndepth;
  int R  = R0 + rl;
  int cam = R / 200;
  const float* s2in = s2in_all + cam*16;
  const float* l2c  = l2c_all + cam*16;
  const float* rK   = rK_all + cam*16;
  float dx = dirs[R*3+0], dy = dirs[R*3+1], dz = dirs[R*3+2];
  float d = dall ? dall[(size_t)rl*ndepth + j] : (((float)j + 0.5f)/32.0f)*100.0f;
  float px = dx*d, py = dy*d, pz = dz*d;
  float lx = s2in[0]*px + s2in[1]*py + s2in[2]*pz + s2in[3];
  float ly = s2in[4]*px + s2in[5]*py + s2in[6]*pz + s2in[7];
  float lz = s2in[8]*px + s2in[9]*py + s2in[10]*pz + s2in[11];
  float ccx = l2c[0]*lx + l2c[1]*ly + l2c[2]*lz + l2c[3];
  float ccy = l2c[4]*lx + l2c[5]*ly + l2c[6]*lz + l2c[7];
  float ccz = l2c[8]*lx + l2c[9]*ly + l2c[10]*lz + l2c[11];
  float zs = fmaxf(ccz, 0.001f);
  float uu = rK[0]*ccx + rK[1]*ccy + rK[2]*ccz;
  float vv = rK[4]*ccx + rK[5]*ccy + rK[6]*ccz;
  float fu = uu/zs*(100.0f/1600.0f);
  float fv = vv/zs*(56.0f/900.0f);
  bool cvalid = (fu>=0.0f)&&(fu<=99.0f)&&(fv>=0.0f)&&(fv<=55.0f)&&(ccz>0.1f);
  float cfx0 = floorf(fu), cfy0 = floorf(fv);
  int cx0=iclampi((int)cfx0,0,99), cx1=iclampi(cx0+1,0,99);
  int cy0=iclampi((int)cfy0,0,55), cy1=iclampi(cy0+1,0,55);
  float cwx=fu-cfx0, cwy=fv-cfy0;
  float cw00=(1-cwx)*(1-cwy), cw01=cwx*(1-cwy), cw10=(1-cwx)*cwy, cw11=cwx*cwy;
  float bx = (lx+51.2f)/102.4f*199.0f;
  float by = (ly+51.2f)/102.4f*199.0f;
  bool bvalid = (bx>=0.0f)&&(bx<=199.0f)&&(by>=0.0f)&&(by<=199.0f);
  float bfx0=floorf(bx), bfy0=floorf(by);
  int bx0=iclampi((int)bfx0,0,199), bx1=iclampi(bx0+1,0,199);
  int by0=iclampi((int)bfy0,0,199), by1=iclampi(by0+1,0,199);
  float bwx=bx-bfx0, bwy=by-bfy0;
  float bw00=(1-bwx)*(1-bwy), bw01=bwx*(1-bwy), bw10=(1-bwx)*bwy, bw11=bwx*bwy;
  float vflag = (cvalid && bvalid) ? 1.0f : 0.0f;
  int t = threadIdx.x;
  uint32* catrow = (uint32*)(cat + (size_t)p*1280);
  { // bev -> CAT cols 512..1023
    size_t sb00 = (size_t)(by0*200+bx0)*512, sb01 = (size_t)(by0*200+bx1)*512;
    size_t sb10 = (size_t)(by1*200+bx0)*512, sb11 = (size_t)(by1*200+bx1)*512;
    uint32 u00 = ((const uint32*)(bevT + sb00))[t];
    uint32 u01 = ((const uint32*)(bevT + sb01))[t];
    uint32 u10 = ((const uint32*)(bevT + sb10))[t];
    uint32 u11 = ((const uint32*)(bevT + sb11))[t];
    float lo = bw00*bf2f(u00&0xffffu) + bw01*bf2f(u01&0xffffu) + bw10*bf2f(u10&0xffffu) + bw11*bf2f(u11&0xffffu);
    float hi = bw00*bf2f(u00>>16) + bw01*bf2f(u01>>16) + bw10*bf2f(u10>>16) + bw11*bf2f(u11>>16);
    lo *= vflag; hi *= vflag;
    catrow[256 + t] = (uint32)f2bf(lo) | ((uint32)f2bf(hi)<<16);
  }
  if (t < 128){ // cam -> CAT cols 1024..1279
    const unsigned short* cfT = camT + (size_t)cam*5600*256;
    size_t sc00 = (size_t)(cy0*100+cx0)*256, sc01 = (size_t)(cy0*100+cx1)*256;
    size_t sc10 = (size_t)(cy1*100+cx0)*256, sc11 = (size_t)(cy1*100+cx1)*256;
    uint32 u00 = ((const uint32*)(cfT + sc00))[t];
    uint32 u01 = ((const uint32*)(cfT + sc01))[t];
    uint32 u10 = ((const uint32*)(cfT + sc10))[t];
    uint32 u11 = ((const uint32*)(cfT + sc11))[t];
    float lo = cw00*bf2f(u00&0xffffu) + cw01*bf2f(u01&0xffffu) + cw10*bf2f(u10&0xffffu) + cw11*bf2f(u11&0xffffu);
    float hi = cw00*bf2f(u00>>16) + cw01*bf2f(u01>>16) + cw10*bf2f(u10>>16) + cw11*bf2f(u11>>16);
    lo *= vflag; hi *= vflag;
    catrow[512 + t] = (uint32)f2bf(lo) | ((uint32)f2bf(hi)<<16);
  }
  if (t < 128){
    float val = 0.0f;
    if (t < 84){
      float plx = lx/51.2f, ply = ly/51.2f, plz = (lz+1.0f)/4.0f;
      float pcx = px/100.0f, pcy = py/100.0f, pcz = pz/100.0f;
      float vx=vd[R*3], vy=vd[R*3+1], vz=vd[R*3+2];
      float wx=vdl[R*3], wy=vdl[R*3+1], wz=vdl[R*3+2];
      if (t < 39)      val = pe_elem(t, plx, ply, plz);
      else if (t < 42) val = (t==39)?wx:((t==40)?wy:wz);
      else if (t < 81) val = pe_elem(t-42, pcx, pcy, pcz);
      else             val = (t==81)?vx:((t==82)?vy:vz);
    }
    feat[(size_t)p*128 + t] = f2bf(val);
  }
  if (vf && t==0) vf[p] = vflag;
}

// ---------------- MFMA bf16 GEMM, m97 structure ----------------
// C[M][N=512] = [C +] A @ BT^T + bias.  global_load_lds width-16 staging with
// pre-swizzled per-lane source (linear LDS dest), XOR-swizzled ds_read_b128,
// 128x128 tile (4 waves x 64x64). Optional XR = relu(C) secondary output.
// XCD-bijective swizzle: 4 col panels of one row panel -> same XCD, adjacent.
#define GBM 128
#define GBN 128
#define GBK 64
template<int ACC, int RELU_OUT, int WRITE_XR>
__global__ __launch_bounds__(256) void mgemm_k(
    const unsigned short* __restrict__ A, int lda,
    const unsigned short* __restrict__ BT,
    const float* __restrict__ bias,
    unsigned short* __restrict__ C, int ldc,
    unsigned short* __restrict__ XR,
    int M, int N, int K)
{
  __shared__ unsigned short As[GBM*GBK];  // 16 KB
  __shared__ unsigned short Bs[GBN*GBK];  // 16 KB
  int w = blockIdx.x;
  int xcd = w & 7, ii = w >> 3;
  int colp = ii & 3, rgrp = ii >> 2;
  int rowp = rgrp*8 + xcd;
  int row0 = rowp*GBM, col0 = colp*GBN;
  if (row0 >= M) return;
  int tid = threadIdx.x;
  int lane = tid & 63, wave = tid >> 6;
  int wm = wave >> 1, wn = wave & 1;
  int l15 = lane & 15, l4 = lane >> 4;
  int lrow = lane >> 3;        // row within the 8-row group this lane stages
  int lch  = lane & 7;         // 16B chunk index
  int chsw = (lch ^ lrow) * 8; // pre-swizzled source chunk offset (shorts); rr&7 == lrow
  // staging base pointers (lane-dependent source, wave-uniform LDS dest)
  const unsigned short* aptr = A  + (size_t)(row0 + wave*32 + lrow)*lda + chsw;
  const unsigned short* bptr = BT + (size_t)(col0 + wave*32 + lrow)*K   + chsw;
  unsigned short* asl = &As[(wave*32)*64];
  unsigned short* bsl = &Bs[(wave*32)*64];

  f32x4 acc[4][4];
  #pragma unroll
  for (int mi=0;mi<4;++mi)
    #pragma unroll
    for (int nj=0;nj<4;++nj){ f32x4 z = {0.f,0.f,0.f,0.f}; acc[mi][nj] = z; }

  for (int k0 = 0; k0 < K; k0 += GBK){
    #pragma unroll
    for (int i=0;i<4;++i) gl_lds16(aptr + (size_t)i*8*lda + k0, asl + i*8*64);
    #pragma unroll
    for (int i=0;i<4;++i) gl_lds16(bptr + (size_t)i*8*K   + k0, bsl + i*8*64);
    __syncthreads();                       // vmcnt(0) drain + barrier
    #pragma unroll
    for (int ks=0; ks<2; ++ks){
      bf16x8 a[4], b[4];
      #pragma unroll
      for (int mi=0;mi<4;++mi){
        int row = wm*64 + mi*16 + l15;
        int sc = (ks*4 + l4) ^ (row&7);
        a[mi] = *(const bf16x8*)&As[row*64 + sc*8];
      }
      #pragma unroll
      for (int nj=0;nj<4;++nj){
        int colr = wn*64 + nj*16 + l15;
        int sc = (ks*4 + l4) ^ (colr&7);
        b[nj] = *(const bf16x8*)&Bs[colr*64 + sc*8];
      }
      #pragma unroll
      for (int mi=0;mi<4;++mi)
        #pragma unroll
        for (int nj=0;nj<4;++nj)
          acc[mi][nj] = __builtin_amdgcn_mfma_f32_16x16x32_bf16(a[mi], b[nj], acc[mi][nj], 0,0,0);
    }
    __syncthreads();                       // protect LDS before next stage
  }
  #pragma unroll
  for (int mi=0;mi<4;++mi){
    int gr0 = row0 + wm*64 + mi*16 + l4*4;
    #pragma unroll
    for (int nj=0;nj<4;++nj){
      int gc = col0 + wn*64 + nj*16 + l15;
      if (gc >= N) continue;
      float bv = bias[gc];
      #pragma unroll
      for (int i=0;i<4;++i){
        int gr = gr0 + i;
        if (gr >= M) continue;
        float v = acc[mi][nj][i] + bv;
        if (ACC) v += bf2f((uint32)C[(size_t)gr*ldc + gc]);
        if (RELU_OUT) v = fmaxf(v, 0.0f);
        C[(size_t)gr*ldc + gc] = f2bf(v);
        if (WRITE_XR) XR[(size_t)gr*512 + gc] = f2bf(fmaxf(v, 0.0f));
      }
    }
  }
}

static inline int gemm_grid(int M){
  int nrow = (M + GBM - 1)/GBM;
  int nrowp = (nrow + 7) & ~7;   // pad to multiple of 8 for bijective XCD swizzle
  return nrowp * 4;              // 4 col panels (N=512)
}

// ---------------- out layer, wave per row ----------------
__global__ __launch_bounds__(256) void outlayer_w_k(const unsigned short* __restrict__ X,
    const float* __restrict__ W, const float* __restrict__ b, float* __restrict__ O,
    int M, int dout)
{
  int wid = threadIdx.x >> 6, lane = threadIdx.x & 63;
  int row = blockIdx.x*4 + wid;
  if (row >= M) return;
  const unsigned short* xr = X + (size_t)row*512;
  float s[4] = {0,0,0,0};
  for (int k=lane; k<512; k+=64){
    float xv = fmaxf(bf2f((uint32)xr[k]), 0.0f);
    #pragma unroll
    for (int c=0;c<4;++c)
      if (c < dout) s[c] += xv * W[(size_t)k*dout + c];
  }
  #pragma unroll
  for (int c=0;c<4;++c)
    #pragma unroll
    for (int m=32;m;m>>=1) s[c] += __shfl_xor(s[c], m, 64);
  if (lane == 0)
    for (int c=0;c<dout;++c) O[(size_t)row*dout + c] = s[c] + b[c];
}

// ---------------- coarse post ----------------
__global__ void coarse_post_k(const float* __restrict__ OUTB, float* __restrict__ MU,
                              float* __restrict__ STD, float* __restrict__ DALL,
                              int R0, int rn)
{
  int rl = blockIdx.x*blockDim.x + threadIdx.x;
  if (rl >= rn) return;
  int R = R0 + rl;
  float mu[4], sd[4];
  for (int g=0; g<4; ++g){
    float lg[8], sv[8], mx = -1e30f;
    for (int pp=0; pp<8; ++pp){
      int j = g*8+pp;
      lg[pp] = OUTB[((size_t)rl*32 + j)*2 + 0];
      sv[pp] = OUTB[((size_t)rl*32 + j)*2 + 1];
      mx = fmaxf(mx, lg[pp]);
    }
    float se = 0.0f;
    for (int pp=0; pp<8; ++pp){ lg[pp] = expf(lg[pp]-mx); se += lg[pp]; }
    float m=0.0f, s=0.0f;
    for (int pp=0; pp<8; ++pp){
      float wgt = lg[pp]/se;
      float du = (((float)(g*8+pp)+0.5f)/32.0f)*100.0f;
      m += wgt*du; s += wgt*sv[pp];
    }
    mu[g]=m; sd[g]=softplusf_(s)+0.1f;
    MU[R*4+g]=mu[g]; STD[R*4+g]=sd[g];
  }
  float da[64];
  for (int j=0;j<32;++j) da[j] = (((float)j+0.5f)/32.0f)*100.0f;
  for (int g=0; g<4; ++g)
    for (int pp=0; pp<8; ++pp){
      float off = -2.0f + (4.0f/7.0f)*(float)pp;
      float v = mu[g] + sd[g]*off;
      v = fminf(fmaxf(v, 0.5f), 100.0f);
      da[32 + g*8+pp] = v;
    }
  for (int i=1;i<64;++i){ float key=da[i]; int k=i-1;
    while (k>=0 && da[k]>key){ da[k+1]=da[k]; --k; } da[k+1]=key; }
  for (int j=0;j<64;++j) DALL[(size_t)rl*64+j] = da[j];
}

__device__ __forceinline__ void bilin_img(const float* __restrict__ img, int H, int W,
                                          float u, float v, float* out3, bool* valid)
{
  *valid = (u>=0.0f)&&(u<=(float)(W-1))&&(v>=0.0f)&&(v<=(float)(H-1));
  float fx0=floorf(u), fy0=floorf(v);
  int x0=iclampi((int)fx0,0,W-1), x1=iclampi(x0+1,0,W-1);
  int y0=iclampi((int)fy0,0,H-1), y1=iclampi(y0+1,0,H-1);
  float wx=u-fx0, wy=v-fy0;
  float w00=(1-wx)*(1-wy), w01=wx*(1-wy), w10=(1-wx)*wy, w11=wx*wy;
  for (int ch=0; ch<3; ++ch){
    const float* p = img + (size_t)ch*H*W;
    out3[ch] = w00*p[y0*W+x0] + w01*p[y0*W+x1] + w10*p[y1*W+x0] + w11*p[y1*W+x1];
  }
}

// ---------------- render + losses, one wave per ray ----------------
__global__ __launch_bounds__(256) void render_loss_w_k(
  const float* __restrict__ OUTB, const float* __restrict__ VF,
  const float* __restrict__ DALL, const float* __restrict__ MU, const float* __restrict__ STD,
  const float* __restrict__ dirs, const int* __restrict__ pix,
  const float* __restrict__ src_imgs, const float* __restrict__ tgt_imgs,
  const float* __restrict__ s2tg_all, const float* __restrict__ sK_all,
  float* __restrict__ acc, int R0, int rn)
{
  int wid = threadIdx.x >> 6, lane = threadIdx.x & 63;
  int rl = blockIdx.x*4 + wid;
  if (rl >= rn) return;
  int R = R0 + rl;
  int cam = R / 200;
  int j = lane;
  float dj = DALL[(size_t)rl*64 + j];
  float delta = (j<63) ? (DALL[(size_t)rl*64 + j + 1] - dj) : 1000.0f;
  f32x4 o = *(const f32x4*)(OUTB + ((size_t)rl*64 + j)*4);
  float vfp = VF[(size_t)rl*64 + j];
  float sg = softplusf_(o[3])*vfp;
  float alpha = 1.0f - expf(-sg*delta);
  float prod = 1.0f - alpha + 1e-10f;
  #pragma unroll
  for (int dstep=1; dstep<64; dstep<<=1){
    float v = __shfl_up(prod, dstep, 64);
    if (lane >= dstep) prod *= v;
  }
  float T = __shfl_up(prod, 1, 64);
  if (lane == 0) T = 1.0f;
  float w = alpha*T;
  float c0 = w*sigmoidf_(o[0]), c1 = w*sigmoidf_(o[1]), c2 = w*sigmoidf_(o[2]);
  float dsum = w*dj, vs = vfp;
  #pragma unroll
  for (int m=32;m;m>>=1){
    c0 += __shfl_xor(c0,m,64); c1 += __shfl_xor(c1,m,64); c2 += __shfl_xor(c2,m,64);
    dsum += __shfl_xor(dsum,m,64); vs += __shfl_xor(vs,m,64);
  }
  float depth = dsum, rvr = vs/64.0f;
  float mu[4], sd[4];
  #pragma unroll
  for (int g=0;g<4;++g){ mu[g]=MU[R*4+g]; sd[g]=STD[R*4+g]; }
  float e[4], mx=-1e30f;
  #pragma unroll
  for (int g=0;g<4;++g){ float dd=dj-mu[g]; e[g]=-dd*dd*0.125f; mx=fmaxf(mx,e[g]); }
  float se=0;
  #pragma unroll
  for (int g=0;g<4;++g){ e[g]=expf(e[g]-mx); se+=e[g]; }
  float rw[4];
  #pragma unroll
  for (int g=0;g<4;++g) rw[g] = e[g]/se*w + 1e-8f;
  float srw[4], srwd[4];
  #pragma unroll
  for (int g=0;g<4;++g){ srw[g]=rw[g]; srwd[g]=rw[g]*dj; }
  #pragma unroll
  for (int m=32;m;m>>=1){
    #pragma unroll
    for (int g=0;g<4;++g){ srw[g]+=__shfl_xor(srw[g],m,64); srwd[g]+=__shfl_xor(srwd[g],m,64); }
  }
  float smean[4];
  #pragma unroll
  for (int g=0;g<4;++g) smean[g]=srwd[g]/srw[g];
  float sv[4];
  #pragma unroll
  for (int g=0;g<4;++g){ float dd=dj-smean[g]; sv[g]=rw[g]*dd*dd; }
  #pragma unroll
  for (int m=32;m;m>>=1){
    #pragma unroll
    for (int g=0;g<4;++g) sv[g]+=__shfl_xor(sv[g],m,64);
  }
  if (lane != 0) return;
  float klsum=0;
  #pragma unroll
  for (int g=0;g<4;++g){
    float var = sv[g]/srw[g];
    float sstd = sqrtf(var + 1e-6f);
    float dm = mu[g]-smean[g];
    klsum += logf(sstd/sd[g]) + (sd[g]*sd[g] + dm*dm)/(2.0f*(var+1e-6f)) - 0.5f;
  }
  float mind=1e30f;
  #pragma unroll
  for (int g=0;g<4;++g) mind = fminf(mind, fabsf(mu[g]-depth));
  const float* si = src_imgs + (size_t)cam*3*300*800;
  const float* ti = tgt_imgs + (size_t)cam*3*300*800;
  const float* s2tg = s2tg_all + cam*16;
  const float* sK = sK_all + cam*16;
  int idx = pix[R];
  float x = (float)(idx % 400) * 2.0f;
  float y = (float)(idx / 400) * 2.0f;
  float csrc[3]; bool sval;
  bilin_img(si, 300, 800, x, y, csrc, &sval);
  if (!sval){ csrc[0]=0; csrc[1]=0; csrc[2]=0; }
  float csum = fabsf(csrc[0]-c0)+fabsf(csrc[1]-c1)+fabsf(csrc[2]-c2);
  float dx=dirs[R*3], dy=dirs[R*3+1], dz=dirs[R*3+2];
  float px=dx*depth, py=dy*depth, pz=dz*depth;
  float tx=s2tg[0]*px+s2tg[1]*py+s2tg[2]*pz+s2tg[3];
  float ty=s2tg[4]*px+s2tg[5]*py+s2tg[6]*pz+s2tg[7];
  float tz=s2tg[8]*px+s2tg[9]*py+s2tg[10]*pz+s2tg[11];
  float zt=fmaxf(tz,0.001f);
  float uu=(sK[0]*tx+sK[1]*ty+sK[2]*tz)/zt;
  float vv=(sK[4]*tx+sK[5]*ty+sK[6]*tz)/zt;
  float pred[3]; bool tval;
  bilin_img(ti, 300, 800, uu, vv, pred, &tval);
  float tvf = tval?1.0f:0.0f;
  pred[0]*=tvf; pred[1]*=tvf; pred[2]*=tvf;
  float mask = (tval && (tz>0.1f) && (depth<30.0f)) ? 1.0f : 0.0f;
  float l1 = (fabsf(pred[0]-csrc[0])+fabsf(pred[1]-csrc[1])+fabsf(pred[2]-csrc[2]))*(1.0f/3.0f);
  float* a = acc + cam*8;
  atomicAdd(&a[0], csum*rvr);
  atomicAdd(&a[1], klsum);
  atomicAdd(&a[2], mind);
  atomicAdd(&a[3], l1*mask);
  atomicAdd(&a[4], mask);
}

__global__ void zero_acc_k(float* a){ a[threadIdx.x] = 0.0f; }

__global__ void finalize_k(const float* __restrict__ acc, float* __restrict__ out){
  if (threadIdx.x==0 && blockIdx.x==0){
    float tot = 0.0f;
    for (int c=0;c<6;++c){
      const float* a = acc + c*8;
      float lc  = a[0] / 600.0f;
      float lkl = a[1] / 800.0f;
      float ld  = a[2] / 200.0f;
      float lr  = a[3] / (a[4] + 1e-6f);
      if (lr != lr) lr = 0.0f;
      tot += lc + lkl + 0.01f*ld + lr;
    }
    out[0] = tot / 6.0f;
  }
}

// ---------------- host-side MLP driver ----------------
// CAT layout: [H(512) | bev(512) | cam(256)] bf16, stride 1280.
// X: residual (bf16). XR: relu(X) copy maintained by GEMM epilogues.
static void run_mlp4(hipStream_t stream, int M,
   const unsigned short* WinT, const float* bin,
   const unsigned short* WzT,  const float* bz,
   const unsigned short* W0T,  const float* b0,
   const unsigned short* W1Wz, const float* CB,
   const unsigned short* W1T2, const float* b1,
   const float* wout, const float* bout, int dout,
   const unsigned short* FEAT, unsigned short* CAT,
   unsigned short* X, unsigned short* XR, float* OUTB)
{
  int g = gemm_grid(M);
  mgemm_k<0,0,1><<<g,256,0,stream>>>(FEAT, 128, WinT, bin, X, 512, XR, M, 512, 128);
  mgemm_k<1,0,1><<<g,256,0,stream>>>(CAT+512, 1280, WzT, bz, X, 512, XR, M, 512, 768);
  for (int i=0;i<2;++i){
    mgemm_k<0,1,0><<<g,256,0,stream>>>(XR, 512, W0T + (size_t)i*512*512, b0 + i*512, CAT, 1280, nullptr, M, 512, 512);
    mgemm_k<1,0,1><<<g,256,0,stream>>>(CAT, 1280, W1Wz + (size_t)i*512*1280, CB + i*512, X, 512, XR, M, 512, 1280);
  }
  mgemm_k<0,1,0><<<g,256,0,stream>>>(XR, 512, W0T + (size_t)2*512*512, b0 + 2*512, CAT, 1280, nullptr, M, 512, 512);
  mgemm_k<1,0,0><<<g,256,0,stream>>>(CAT, 1280, W1T2, b1 + 2*512, X, 512, nullptr, M, 512, 512);
  outlayer_w_k<<<(M+3)/4, 256, 0, stream>>>(X, wout, bout, OUTB, M, dout);
}

extern "C" void kernel_launch(void* const* d_in, const int* in_sizes, int n_in,
                              void* d_out, int out_size, void* d_ws, size_t ws_size,
                              hipStream_t stream) {
  (void)in_sizes; (void)n_in; (void)out_size;
  const float* cam_feat = (const float*)d_in[0];
  const float* bev_feat = (const float*)d_in[1];
  const float* src_imgs = (const float*)d_in[2];
  const float* tgt_imgs = (const float*)d_in[3];
  const float* rK   = (const float*)d_in[4];
  const float* sK   = (const float*)d_in[5];
  const float* l2c  = (const float*)d_in[6];
  const float* s2in = (const float*)d_in[7];
  const float* s2tg = (const float*)d_in[8];
  const int*   pix  = (const int*)d_in[9];
  const float* mlp_win = (const float*)d_in[10];
  const float* mlp_bin = (const float*)d_in[11];
  const float* mlp_wz  = (const float*)d_in[12];
  const float* mlp_bz  = (const float*)d_in[13];
  const float* mlp_w0  = (const float*)d_in[14];
  const float* mlp_b0  = (const float*)d_in[15];
  const float* mlp_w1  = (const float*)d_in[16];
  const float* mlp_b1  = (const float*)d_in[17];
  const float* mlp_wout= (const float*)d_in[18];
  const float* mlp_bout= (const float*)d_in[19];
  const float* g_win = (const float*)d_in[20];
  const float* g_bin = (const float*)d_in[21];
  const float* g_wz  = (const float*)d_in[22];
  const float* g_bz  = (const float*)d_in[23];
  const float* g_w0  = (const float*)d_in[24];
  const float* g_b0  = (const float*)d_in[25];
  const float* g_w1  = (const float*)d_in[26];
  const float* g_b1  = (const float*)d_in[27];
  const float* g_wout= (const float*)d_in[28];
  const float* g_bout= (const float*)d_in[29];

  char* base = (char*)d_ws;
  size_t off = 0;
  auto alloc = [&](size_t bytes)->char*{
    char* p = base + off;
    off = (off + bytes + 255) & ~(size_t)255;
    return p;
  };
  float* ACC  = (float*)alloc(64*4);
  float* DIR  = (float*)alloc(3600*4);
  float* VD   = (float*)alloc(3600*4);
  float* VDL  = (float*)alloc(3600*4);
  float* MU   = (float*)alloc(4800*4);
  float* STD  = (float*)alloc(4800*4);
  float* CBm  = (float*)alloc(2048*4);
  unsigned short* bevT = (unsigned short*)alloc((size_t)40000*512*2);
  unsigned short* camT = (unsigned short*)alloc((size_t)6*5600*256*2);
  unsigned short* gWinT = (unsigned short*)alloc((size_t)512*128*2);
  unsigned short* mWinT = (unsigned short*)alloc((size_t)512*128*2);
  unsigned short* gWzT  = (unsigned short*)alloc((size_t)512*768*2);
  unsigned short* mWzT  = (unsigned short*)alloc((size_t)512*768*2);
  unsigned short* gW0T  = (unsigned short*)alloc((size_t)3*512*512*2);
  unsigned short* mW0T  = (unsigned short*)alloc((size_t)3*512*512*2);
  unsigned short* gW1Wz = (unsigned short*)alloc((size_t)2*512*1280*2);
  unsigned short* mW1Wz = (unsigned short*)alloc((size_t)2*512*1280*2);
  unsigned short* gW1T2 = (unsigned short*)alloc((size_t)512*512*2);
  unsigned short* mW1T2 = (unsigned short*)alloc((size_t)512*512*2);
  size_t fixed = off;
  // per-ray bytes: dall 256 + feat 16384 + cat 163840 + x 65536 + xr 65536 + out 1024 + vf 256
  const size_t perray = 256 + 16384 + 163840 + 65536 + 65536 + 1024 + 256;
  const size_t SLACK = 512*1024;  // OOB-staging slack for partial panels
  int Rc = 1200;
  {
    size_t need = fixed + (size_t)1200*perray + SLACK + 8192;
    if (need > ws_size){
      size_t avail = (ws_size > fixed + SLACK + 8192) ? (ws_size - fixed - SLACK - 8192) : perray;
      Rc = (int)(avail / perray);
      if (Rc < 1) Rc = 1;
      if (Rc > 1200) Rc = 1200;
    }
  }
  float*          DALL = (float*)alloc((size_t)Rc*64*4);
  unsigned short* FEAT = (unsigned short*)alloc((size_t)Rc*64*128*2);
  unsigned short* CAT  = (unsigned short*)alloc((size_t)Rc*64*1280*2);
  unsigned short* X    = (unsigned short*)alloc((size_t)Rc*64*512*2);
  unsigned short* XR   = (unsigned short*)alloc((size_t)Rc*64*512*2);
  float*          OUTB = (float*)alloc((size_t)Rc*64*4*4);
  float*          VF   = (float*)alloc((size_t)Rc*64*4);

  // ---- transposes / weight prep ----
  { dim3 g((40000+31)/32, (512+31)/32, 1);
    transpose_cb_k<<<g,256,0,stream>>>(bev_feat, bevT, 512, 40000, 512, 0, 0, 512); }
  { dim3 g((5600+31)/32, (256+31)/32, 6);
    transpose_cb_k<<<g,256,0,stream>>>(cam_feat, camT, 256, 5600, 256, (size_t)256*5600, (size_t)5600*256, 256); }
  { dim3 g((512+31)/32, (128+31)/32, 1);
    transpose_cb_k<<<g,256,0,stream>>>(g_win,  gWinT, 84, 512, 128, 0, 0, 128);
    transpose_cb_k<<<g,256,0,stream>>>(mlp_win, mWinT, 84, 512, 128, 0, 0, 128); }
  { dim3 g((512+31)/32, (768+31)/32, 1);
    transpose_cb_k<<<g,256,0,stream>>>(g_wz,  gWzT, 768, 512, 768, 0, 0, 768);
    transpose_cb_k<<<g,256,0,stream>>>(mlp_wz, mWzT, 768, 512, 768, 0, 0, 768); }
  { dim3 g((512+31)/32, (512+31)/32, 3);
    transpose_cb_k<<<g,256,0,stream>>>(g_w0,  gW0T, 512, 512, 512, (size_t)512*512, (size_t)512*512, 512);
    transpose_cb_k<<<g,256,0,stream>>>(mlp_w0, mW0T, 512, 512, 512, (size_t)512*512, (size_t)512*512, 512); }
  { dim3 g((512+31)/32, (512+31)/32, 2);
    transpose_cb_k<<<g,256,0,stream>>>(g_w1,  gW1Wz, 512, 512, 512, (size_t)512*512, (size_t)512*1280, 1280);
    transpose_cb_k<<<g,256,0,stream>>>(mlp_w1, mW1Wz, 512, 512, 512, (size_t)512*512, (size_t)512*1280, 1280); }
  { dim3 g((512+31)/32, (768+31)/32, 2);
    transpose_cb_k<<<g,256,0,stream>>>(g_wz + (size_t)768*512,  gW1Wz + 512, 768, 512, 768, (size_t)768*512, (size_t)512*1280, 1280);
    transpose_cb_k<<<g,256,0,stream>>>(mlp_wz + (size_t)768*512, mW1Wz + 512, 768, 512, 768, (size_t)768*512, (size_t)512*1280, 1280); }
  { dim3 g((512+31)/32, (512+31)/32, 1);
    transpose_cb_k<<<g,256,0,stream>>>(g_w1 + (size_t)2*512*512,  gW1T2, 512, 512, 512, 0, 0, 512);
    transpose_cb_k<<<g,256,0,stream>>>(mlp_w1 + (size_t)2*512*512, mW1T2, 512, 512, 512, 0, 0, 512); }
  combine_bias_k<<<8,256,0,stream>>>(mlp_b1, mlp_bz, g_b1, g_bz, CBm);

  zero_acc_k<<<1,64,0,stream>>>(ACC);
  setup_rays_k<<<5,256,0,stream>>>(pix, sK, s2in, DIR, VD, VDL);

  for (int R0=0; R0<1200; R0+=Rc){
    int rn = (1200 - R0 < Rc) ? (1200 - R0) : Rc;
    int Pc = rn*32;
    eval2_k<<<Pc,256,0,stream>>>(camT, bevT, DIR, VD, VDL,
        nullptr, 32, R0, s2in, l2c, rK, FEAT, CAT, nullptr);
    run_mlp4(stream, Pc, gWinT,g_bin, gWzT,g_bz, gW0T,g_b0, gW1Wz, CBm+1024,
             gW1T2, g_b1, g_wout, g_bout, 2, FEAT, CAT, X, XR, OUTB);
    coarse_post_k<<<(rn+255)/256,256,0,stream>>>(OUTB, MU, STD, DALL, R0, rn);
    int Pf = rn*64;
    eval2_k<<<Pf,256,0,stream>>>(camT, bevT, DIR, VD, VDL,
        DALL, 64, R0, s2in, l2c, rK, FEAT, CAT, VF);
    run_mlp4(stream, Pf, mWinT,mlp_bin, mWzT,mlp_bz, mW0T,mlp_b0, mW1Wz, CBm,
             mW1T2, mlp_b1, mlp_wout, mlp_bout, 4, FEAT, CAT, X, XR, OUTB);
    render_loss_w_k<<<(rn+3)/4,256,0,stream>>>(OUTB, VF, DALL, MU, STD,
        DIR, pix, src_imgs, tgt_imgs, s2tg, sK, ACC, R0, rn);
  }
  finalize_k<<<1,1,0,stream>>>(ACC, (float*)d_out);
}

// Round 7
// 2120.576 us; speedup vs baseline: 8.1777x; 1.1616x over previous
//
#include <hip/hip_runtime.h>
#include <math.h>

typedef unsigned int uint32;
typedef short bf16x8 __attribute__((ext_vector_type(8)));
typedef float f32x4 __attribute__((ext_vector_type(4)));

__device__ __forceinline__ float sigmoidf_(float x){ return 1.0f/(1.0f+expf(-x)); }
__device__ __forceinline__ float softplusf_(float x){ return x>20.0f ? x : log1pf(expf(x)); }
__device__ __forceinline__ int iclampi(int v,int lo,int hi){ return v<lo?lo:(v>hi?hi:v); }

__device__ __forceinline__ float bf2f(uint32 u){ return __uint_as_float(u<<16); }
__device__ __forceinline__ unsigned short f2bf(float f){
  uint32 x = __float_as_uint(f);
  uint32 r = (x + 0x7fffu + ((x>>16)&1u)) >> 16;
  return (unsigned short)r;
}

typedef __attribute__((address_space(1))) const unsigned int ga_u32;
typedef __attribute__((address_space(3))) unsigned int ls_u32;
__device__ __forceinline__ void gl_lds16(const unsigned short* g, unsigned short* l){
  __builtin_amdgcn_global_load_lds((ga_u32*)g, (ls_u32*)l, 16, 0, 0);
}

__device__ __forceinline__ float pe_elem(int s, float vx, float vy, float vz){
  const float F0 = 3.14159265358979f;
  if (s < 3) return s==0?vx:(s==1?vy:vz);
  s -= 3;
  bool isCos = false;
  if (s >= 18){ s -= 18; isCos = true; }
  int fi = s/3, ci = s%3;
  float v = ci==0?vx:(ci==1?vy:vz);
  float f = F0 * (float)(1<<fi);
  return isCos ? cosf(f*v) : sinf(f*v);
}

// ---- transpose+convert: in f32 [C][S] -> out bf16 [S][rowStride], cols c<Cout (zero-pad c>=C) ----
__global__ __launch_bounds__(256) void transpose_cb_k(const float* __restrict__ in,
    unsigned short* __restrict__ out, int C, int S, int Cout,
    size_t inStride, size_t outStride, int rowStride)
{
  __shared__ float tile[32][33];
  int b = blockIdx.z;
  int s0 = blockIdx.x*32, c0 = blockIdx.y*32;
  int tx = threadIdx.x & 31, ty = threadIdx.x >> 5;
  #pragma unroll
  for (int i=0;i<32;i+=8){
    int c = c0+ty+i, s = s0+tx;
    tile[ty+i][tx] = (c<C && s<S) ? in[(size_t)b*inStride + (size_t)c*S + s] : 0.0f;
  }
  __syncthreads();
  #pragma unroll
  for (int i=0;i<32;i+=8){
    int s = s0+ty+i, c = c0+tx;
    if (s<S && c<Cout) out[(size_t)b*outStride + (size_t)s*rowStride + c] = f2bf(tile[tx][ty+i]);
  }
}

// ---- combined biases: w0..3 = {mlp i0, mlp i1, g i0, g i1}: b1[i]+bz[i+1];
//      w4 = mlp bin+bz0; w5 = g bin+bz0
__global__ void combine_bias_k(const float* __restrict__ m_b1, const float* __restrict__ m_bz,
                               const float* __restrict__ g_b1, const float* __restrict__ g_bz,
                               const float* __restrict__ m_bin, const float* __restrict__ g_bin,
                               float* __restrict__ CB)
{
  int idx = blockIdx.x*blockDim.x + threadIdx.x;
  if (idx >= 3072) return;
  int w = idx >> 9, n = idx & 511;
  float v;
  if (w < 4){
    const float* b1 = (w < 2) ? m_b1 : g_b1;
    const float* bz = (w < 2) ? m_bz : g_bz;
    int i = w & 1;
    v = b1[i*512 + n] + bz[(i+1)*512 + n];
  } else if (w == 4) v = m_bin[n] + m_bz[n];
  else               v = g_bin[n] + g_bz[n];
  CB[idx] = v;
}

// ---------------- per-ray setup: all 1200 rays ----------------
__global__ void setup_rays_k(const int* __restrict__ pix, const float* __restrict__ sK_all,
                             const float* __restrict__ s2in_all,
                             float* __restrict__ dirs, float* __restrict__ vd,
                             float* __restrict__ vdl)
{
  int r = blockIdx.x*blockDim.x + threadIdx.x;
  if (r >= 1200) return;
  int cam = r / 200;
  const float* sK = sK_all + cam*16;
  const float* s2in = s2in_all + cam*16;
  float a=sK[0],b=sK[1],c=sK[2],d=sK[4],e=sK[5],f=sK[6],g=sK[8],h=sK[9],i=sK[10];
  float det = a*(e*i-f*h) - b*(d*i-f*g) + c*(d*h-e*g);
  float inv00=(e*i-f*h)/det, inv01=(c*h-b*i)/det, inv02=(b*f-c*e)/det;
  float inv10=(f*g-d*i)/det, inv11=(a*i-c*g)/det, inv12=(c*d-a*f)/det;
  float inv20=(d*h-e*g)/det, inv21=(b*g-a*h)/det, inv22=(a*e-b*d)/det;
  int idx = pix[r];
  float x = (float)(idx % 400) * 2.0f;
  float y = (float)(idx / 400) * 2.0f;
  float dx = inv00*x + inv01*y + inv02;
  float dy = inv10*x + inv11*y + inv12;
  float dz = inv20*x + inv21*y + inv22;
  dirs[r*3+0]=dx; dirs[r*3+1]=dy; dirs[r*3+2]=dz;
  float n = sqrtf(dx*dx+dy*dy+dz*dz);
  float vx=dx/n, vy=dy/n, vz=dz/n;
  vd[r*3+0]=vx; vd[r*3+1]=vy; vd[r*3+2]=vz;
  vdl[r*3+0]=s2in[0]*vx + s2in[1]*vy + s2in[2]*vz;
  vdl[r*3+1]=s2in[4]*vx + s2in[5]*vy + s2in[6]*vz;
  vdl[r*3+2]=s2in[8]*vx + s2in[9]*vy + s2in[10]*vz;
}

// ---- point eval: CAT row = [H(512) | bev(512) | cam(256) | feat(128)] stride 1408 ----
__global__ __launch_bounds__(256) void eval2_k(
    const unsigned short* __restrict__ camT,  // [6][5600][256] bf16
    const unsigned short* __restrict__ bevT,  // [40000][512] bf16
    const float* __restrict__ dirs, const float* __restrict__ vd, const float* __restrict__ vdl,
    const float* __restrict__ dall, int ndepth, int R0,
    const float* __restrict__ s2in_all, const float* __restrict__ l2c_all, const float* __restrict__ rK_all,
    unsigned short* __restrict__ cat, float* __restrict__ vf)
{
  int p  = blockIdx.x;
  int rl = p / ndepth;
  int j  = p - rl*ndepth;
  int R  = R0 + rl;
  int cam = R / 200;
  const float* s2in = s2in_all + cam*16;
  const float* l2c  = l2c_all + cam*16;
  const float* rK   = rK_all + cam*16;
  float dx = dirs[R*3+0], dy = dirs[R*3+1], dz = dirs[R*3+2];
  float d = dall ? dall[(size_t)rl*ndepth + j] : (((float)j + 0.5f)/32.0f)*100.0f;
  float px = dx*d, py = dy*d, pz = dz*d;
  float lx = s2in[0]*px + s2in[1]*py + s2in[2]*pz + s2in[3];
  float ly = s2in[4]*px + s2in[5]*py + s2in[6]*pz + s2in[7];
  float lz = s2in[8]*px + s2in[9]*py + s2in[10]*pz + s2in[11];
  float ccx = l2c[0]*lx + l2c[1]*ly + l2c[2]*lz + l2c[3];
  float ccy = l2c[4]*lx + l2c[5]*ly + l2c[6]*lz + l2c[7];
  float ccz = l2c[8]*lx + l2c[9]*ly + l2c[10]*lz + l2c[11];
  float zs = fmaxf(ccz, 0.001f);
  float uu = rK[0]*ccx + rK[1]*ccy + rK[2]*ccz;
  float vv = rK[4]*ccx + rK[5]*ccy + rK[6]*ccz;
  float fu = uu/zs*(100.0f/1600.0f);
  float fv = vv/zs*(56.0f/900.0f);
  bool cvalid = (fu>=0.0f)&&(fu<=99.0f)&&(fv>=0.0f)&&(fv<=55.0f)&&(ccz>0.1f);
  float cfx0 = floorf(fu), cfy0 = floorf(fv);
  int cx0=iclampi((int)cfx0,0,99), cx1=iclampi(cx0+1,0,99);
  int cy0=iclampi((int)cfy0,0,55), cy1=iclampi(cy0+1,0,55);
  float cwx=fu-cfx0, cwy=fv-cfy0;
  float cw00=(1-cwx)*(1-cwy), cw01=cwx*(1-cwy), cw10=(1-cwx)*cwy, cw11=cwx*cwy;
  float bx = (lx+51.2f)/102.4f*199.0f;
  float by = (ly+51.2f)/102.4f*199.0f;
  bool bvalid = (bx>=0.0f)&&(bx<=199.0f)&&(by>=0.0f)&&(by<=199.0f);
  float bfx0=floorf(bx), bfy0=floorf(by);
  int bx0=iclampi((int)bfx0,0,199), bx1=iclampi(bx0+1,0,199);
  int by0=iclampi((int)bfy0,0,199), by1=iclampi(by0+1,0,199);
  float bwx=bx-bfx0, bwy=by-bfy0;
  float bw00=(1-bwx)*(1-bwy), bw01=bwx*(1-bwy), bw10=(1-bwx)*bwy, bw11=bwx*bwy;
  float vflag = (cvalid && bvalid) ? 1.0f : 0.0f;
  int t = threadIdx.x;
  uint32* catrow = (uint32*)(cat + (size_t)p*1408);
  { // bev -> cols 512..1023 (u32 idx 256..511)
    size_t sb00 = (size_t)(by0*200+bx0)*512, sb01 = (size_t)(by0*200+bx1)*512;
    size_t sb10 = (size_t)(by1*200+bx0)*512, sb11 = (size_t)(by1*200+bx1)*512;
    uint32 u00 = ((const uint32*)(bevT + sb00))[t];
    uint32 u01 = ((const uint32*)(bevT + sb01))[t];
    uint32 u10 = ((const uint32*)(bevT + sb10))[t];
    uint32 u11 = ((const uint32*)(bevT + sb11))[t];
    float lo = bw00*bf2f(u00&0xffffu) + bw01*bf2f(u01&0xffffu) + bw10*bf2f(u10&0xffffu) + bw11*bf2f(u11&0xffffu);
    float hi = bw00*bf2f(u00>>16) + bw01*bf2f(u01>>16) + bw10*bf2f(u10>>16) + bw11*bf2f(u11>>16);
    lo *= vflag; hi *= vflag;
    catrow[256 + t] = (uint32)f2bf(lo) | ((uint32)f2bf(hi)<<16);
  }
  if (t < 128){ // cam -> cols 1024..1279 (u32 idx 512..639)
    const unsigned short* cfT = camT + (size_t)cam*5600*256;
    size_t sc00 = (size_t)(cy0*100+cx0)*256, sc01 = (size_t)(cy0*100+cx1)*256;
    size_t sc10 = (size_t)(cy1*100+cx0)*256, sc11 = (size_t)(cy1*100+cx1)*256;
    uint32 u00 = ((const uint32*)(cfT + sc00))[t];
    uint32 u01 = ((const uint32*)(cfT + sc01))[t];
    uint32 u10 = ((const uint32*)(cfT + sc10))[t];
    uint32 u11 = ((const uint32*)(cfT + sc11))[t];
    float lo = cw00*bf2f(u00&0xffffu) + cw01*bf2f(u01&0xffffu) + cw10*bf2f(u10&0xffffu) + cw11*bf2f(u11&0xffffu);
    float hi = cw00*bf2f(u00>>16) + cw01*bf2f(u01>>16) + cw10*bf2f(u10>>16) + cw11*bf2f(u11>>16);
    lo *= vflag; hi *= vflag;
    catrow[512 + t] = (uint32)f2bf(lo) | ((uint32)f2bf(hi)<<16);
  }
  if (t < 64){ // feat -> cols 1280..1407 (u32 idx 640..703)
    float plx = lx/51.2f, ply = ly/51.2f, plz = (lz+1.0f)/4.0f;
    float pcx = px/100.0f, pcy = py/100.0f, pcz = pz/100.0f;
    float vx=vd[R*3], vy=vd[R*3+1], vz=vd[R*3+2];
    float wx=vdl[R*3], wy=vdl[R*3+1], wz=vdl[R*3+2];
    auto featv = [&](int s)->float{
      if (s >= 84) return 0.0f;
      if (s < 39)  return pe_elem(s, plx, ply, plz);
      if (s < 42)  return (s==39)?wx:((s==40)?wy:wz);
      if (s < 81)  return pe_elem(s-42, pcx, pcy, pcz);
      return (s==81)?vx:((s==82)?vy:vz);
    };
    float v0 = featv(2*t), v1 = featv(2*t+1);
    catrow[640 + t] = (uint32)f2bf(v0) | ((uint32)f2bf(v1)<<16);
  }
  if (vf && t==0) vf[p] = vflag;
}

// ---------------- MFMA bf16 GEMM, 2-phase double-buffered (T3 minimum form) ----------------
// C[M][N=512] = [C +] A @ BT^T + bias. global_load_lds w16, pre-swizzled source,
// XOR-swizzled ds_read_b128, 128x128 tile, dbuf LDS: sync; STAGE(t+1); compute(t).
// XCD-bijective swizzle: 4 col panels of a row panel -> same XCD, adjacent.
#define GBM 128
#define GBN 128
#define GBK 64
template<int ACC, int RELU_OUT, int WRITE_XR>
__global__ __launch_bounds__(256) void mgemm_k(
    const unsigned short* __restrict__ A, int lda,
    const unsigned short* __restrict__ BT,
    const float* __restrict__ bias,
    unsigned short* __restrict__ C, int ldc,
    unsigned short* __restrict__ XR,
    int M, int N, int K)
{
  __shared__ unsigned short As[2][GBM*GBK];  // 2 x 16 KB
  __shared__ unsigned short Bs[2][GBN*GBK];  // 2 x 16 KB
  int w = blockIdx.x;
  int xcd = w & 7, ii = w >> 3;
  int colp = ii & 3, rgrp = ii >> 2;
  int rowp = rgrp*8 + xcd;
  int row0 = rowp*GBM, col0 = colp*GBN;
  if (row0 >= M) return;
  int tid = threadIdx.x;
  int lane = tid & 63, wave = tid >> 6;
  int wm = wave >> 1, wn = wave & 1;
  int l15 = lane & 15, l4 = lane >> 4;
  int lrow = lane >> 3;        // row within this lane's 8-row group
  int lch  = lane & 7;         // 16B chunk index
  int chsw = (lch ^ lrow) * 8; // pre-swizzled source chunk offset (shorts)
  const unsigned short* aptr = A  + (size_t)(row0 + wave*32 + lrow)*lda + chsw;
  const unsigned short* bptr = BT + (size_t)(col0 + wave*32 + lrow)*K   + chsw;
  int woff = (wave*32)*64;

  auto STAGE = [&](int buf, int kk){
    unsigned short* ab = (buf ? &As[1][0] : &As[0][0]) + woff;
    unsigned short* bb = (buf ? &Bs[1][0] : &Bs[0][0]) + woff;
    #pragma unroll
    for (int i=0;i<4;++i) gl_lds16(aptr + (size_t)i*8*lda + kk, ab + i*8*64);
    #pragma unroll
    for (int i=0;i<4;++i) gl_lds16(bptr + (size_t)i*8*K   + kk, bb + i*8*64);
  };

  f32x4 acc[4][4];
  #pragma unroll
  for (int mi=0;mi<4;++mi)
    #pragma unroll
    for (int nj=0;nj<4;++nj){ f32x4 z = {0.f,0.f,0.f,0.f}; acc[mi][nj] = z; }

  STAGE(0, 0);
  int nk = K / GBK;
  for (int t=0; t<nk; ++t){
    __syncthreads();                 // drains tile-t loads; frees buf (t+1)&1
    if (t+1 < nk) STAGE((t+1)&1, (t+1)*GBK);
    const unsigned short* Ab = (t&1) ? &As[1][0] : &As[0][0];
    const unsigned short* Bb = (t&1) ? &Bs[1][0] : &Bs[0][0];
    #pragma unroll
    for (int ks=0; ks<2; ++ks){
      bf16x8 a[4], b[4];
      #pragma unroll
      for (int mi=0;mi<4;++mi){
        int row = wm*64 + mi*16 + l15;
        int sc = (ks*4 + l4) ^ (row&7);
        a[mi] = *(const bf16x8*)&Ab[row*64 + sc*8];
      }
      #pragma unroll
      for (int nj=0;nj<4;++nj){
        int colr = wn*64 + nj*16 + l15;
        int sc = (ks*4 + l4) ^ (colr&7);
        b[nj] = *(const bf16x8*)&Bb[colr*64 + sc*8];
      }
      #pragma unroll
      for (int mi=0;mi<4;++mi)
        #pragma unroll
        for (int nj=0;nj<4;++nj)
          acc[mi][nj] = __builtin_amdgcn_mfma_f32_16x16x32_bf16(a[mi], b[nj], acc[mi][nj], 0,0,0);
    }
  }
  #pragma unroll
  for (int mi=0;mi<4;++mi){
    int gr0 = row0 + wm*64 + mi*16 + l4*4;
    #pragma unroll
    for (int nj=0;nj<4;++nj){
      int gc = col0 + wn*64 + nj*16 + l15;
      if (gc >= N) continue;
      float bv = bias[gc];
      #pragma unroll
      for (int i=0;i<4;++i){
        int gr = gr0 + i;
        if (gr >= M) continue;
        float v = acc[mi][nj][i] + bv;
        if (ACC) v += bf2f((uint32)C[(size_t)gr*ldc + gc]);
        if (RELU_OUT) v = fmaxf(v, 0.0f);
        C[(size_t)gr*ldc + gc] = f2bf(v);
        if (WRITE_XR) XR[(size_t)gr*512 + gc] = f2bf(fmaxf(v, 0.0f));
      }
    }
  }
}

static inline int gemm_grid(int M){
  int nrow = (M + GBM - 1)/GBM;
  int nrowp = (nrow + 7) & ~7;   // pad to multiple of 8 for bijective XCD swizzle
  return nrowp * 4;              // 4 col panels (N=512)
}

// ---------------- out layer, wave per row ----------------
__global__ __launch_bounds__(256) void outlayer_w_k(const unsigned short* __restrict__ X,
    const float* __restrict__ W, const float* __restrict__ b, float* __restrict__ O,
    int M, int dout)
{
  int wid = threadIdx.x >> 6, lane = threadIdx.x & 63;
  int row = blockIdx.x*4 + wid;
  if (row >= M) return;
  const unsigned short* xr = X + (size_t)row*512;
  float s[4] = {0,0,0,0};
  for (int k=lane; k<512; k+=64){
    float xv = fmaxf(bf2f((uint32)xr[k]), 0.0f);
    #pragma unroll
    for (int c=0;c<4;++c)
      if (c < dout) s[c] += xv * W[(size_t)k*dout + c];
  }
  #pragma unroll
  for (int c=0;c<4;++c)
    #pragma unroll
    for (int m=32;m;m>>=1) s[c] += __shfl_xor(s[c], m, 64);
  if (lane == 0)
    for (int c=0;c<dout;++c) O[(size_t)row*dout + c] = s[c] + b[c];
}

// ---------------- coarse post, one wave per ray ----------------
// lanes 0..31: per-group (8-lane) softmax -> mu/std; lanes 32..63: gaussian
// samples; then 64-lane rank sort -> DALL.
__global__ __launch_bounds__(256) void coarse_post_w_k(const float* __restrict__ OUTB,
    float* __restrict__ MU, float* __restrict__ STD, float* __restrict__ DALL,
    int R0, int rn)
{
  int wid = threadIdx.x >> 6, lane = threadIdx.x & 63;
  int rl = blockIdx.x*4 + wid;
  if (rl >= rn) return;
  int R = R0 + rl;
  float v = 0.0f, muv = 0.0f, sdv = 0.0f;
  if (lane < 32){
    float lg = OUTB[((size_t)rl*32 + lane)*2 + 0];
    float sv = OUTB[((size_t)rl*32 + lane)*2 + 1];
    float mx = lg;
    #pragma unroll
    for (int m=1;m<8;m<<=1) mx = fmaxf(mx, __shfl_xor(mx, m, 64));
    float e = expf(lg - mx);
    float se = e;
    #pragma unroll
    for (int m=1;m<8;m<<=1) se += __shfl_xor(se, m, 64);
    float du = ((float)lane + 0.5f)/32.0f*100.0f;
    float wgt = e/se;
    float mp = wgt*du, sp = wgt*sv;
    #pragma unroll
    for (int m=1;m<8;m<<=1){ mp += __shfl_xor(mp, m, 64); sp += __shfl_xor(sp, m, 64); }
    muv = mp; sdv = softplusf_(sp) + 0.1f;
    if ((lane & 7) == 0){
      MU[R*4 + (lane>>3)] = muv;
      STD[R*4 + (lane>>3)] = sdv;
    }
    v = du;
  }
  { // broadcast group stats to lanes 32..63
    int g = (lane - 32) >> 3;
    int src = (lane >= 32) ? g*8 : 0;
    float mub = __shfl(muv, src, 64);
    float sdb = __shfl(sdv, src, 64);
    if (lane >= 32){
      int pp = (lane - 32) & 7;
      float off = -2.0f + (4.0f/7.0f)*(float)pp;
      v = fminf(fmaxf(mub + sdb*off, 0.5f), 100.0f);
    }
  }
  int rank = 0;
  for (int i=0;i<64;++i){
    float vi = __shfl(v, i, 64);
    rank += (vi < v) || (vi == v && i < lane);
  }
  DALL[(size_t)rl*64 + rank] = v;
}

__device__ __forceinline__ void bilin_img(const float* __restrict__ img, int H, int W,
                                          float u, float v, float* out3, bool* valid)
{
  *valid = (u>=0.0f)&&(u<=(float)(W-1))&&(v>=0.0f)&&(v<=(float)(H-1));
  float fx0=floorf(u), fy0=floorf(v);
  int x0=iclampi((int)fx0,0,W-1), x1=iclampi(x0+1,0,W-1);
  int y0=iclampi((int)fy0,0,H-1), y1=iclampi(y0+1,0,H-1);
  float wx=u-fx0, wy=v-fy0;
  float w00=(1-wx)*(1-wy), w01=wx*(1-wy), w10=(1-wx)*wy, w11=wx*wy;
  for (int ch=0; ch<3; ++ch){
    const float* p = img + (size_t)ch*H*W;
    out3[ch] = w00*p[y0*W+x0] + w01*p[y0*W+x1] + w10*p[y1*W+x0] + w11*p[y1*W+x1];
  }
}

// ---------------- render + losses, one wave per ray ----------------
__global__ __launch_bounds__(256) void render_loss_w_k(
  const float* __restrict__ OUTB, const float* __restrict__ VF,
  const float* __restrict__ DALL, const float* __restrict__ MU, const float* __restrict__ STD,
  const float* __restrict__ dirs, const int* __restrict__ pix,
  const float* __restrict__ src_imgs, const float* __restrict__ tgt_imgs,
  const float* __restrict__ s2tg_all, const float* __restrict__ sK_all,
  float* __restrict__ acc, int R0, int rn)
{
  int wid = threadIdx.x >> 6, lane = threadIdx.x & 63;
  int rl = blockIdx.x*4 + wid;
  if (rl >= rn) return;
  int R = R0 + rl;
  int cam = R / 200;
  int j = lane;
  float dj = DALL[(size_t)rl*64 + j];
  float delta = (j<63) ? (DALL[(size_t)rl*64 + j + 1] - dj) : 1000.0f;
  f32x4 o = *(const f32x4*)(OUTB + ((size_t)rl*64 + j)*4);
  float vfp = VF[(size_t)rl*64 + j];
  float sg = softplusf_(o[3])*vfp;
  float alpha = 1.0f - expf(-sg*delta);
  float prod = 1.0f - alpha + 1e-10f;
  #pragma unroll
  for (int dstep=1; dstep<64; dstep<<=1){
    float v = __shfl_up(prod, dstep, 64);
    if (lane >= dstep) prod *= v;
  }
  float T = __shfl_up(prod, 1, 64);
  if (lane == 0) T = 1.0f;
  float w = alpha*T;
  float c0 = w*sigmoidf_(o[0]), c1 = w*sigmoidf_(o[1]), c2 = w*sigmoidf_(o[2]);
  float dsum = w*dj, vs = vfp;
  #pragma unroll
  for (int m=32;m;m>>=1){
    c0 += __shfl_xor(c0,m,64); c1 += __shfl_xor(c1,m,64); c2 += __shfl_xor(c2,m,64);
    dsum += __shfl_xor(dsum,m,64); vs += __shfl_xor(vs,m,64);
  }
  float depth = dsum, rvr = vs/64.0f;
  float mu[4], sd[4];
  #pragma unroll
  for (int g=0;g<4;++g){ mu[g]=MU[R*4+g]; sd[g]=STD[R*4+g]; }
  float e[4], mx=-1e30f;
  #pragma unroll
  for (int g=0;g<4;++g){ float dd=dj-mu[g]; e[g]=-dd*dd*0.125f; mx=fmaxf(mx,e[g]); }
  float se=0;
  #pragma unroll
  for (int g=0;g<4;++g){ e[g]=expf(e[g]-mx); se+=e[g]; }
  float rw[4];
  #pragma unroll
  for (int g=0;g<4;++g) rw[g] = e[g]/se*w + 1e-8f;
  float srw[4], srwd[4];
  #pragma unroll
  for (int g=0;g<4;++g){ srw[g]=rw[g]; srwd[g]=rw[g]*dj; }
  #pragma unroll
  for (int m=32;m;m>>=1){
    #pragma unroll
    for (int g=0;g<4;++g){ srw[g]+=__shfl_xor(srw[g],m,64); srwd[g]+=__shfl_xor(srwd[g],m,64); }
  }
  float smean[4];
  #pragma unroll
  for (int g=0;g<4;++g) smean[g]=srwd[g]/srw[g];
  float sv[4];
  #pragma unroll
  for (int g=0;g<4;++g){ float dd=dj-smean[g]; sv[g]=rw[g]*dd*dd; }
  #pragma unroll
  for (int m=32;m;m>>=1){
    #pragma unroll
    for (int g=0;g<4;++g) sv[g]+=__shfl_xor(sv[g],m,64);
  }
  if (lane != 0) return;
  float klsum=0;
  #pragma unroll
  for (int g=0;g<4;++g){
    float var = sv[g]/srw[g];
    float sstd = sqrtf(var + 1e-6f);
    float dm = mu[g]-smean[g];
    klsum += logf(sstd/sd[g]) + (sd[g]*sd[g] + dm*dm)/(2.0f*(var+1e-6f)) - 0.5f;
  }
  float mind=1e30f;
  #pragma unroll
  for (int g=0;g<4;++g) mind = fminf(mind, fabsf(mu[g]-depth));
  const float* si = src_imgs + (size_t)cam*3*300*800;
  const float* ti = tgt_imgs + (size_t)cam*3*300*800;
  const float* s2tg = s2tg_all + cam*16;
  const float* sK = sK_all + cam*16;
  int idx = pix[R];
  float x = (float)(idx % 400) * 2.0f;
  float y = (float)(idx / 400) * 2.0f;
  float csrc[3]; bool sval;
  bilin_img(si, 300, 800, x, y, csrc, &sval);
  if (!sval){ csrc[0]=0; csrc[1]=0; csrc[2]=0; }
  float csum = fabsf(csrc[0]-c0)+fabsf(csrc[1]-c1)+fabsf(csrc[2]-c2);
  float dx=dirs[R*3], dy=dirs[R*3+1], dz=dirs[R*3+2];
  float px=dx*depth, py=dy*depth, pz=dz*depth;
  float tx=s2tg[0]*px+s2tg[1]*py+s2tg[2]*pz+s2tg[3];
  float ty=s2tg[4]*px+s2tg[5]*py+s2tg[6]*pz+s2tg[7];
  float tz=s2tg[8]*px+s2tg[9]*py+s2tg[10]*pz+s2tg[11];
  float zt=fmaxf(tz,0.001f);
  float uu=(sK[0]*tx+sK[1]*ty+sK[2]*tz)/zt;
  float vv=(sK[4]*tx+sK[5]*ty+sK[6]*tz)/zt;
  float pred[3]; bool tval;
  bilin_img(ti, 300, 800, uu, vv, pred, &tval);
  float tvf = tval?1.0f:0.0f;
  pred[0]*=tvf; pred[1]*=tvf; pred[2]*=tvf;
  float mask = (tval && (tz>0.1f) && (depth<30.0f)) ? 1.0f : 0.0f;
  float l1 = (fabsf(pred[0]-csrc[0])+fabsf(pred[1]-csrc[1])+fabsf(pred[2]-csrc[2]))*(1.0f/3.0f);
  float* a = acc + cam*8;
  atomicAdd(&a[0], csum*rvr);
  atomicAdd(&a[1], klsum);
  atomicAdd(&a[2], mind);
  atomicAdd(&a[3], l1*mask);
  atomicAdd(&a[4], mask);
}

__global__ void zero_acc_k(float* a){ a[threadIdx.x] = 0.0f; }

__global__ void finalize_k(const float* __restrict__ acc, float* __restrict__ out){
  if (threadIdx.x==0 && blockIdx.x==0){
    float tot = 0.0f;
    for (int c=0;c<6;++c){
      const float* a = acc + c*8;
      float lc  = a[0] / 600.0f;
      float lkl = a[1] / 800.0f;
      float ld  = a[2] / 200.0f;
      float lr  = a[3] / (a[4] + 1e-6f);
      if (lr != lr) lr = 0.0f;
      tot += lc + lkl + 0.01f*ld + lr;
    }
    out[0] = tot / 6.0f;
  }
}

// ---------------- host-side MLP driver ----------------
// CAT: [H(512) | bev(512) | cam(256) | feat(128)] stride 1408.
// X: bf16 residual; XR: relu(X) maintained by epilogues.
static void run_mlp5(hipStream_t stream, int M,
   const unsigned short* WmT, const float* CBin,    // merged [wz0;win], K=896
   const unsigned short* W0T, const float* b0,
   const unsigned short* W1Wz, const float* CB,
   const unsigned short* W1T2, const float* b1,
   const float* wout, const float* bout, int dout,
   unsigned short* CAT, unsigned short* X, unsigned short* XR, float* OUTB)
{
  int g = gemm_grid(M);
  mgemm_k<0,0,1><<<g,256,0,stream>>>(CAT+512, 1408, WmT, CBin, X, 512, XR, M, 512, 896);
  for (int i=0;i<2;++i){
    mgemm_k<0,1,0><<<g,256,0,stream>>>(XR, 512, W0T + (size_t)i*512*512, b0 + i*512, CAT, 1408, nullptr, M, 512, 512);
    mgemm_k<1,0,1><<<g,256,0,stream>>>(CAT, 1408, W1Wz + (size_t)i*512*1280, CB + i*512, X, 512, XR, M, 512, 1280);
  }
  mgemm_k<0,1,0><<<g,256,0,stream>>>(XR, 512, W0T + (size_t)2*512*512, b0 + 2*512, CAT, 1408, nullptr, M, 512, 512);
  mgemm_k<1,0,0><<<g,256,0,stream>>>(CAT, 1408, W1T2, b1 + 2*512, X, 512, nullptr, M, 512, 512);
  outlayer_w_k<<<(M+3)/4, 256, 0, stream>>>(X, wout, bout, OUTB, M, dout);
}

extern "C" void kernel_launch(void* const* d_in, const int* in_sizes, int n_in,
                              void* d_out, int out_size, void* d_ws, size_t ws_size,
                              hipStream_t stream) {
  (void)in_sizes; (void)n_in; (void)out_size;
  const float* cam_feat = (const float*)d_in[0];
  const float* bev_feat = (const float*)d_in[1];
  const float* src_imgs = (const float*)d_in[2];
  const float* tgt_imgs = (const float*)d_in[3];
  const float* rK   = (const float*)d_in[4];
  const float* sK   = (const float*)d_in[5];
  const float* l2c  = (const float*)d_in[6];
  const float* s2in = (const float*)d_in[7];
  const float* s2tg = (const float*)d_in[8];
  const int*   pix  = (const int*)d_in[9];
  const float* mlp_win = (const float*)d_in[10];
  const float* mlp_bin = (const float*)d_in[11];
  const float* mlp_wz  = (const float*)d_in[12];
  const float* mlp_bz  = (const float*)d_in[13];
  const float* mlp_w0  = (const float*)d_in[14];
  const float* mlp_b0  = (const float*)d_in[15];
  const float* mlp_w1  = (const float*)d_in[16];
  const float* mlp_b1  = (const float*)d_in[17];
  const float* mlp_wout= (const float*)d_in[18];
  const float* mlp_bout= (const float*)d_in[19];
  const float* g_win = (const float*)d_in[20];
  const float* g_bin = (const float*)d_in[21];
  const float* g_wz  = (const float*)d_in[22];
  const float* g_bz  = (const float*)d_in[23];
  const float* g_w0  = (const float*)d_in[24];
  const float* g_b0  = (const float*)d_in[25];
  const float* g_w1  = (const float*)d_in[26];
  const float* g_b1  = (const float*)d_in[27];
  const float* g_wout= (const float*)d_in[28];
  const float* g_bout= (const float*)d_in[29];

  char* base = (char*)d_ws;
  size_t off = 0;
  auto alloc = [&](size_t bytes)->char*{
    char* p = base + off;
    off = (off + bytes + 255) & ~(size_t)255;
    return p;
  };
  float* ACC  = (float*)alloc(64*4);
  float* DIR  = (float*)alloc(3600*4);
  float* VD   = (float*)alloc(3600*4);
  float* VDL  = (float*)alloc(3600*4);
  float* MU   = (float*)alloc(4800*4);
  float* STD  = (float*)alloc(4800*4);
  float* CBm  = (float*)alloc(3072*4);   // {mlp i0, mlp i1, g i0, g i1, mlp in, g in}
  unsigned short* bevT = (unsigned short*)alloc((size_t)40000*512*2);
  unsigned short* camT = (unsigned short*)alloc((size_t)6*5600*256*2);
  unsigned short* gWmT  = (unsigned short*)alloc((size_t)512*896*2);
  unsigned short* mWmT  = (unsigned short*)alloc((size_t)512*896*2);
  unsigned short* gW0T  = (unsigned short*)alloc((size_t)3*512*512*2);
  unsigned short* mW0T  = (unsigned short*)alloc((size_t)3*512*512*2);
  unsigned short* gW1Wz = (unsigned short*)alloc((size_t)2*512*1280*2);
  unsigned short* mW1Wz = (unsigned short*)alloc((size_t)2*512*1280*2);
  unsigned short* gW1T2 = (unsigned short*)alloc((size_t)512*512*2);
  unsigned short* mW1T2 = (unsigned short*)alloc((size_t)512*512*2);
  size_t fixed = off;
  // per-ray bytes: dall 256 + cat 180224 + x 65536 + xr 65536 + out 1024 + vf 256
  const size_t perray = 256 + 180224 + 65536 + 65536 + 1024 + 256;
  const size_t SLACK = 512*1024;
  int Rc = 1200;
  {
    size_t need = fixed + (size_t)1200*perray + SLACK + 8192;
    if (need > ws_size){
      size_t avail = (ws_size > fixed + SLACK + 8192) ? (ws_size - fixed - SLACK - 8192) : perray;
      Rc = (int)(avail / perray);
      if (Rc < 2) Rc = 2;
      Rc &= ~1;                       // keep M divisible by 128
      if (Rc > 1200) Rc = 1200;
    }
  }
  float*          DALL = (float*)alloc((size_t)Rc*64*4);
  unsigned short* CAT  = (unsigned short*)alloc((size_t)Rc*64*1408*2);
  unsigned short* X    = (unsigned short*)alloc((size_t)Rc*64*512*2);
  unsigned short* XR   = (unsigned short*)alloc((size_t)Rc*64*512*2);
  float*          OUTB = (float*)alloc((size_t)Rc*64*4*4);
  float*          VF   = (float*)alloc((size_t)Rc*64*4);

  // ---- transposes / weight prep ----
  { dim3 g((40000+31)/32, (512+31)/32, 1);
    transpose_cb_k<<<g,256,0,stream>>>(bev_feat, bevT, 512, 40000, 512, 0, 0, 512); }
  { dim3 g((5600+31)/32, (256+31)/32, 6);
    transpose_cb_k<<<g,256,0,stream>>>(cam_feat, camT, 256, 5600, 256, (size_t)256*5600, (size_t)5600*256, 256); }
  { dim3 g((512+31)/32, (768+31)/32, 1);  // wz[0] -> WmT cols 0..767
    transpose_cb_k<<<g,256,0,stream>>>(g_wz,  gWmT, 768, 512, 768, 0, 0, 896);
    transpose_cb_k<<<g,256,0,stream>>>(mlp_wz, mWmT, 768, 512, 768, 0, 0, 896); }
  { dim3 g((512+31)/32, (128+31)/32, 1);  // win -> WmT cols 768..895 (zero-pad 852..)
    transpose_cb_k<<<g,256,0,stream>>>(g_win,  gWmT+768, 84, 512, 128, 0, 0, 896);
    transpose_cb_k<<<g,256,0,stream>>>(mlp_win, mWmT+768, 84, 512, 128, 0, 0, 896); }
  { dim3 g((512+31)/32, (512+31)/32, 3);  // w0 all 3
    transpose_cb_k<<<g,256,0,stream>>>(g_w0,  gW0T, 512, 512, 512, (size_t)512*512, (size_t)512*512, 512);
    transpose_cb_k<<<g,256,0,stream>>>(mlp_w0, mW0T, 512, 512, 512, (size_t)512*512, (size_t)512*512, 512); }
  { dim3 g((512+31)/32, (512+31)/32, 2);  // w1[0..1] -> W1Wz cols 0..511
    transpose_cb_k<<<g,256,0,stream>>>(g_w1,  gW1Wz, 512, 512, 512, (size_t)512*512, (size_t)512*1280, 1280);
    transpose_cb_k<<<g,256,0,stream>>>(mlp_w1, mW1Wz, 512, 512, 512, (size_t)512*512, (size_t)512*1280, 1280); }
  { dim3 g((512+31)/32, (768+31)/32, 2);  // wz[1..2] -> W1Wz cols 512..1279
    transpose_cb_k<<<g,256,0,stream>>>(g_wz + (size_t)768*512,  gW1Wz + 512, 768, 512, 768, (size_t)768*512, (size_t)512*1280, 1280);
    transpose_cb_k<<<g,256,0,stream>>>(mlp_wz + (size_t)768*512, mW1Wz + 512, 768, 512, 768, (size_t)768*512, (size_t)512*1280, 1280); }
  { dim3 g((512+31)/32, (512+31)/32, 1);  // w1[2]
    transpose_cb_k<<<g,256,0,stream>>>(g_w1 + (size_t)2*512*512,  gW1T2, 512, 512, 512, 0, 0, 512);
    transpose_cb_k<<<g,256,0,stream>>>(mlp_w1 + (size_t)2*512*512, mW1T2, 512, 512, 512, 0, 0, 512); }
  combine_bias_k<<<12,256,0,stream>>>(mlp_b1, mlp_bz, g_b1, g_bz, mlp_bin, g_bin, CBm);

  zero_acc_k<<<1,64,0,stream>>>(ACC);
  setup_rays_k<<<5,256,0,stream>>>(pix, sK, s2in, DIR, VD, VDL);

  for (int R0=0; R0<1200; R0+=Rc){
    int rn = (1200 - R0 < Rc) ? (1200 - R0) : Rc;
    int Pc = rn*32;
    eval2_k<<<Pc,256,0,stream>>>(camT, bevT, DIR, VD, VDL,
        nullptr, 32, R0, s2in, l2c, rK, CAT, nullptr);
    run_mlp5(stream, Pc, gWmT, CBm+2560, gW0T, g_b0, gW1Wz, CBm+1024,
             gW1T2, g_b1, g_wout, g_bout, 2, CAT, X, XR, OUTB);
    coarse_post_w_k<<<(rn+3)/4,256,0,stream>>>(OUTB, MU, STD, DALL, R0, rn);
    int Pf = rn*64;
    eval2_k<<<Pf,256,0,stream>>>(camT, bevT, DIR, VD, VDL,
        DALL, 64, R0, s2in, l2c, rK, CAT, VF);
    run_mlp5(stream, Pf, mWmT, CBm+2048, mW0T, mlp_b0, mW1Wz, CBm,
             mW1T2, mlp_b1, mlp_wout, mlp_bout, 4, CAT, X, XR, OUTB);
    render_loss_w_k<<<(rn+3)/4,256,0,stream>>>(OUTB, VF, DALL, MU, STD,
        DIR, pix, src_imgs, tgt_imgs, s2tg, sK, ACC, R0, rn);
  }
  finalize_k<<<1,1,0,stream>>>(ACC, (float*)d_out);
}